// Round 3
// baseline (323.504 us; speedup 1.0000x reference)
//
#include <hip/hip_runtime.h>
#include <cstdint>
#include <cstddef>

#define HDIM 128
#define DDIM 64
#define NTYPES 5
#define NGRAPHS 16
#define PCHUNK 128   // edges per pooling block
#define EPB 64       // edges per block (one per lane)
#define APW 8        // atoms per wave in atom_proj

typedef __attribute__((ext_vector_type(8))) short short8;   // 8 bf16
typedef __attribute__((ext_vector_type(4))) float f32x4;

static __device__ __forceinline__ short8 as_s8(uint4 u) {
    return __builtin_bit_cast(short8, u);
}

// fast silu: v_rcp_f32 (rel err ~1e-7) instead of precise-division sequence
static __device__ __forceinline__ float silu_f(float v) {
    return v * __builtin_amdgcn_rcpf(1.0f + __expf(-v));
}

static __device__ __forceinline__ float4 ld4(const float* p) {
    return *reinterpret_cast<const float4*>(p);
}

static __device__ __forceinline__ void st4(float* p, float4 v) {
    *reinterpret_cast<float4*>(p) = v;
}

static __device__ __forceinline__ float4 add4(float4 a, float4 b) {
    return make_float4(a.x + b.x, a.y + b.y, a.z + b.z, a.w + b.w);
}

static __device__ __forceinline__ void silu_acc4(float4& s, float4 v) {
    s.x += silu_f(v.x);
    s.y += silu_f(v.y);
    s.z += silu_f(v.z);
    s.w += silu_f(v.w);
}

// ---- bf16 pack/unpack (round-to-nearest-even; feature j0+0 in low half) ----
static __device__ __forceinline__ unsigned int bf16r(float f) {
    unsigned int u = __float_as_uint(f);
    return (u + 0x7FFFu + ((u >> 16) & 1u)) >> 16;
}
static __device__ __forceinline__ uint4 pack8(const float* f) {
    uint4 r;
    r.x = bf16r(f[0]) | (bf16r(f[1]) << 16);
    r.y = bf16r(f[2]) | (bf16r(f[3]) << 16);
    r.z = bf16r(f[4]) | (bf16r(f[5]) << 16);
    r.w = bf16r(f[6]) | (bf16r(f[7]) << 16);
    return r;
}
static __device__ __forceinline__ void unpack8(uint4 u, float4& a, float4& b) {
    a.x = __uint_as_float(u.x << 16);
    a.y = __uint_as_float(u.x & 0xFFFF0000u);
    a.z = __uint_as_float(u.y << 16);
    a.w = __uint_as_float(u.y & 0xFFFF0000u);
    b.x = __uint_as_float(u.z << 16);
    b.y = __uint_as_float(u.z & 0xFFFF0000u);
    b.z = __uint_as_float(u.w << 16);
    b.w = __uint_as_float(u.w & 0xFFFF0000u);
}

// split fp32 -> bf16 hi + bf16 lo (lo = v - float(hi)); hi+lo ~ 16 mantissa bits
static __device__ __forceinline__ void hilo8(const float* f, uint4& h, uint4& lo) {
    h = pack8(f);
    float4 a, b;
    unpack8(h, a, b);
    float g[8] = {f[0] - a.x, f[1] - a.y, f[2] - a.z, f[3] - a.w,
                  f[4] - b.x, f[5] - b.y, f[6] - b.z, f[7] - b.w};
    lo = pack8(g);
}

// XCD-affinity swizzle (heuristic blk%8 -> XCD round-robin; validated r7:
// layer_k FETCH 82 -> 25.7 MB).
static __device__ __forceinline__ int xcd_logical_block() {
    int chunk = (int)(gridDim.x >> 3);
    return (int)(blockIdx.x & 7) * chunk + (int)(blockIdx.x >> 3);
}

// ---------------- CSR build ----------------
__global__ void __launch_bounds__(256) count_k(const int* __restrict__ bdst,
                                               int* __restrict__ cnt, int BE) {
    int i = blockIdx.x * 256 + threadIdx.x;
    if (i < BE)
        __hip_atomic_fetch_add(&cnt[bdst[i]], 1, __ATOMIC_RELAXED, __HIP_MEMORY_SCOPE_AGENT);
}

__global__ void __launch_bounds__(256) bsum_k(const int* __restrict__ cnt,
                                              int* __restrict__ bsum, int E) {
    __shared__ int red[256];
    int t = threadIdx.x;
    int i = blockIdx.x * 256 + t;
    red[t] = (i < E) ? cnt[i] : 0;
    __syncthreads();
    #pragma unroll
    for (int off = 128; off > 0; off >>= 1) {
        if (t < off) red[t] += red[t + off];
        __syncthreads();
    }
    if (t == 0) bsum[blockIdx.x] = red[0];
}

__global__ void __launch_bounds__(1024) bscan_k(const int* __restrict__ bsum,
                                                int* __restrict__ bpre, int NB) {
    __shared__ int sh[1024];
    int t = threadIdx.x;
    int v0 = (t < NB) ? bsum[t] : 0;
    sh[t] = v0;
    __syncthreads();
    for (int off = 1; off < 1024; off <<= 1) {
        int v = (t >= off) ? sh[t - off] : 0;
        __syncthreads();
        sh[t] += v;
        __syncthreads();
    }
    if (t < NB) bpre[t] = sh[t] - v0;
}

__global__ void __launch_bounds__(256) offs_k(const int* __restrict__ cnt,
                                              const int* __restrict__ bpre,
                                              int* __restrict__ offs,
                                              int* __restrict__ cursor, int E) {
    __shared__ int sh[256];
    int t = threadIdx.x;
    int i = blockIdx.x * 256 + t;
    int v0 = (i < E) ? cnt[i] : 0;
    sh[t] = v0;
    __syncthreads();
    for (int off = 1; off < 256; off <<= 1) {
        int v = (t >= off) ? sh[t - off] : 0;
        __syncthreads();
        sh[t] += v;
        __syncthreads();
    }
    int ex = sh[t] - v0 + bpre[blockIdx.x];
    if (i < E) { offs[i] = ex; cursor[i] = ex; }
    if (i == E - 1) offs[E] = ex + v0;
}

__global__ void __launch_bounds__(256) scatter_k(const int* __restrict__ bsrc,
                                                 const int* __restrict__ bdst,
                                                 int* __restrict__ cursor,
                                                 int* __restrict__ srclist, int BE) {
    int i = blockIdx.x * 256 + threadIdx.x;
    if (i < BE) {
        int d = bdst[i];
        int p = __hip_atomic_fetch_add(&cursor[d], 1, __ATOMIC_RELAXED,
                                       __HIP_MEMORY_SCOPE_AGENT);
        srclist[p] = bsrc[i];
    }
}

// ---------------- merged prep: tt + b2u + all MFMA B-fragment packs ----------------
// B-frag pack layout for mfma_f32_16x16x32_bf16 (B is K32 x N16):
//   lane l holds B[ks*32 + (l>>4)*8 + i][jt*16 + (l&15)], i=0..7, as 8 bf16.
// Buffer index: ((jt*2+ks)*64 + lane)*2 + {0=hi,1=lo}.  One 64x64 matrix = 1024 uint4.
// Blocks 0..9: tt; 10..11: b2u; 12..99: fragment packs (fW2u computed on the fly).
__global__ void __launch_bounds__(64) prep_k(const float* __restrict__ emb,
                                             const float* __restrict__ mw1,
                                             const float* __restrict__ mb1,
                                             const float* __restrict__ mw2,
                                             const float* __restrict__ mb2,
                                             const float* __restrict__ uw1,
                                             const float* __restrict__ uw2,
                                             const float* __restrict__ iw2,
                                             float* __restrict__ tt,
                                             float* __restrict__ b2u,
                                             uint4* __restrict__ fw2u,
                                             uint4* __restrict__ fu1b,
                                             uint4* __restrict__ fu2,
                                             uint4* __restrict__ fp,
                                             uint4* __restrict__ fiw2,
                                             uint4* __restrict__ fp0) {
    int b = blockIdx.x;
    int l = threadIdx.x;
    if (b < 10) {            // tt[l][t] = emb[l][t] @ mw1[l][128:192] + mb1[l]
        int ll = b / NTYPES, t = b % NTYPES;
        const float* embl = emb + (size_t)ll * NTYPES * DDIM + (size_t)t * DDIM;
        const float* w1 = mw1 + (size_t)ll * 192 * DDIM;
        float s = mb1[ll * DDIM + l];
        #pragma unroll 8
        for (int k = 0; k < DDIM; ++k)
            s = fmaf(embl[k], w1[(HDIM + k) * DDIM + l], s);
        tt[(size_t)b * DDIM + l] = s;
        return;
    }
    if (b < 12) {            // b2u[l] = mb2[l] @ uw1[l][0:64]
        int ll = b - 10;
        const float* u1 = uw1 + (size_t)ll * 128 * DDIM;
        float s = 0.f;
        #pragma unroll 8
        for (int t = 0; t < DDIM; ++t)
            s = fmaf(mb2[ll * DDIM + t], u1[(size_t)t * DDIM + l], s);
        b2u[ll * DDIM + l] = s;
        return;
    }
    int pb = b - 12;
    int mat = pb >> 3, jt = (pb >> 1) & 3, ks = pb & 1;
    int k0 = ks * 32 + (l >> 4) * 8;
    int j = jt * 16 + (l & 15);
    float f[8];
    uint4* dst;
    if (mat <= 1) {          // fW2u: w2u[k][j] = mw2[l] @ uw1[l][0:64] on the fly
        const float* w2 = mw2 + (size_t)mat * DDIM * DDIM;
        const float* u1 = uw1 + (size_t)mat * 128 * DDIM;
        #pragma unroll
        for (int i = 0; i < 8; ++i) {
            float s = 0.f;
            #pragma unroll 8
            for (int t = 0; t < DDIM; ++t)
                s = fmaf(w2[(size_t)(k0 + i) * DDIM + t], u1[(size_t)t * DDIM + j], s);
            f[i] = s;
        }
        dst = fw2u + (size_t)mat * 1024;
    } else {
        const float* src;
        switch (mat) {
            case 2:  src = uw1 + 64 * 64;                   dst = fu1b;        break;
            case 3:  src = uw1 + 128 * 64 + 64 * 64;        dst = fu1b + 1024; break;
            case 4:  src = uw2;                             dst = fu2;         break;
            case 5:  src = uw2 + 4096;                      dst = fu2 + 1024;  break;
            case 6:  src = mw1 + (size_t)192 * 64;          dst = fp;          break;
            case 7:  src = mw1 + (size_t)192 * 64 + 64 * 64; dst = fp + 1024;  break;
            case 8:  src = iw2;                             dst = fiw2;        break;
            case 9:  src = mw1;                             dst = fp0;         break;
            default: src = mw1 + (size_t)64 * 64;           dst = fp0 + 1024;  break;
        }
        #pragma unroll
        for (int i = 0; i < 8; ++i) f[i] = src[(size_t)(k0 + i) * DDIM + j];
    }
    uint4 h, lo;
    hilo8(f, h, lo);
    size_t di = ((size_t)(jt * 2 + ks) * 64 + l) * 2;
    dst[di] = h;
    dst[di + 1] = lo;
}

// LDS A-tile: [64 rows][8 slots of 16B] bf16, XOR-swizzled within the row so the
// 128B-stride fragment reads don't 16-way bank-conflict (G4).
static __device__ __forceinline__ int slotIdx(int row, int slot) {
    return row * 8 + (slot ^ (row & 7));
}

// A-frag (M16 x K32): lane l holds A[rowBase + (l&15)][ks*32 + (l>>4)*8 + i], i=0..7.
static __device__ __forceinline__ short8 ldFragA(const uint4* buf, int rowBase, int lane, int ks) {
    int row = rowBase + (lane & 15);
    int slot = ks * 4 + (lane >> 4);
    return as_s8(buf[slotIdx(row, slot)]);
}

static __device__ __forceinline__ void loadB(const uint4* __restrict__ frag, int jt, int lane,
                                             short8& h0, short8& h1, short8& l0, short8& l1) {
    const uint4* p0 = frag + ((size_t)(jt * 2 + 0) * 64 + lane) * 2;
    const uint4* p1 = frag + ((size_t)(jt * 2 + 1) * 64 + lane) * 2;
    h0 = as_s8(p0[0]); l0 = as_s8(p0[1]);
    h1 = as_s8(p1[0]); l1 = as_s8(p1[1]);
}

// one 16x16 output tile, K=64, split-precision: Ahi*Bhi + Alo*Bhi + Ahi*Blo
static __device__ __forceinline__ f32x4 gemm_tile(const uint4* Ahi, const uint4* Alo,
        int rowBase, int lane,
        short8 bh0, short8 bh1, short8 bl0, short8 bl1, f32x4 acc) {
    short8 ah0 = ldFragA(Ahi, rowBase, lane, 0);
    short8 ah1 = ldFragA(Ahi, rowBase, lane, 1);
    short8 al0 = ldFragA(Alo, rowBase, lane, 0);
    short8 al1 = ldFragA(Alo, rowBase, lane, 1);
    acc = __builtin_amdgcn_mfma_f32_16x16x32_bf16(ah0, bh0, acc, 0, 0, 0);
    acc = __builtin_amdgcn_mfma_f32_16x16x32_bf16(ah1, bh1, acc, 0, 0, 0);
    acc = __builtin_amdgcn_mfma_f32_16x16x32_bf16(al0, bh0, acc, 0, 0, 0);
    acc = __builtin_amdgcn_mfma_f32_16x16x32_bf16(al1, bh1, acc, 0, 0, 0);
    acc = __builtin_amdgcn_mfma_f32_16x16x32_bf16(ah0, bl0, acc, 0, 0, 0);
    acc = __builtin_amdgcn_mfma_f32_16x16x32_bf16(ah1, bl1, acc, 0, 0, 0);
    return acc;
}

// ---------------- atom-side projection: wave-per-8-atoms, lane = feature ----------------
__global__ void __launch_bounds__(256) atom_proj_k(
    const float* __restrict__ AF, const float* __restrict__ iw1,
    float* __restrict__ pa, float* __restrict__ qa, float* __restrict__ na, int N) {
    int lane = threadIdx.x & 63;
    int w = __builtin_amdgcn_readfirstlane((int)(threadIdx.x >> 6));
    int abase = blockIdx.x * (4 * APW) + w * APW;
    if (abase >= N) return;

    float accp[APW], accq[APW], nrm[APW];
    #pragma unroll
    for (int a = 0; a < APW; ++a) { accp[a] = 0.f; accq[a] = 0.f; nrm[a] = 0.f; }

    #pragma unroll 4
    for (int k = 0; k < HDIM; k += 4) {
        float wt[4], wb[4];
        #pragma unroll
        for (int kk = 0; kk < 4; ++kk) {
            wt[kk] = iw1[(size_t)(k + kk) * DDIM + lane];
            wb[kk] = iw1[(size_t)(HDIM + k + kk) * DDIM + lane];
        }
        #pragma unroll
        for (int a = 0; a < APW; ++a) {
            int aa = min(abase + a, N - 1);           // wave-uniform
            float4 hv = ld4(AF + (size_t)aa * HDIM + k);
            accp[a] = fmaf(hv.x, wt[0], accp[a]);
            accp[a] = fmaf(hv.y, wt[1], accp[a]);
            accp[a] = fmaf(hv.z, wt[2], accp[a]);
            accp[a] = fmaf(hv.w, wt[3], accp[a]);
            accq[a] = fmaf(hv.x, wb[0], accq[a]);
            accq[a] = fmaf(hv.y, wb[1], accq[a]);
            accq[a] = fmaf(hv.z, wb[2], accq[a]);
            accq[a] = fmaf(hv.w, wb[3], accq[a]);
            nrm[a] = fmaf(hv.x, hv.x, nrm[a]);
            nrm[a] = fmaf(hv.y, hv.y, nrm[a]);
            nrm[a] = fmaf(hv.z, hv.z, nrm[a]);
            nrm[a] = fmaf(hv.w, hv.w, nrm[a]);
        }
    }
    #pragma unroll
    for (int a = 0; a < APW; ++a) {
        int atom = abase + a;
        if (atom < N) {
            pa[(size_t)atom * DDIM + lane] = accp[a];
            qa[(size_t)atom * DDIM + lane] = accq[a];
            if (lane == 0) na[atom] = sqrtf(nrm[a]);
        }
    }
}

// ---------------- bond init (MFMA, 1024-thread version) ----------------
// 1024 threads = 16 waves, block = 64 bonds.
// P0: thread (dl=tid>>4, q=(tid>>1)&7, h=tid&1): h splits the dot k-range and the
//     pa/qa load; combine via shfl_xor(1..8); h==0 stages h = silu(pa+qa+b1).
// P1: x = h@iw2 + b2 (1 tile/wave); store fp32 x; stage x hi/lo.
// P2: pd = x@mw1_l0[0:64] (fp32), ps = bf16(x@mw1_l0[64:128])  (2 tiles/wave).
__global__ void __launch_bounds__(1024, 8) bond_init2_k(
    const float* __restrict__ AF, const int* __restrict__ row, const int* __restrict__ col,
    const float* __restrict__ pa, const float* __restrict__ qa, const float* __restrict__ na,
    const float* __restrict__ b1, const uint4* __restrict__ fW2, const float* __restrict__ b2,
    const uint4* __restrict__ fP0,
    float* __restrict__ x, int* __restrict__ bt,
    float* __restrict__ pd, uint4* __restrict__ ps, int E) {
    __shared__ uint4 sAhi[512];   // h, then ps staging (hi)
    __shared__ uint4 sAlo[512];   //                    (lo)
    __shared__ uint4 sXhi[512];   // x                  (hi)
    __shared__ uint4 sXlo[512];   //                    (lo)
    int nEB = (E + EPB - 1) / EPB;
    int lb = xcd_logical_block();
    if (lb >= nEB) return;
    int tid = threadIdx.x;
    int lane = tid & 63;
    int w = __builtin_amdgcn_readfirstlane((int)(tid >> 6));   // 0..15
    int e0 = lb * EPB;

    // ---- P0 ----
    {
        int dl = tid >> 4, q = (tid >> 1) & 7, h = tid & 1;
        int d = e0 + dl;
        bool ok = d < E;
        int dd = ok ? d : 0;
        int r = row[dd], c = col[dd];
        int jq = q * 8;

        // dot partial over AF[.][16q+8h .. +8)
        const float* hi = AF + (size_t)r * HDIM + q * 16 + h * 8;
        const float* hj = AF + (size_t)c * HDIM + q * 16 + h * 8;
        float4 a4 = ld4(hi), a5 = ld4(hi + 4);
        float4 b4 = ld4(hj), b5 = ld4(hj + 4);
        float dt = a4.x * b4.x + a4.y * b4.y + a4.z * b4.z + a4.w * b4.w
                 + a5.x * b5.x + a5.y * b5.y + a5.z * b5.z + a5.w * b5.w;
        // reduce across the 16 lanes of this bond (lane bits 0..3 = h,q)
        dt += __shfl_xor(dt, 1, 64);
        dt += __shfl_xor(dt, 2, 64);
        dt += __shfl_xor(dt, 4, 64);
        dt += __shfl_xor(dt, 8, 64);
        if (q == 0 && h == 0 && ok) {
            float nr = fmaxf(na[r], 1e-8f), nc = fmaxf(na[c], 1e-8f);
            float sim = dt / (nr * nc);
            int t = 0;
            if (sim > 0.8f) t = 1;
            if (sim > 0.9f) t = 2;
            if (sim < 0.3f) t = 3;
            bt[d] = t;
        }

        // pa (h=0) / qa (h=1) octet; combine via shfl_xor(1)
        const float* srcv = h ? (qa + (size_t)c * DDIM + jq) : (pa + (size_t)r * DDIM + jq);
        float4 v0 = ld4(srcv), v1 = ld4(srcv + 4);
        v0.x += __shfl_xor(v0.x, 1, 64);
        v0.y += __shfl_xor(v0.y, 1, 64);
        v0.z += __shfl_xor(v0.z, 1, 64);
        v0.w += __shfl_xor(v0.w, 1, 64);
        v1.x += __shfl_xor(v1.x, 1, 64);
        v1.y += __shfl_xor(v1.y, 1, 64);
        v1.z += __shfl_xor(v1.z, 1, 64);
        v1.w += __shfl_xor(v1.w, 1, 64);
        if (h == 0) {
            float hv[8];
            hv[0] = silu_f(v0.x + b1[jq + 0]);
            hv[1] = silu_f(v0.y + b1[jq + 1]);
            hv[2] = silu_f(v0.z + b1[jq + 2]);
            hv[3] = silu_f(v0.w + b1[jq + 3]);
            hv[4] = silu_f(v1.x + b1[jq + 4]);
            hv[5] = silu_f(v1.y + b1[jq + 5]);
            hv[6] = silu_f(v1.z + b1[jq + 6]);
            hv[7] = silu_f(v1.w + b1[jq + 7]);
            if (!ok) {
                #pragma unroll
                for (int i = 0; i < 8; ++i) hv[i] = 0.f;
            }
            uint4 h4, l4;
            hilo8(hv, h4, l4);
            int si = slotIdx(dl, q);
            sAhi[si] = h4; sAlo[si] = l4;
        }
    }
    // preload W2 frags (independent of LDS; overlaps barrier wait)
    int jt = w & 3, rt = (w >> 2) & 3;
    short8 W2h0, W2h1, W2l0, W2l1;
    loadB(fW2, jt, lane, W2h0, W2h1, W2l0, W2l1);
    __syncthreads();

    // ---- P1: x = h@iw2 + b2 (1 tile/wave) ----
    int rb = rt * 16;
    f32x4 z4 = {0.f, 0.f, 0.f, 0.f};
    f32x4 acc = gemm_tile(sAhi, sAlo, rb, lane, W2h0, W2h1, W2l0, W2l1, z4);
    int j = jt * 16 + (lane & 15);
    float b2j = b2[j];
    unsigned short* hX = (unsigned short*)sXhi;
    unsigned short* lX = (unsigned short*)sXlo;
    #pragma unroll
    for (int r = 0; r < 4; ++r) {
        int rowi = rb + (lane >> 4) * 4 + r;
        int e = e0 + rowi;
        float xn = acc[r] + b2j;
        if (e < E) x[(size_t)e * DDIM + j] = xn;
        unsigned int hb = bf16r(xn);
        float lov = xn - __uint_as_float(hb << 16);
        int ui = (rowi * 8 + ((j >> 3) ^ (rowi & 7))) * 8 + (j & 7);
        hX[ui] = (unsigned short)hb;
        lX[ui] = (unsigned short)bf16r(lov);
    }
    __syncthreads();    // x staged; P1 h-reads done before P2 sA-writes

    // ---- P2: layer-0 proj (2 tiles/wave over the 128-wide output) ----
    int c8 = w & 7, rt2 = w >> 3;
    const uint4* fPw = (c8 < 4) ? fP0 : (fP0 + 1024);
    int jp = w & 3;
    short8 Ph0, Ph1, Pl0, Pl1;
    loadB(fPw, jp, lane, Ph0, Ph1, Pl0, Pl1);
    f32x4 q0 = gemm_tile(sXhi, sXlo, rt2 * 32, lane, Ph0, Ph1, Pl0, Pl1, z4);
    f32x4 q1 = gemm_tile(sXhi, sXlo, rt2 * 32 + 16, lane, Ph0, Ph1, Pl0, Pl1, z4);
    unsigned short* hA = (unsigned short*)sAhi;
    if (c8 < 4) {
        int jd = jp * 16 + (lane & 15);
        #pragma unroll
        for (int mt = 0; mt < 2; ++mt) {
            f32x4 qq = (mt == 0) ? q0 : q1;
            #pragma unroll
            for (int r = 0; r < 4; ++r) {
                int rowi = rt2 * 32 + mt * 16 + (lane >> 4) * 4 + r;
                int e = e0 + rowi;
                if (e < E) pd[(size_t)e * DDIM + jd] = qq[r];
            }
        }
    } else {
        int js = jp * 16 + (lane & 15);
        #pragma unroll
        for (int mt = 0; mt < 2; ++mt) {
            f32x4 qq = (mt == 0) ? q0 : q1;
            #pragma unroll
            for (int r = 0; r < 4; ++r) {
                int rowi = rt2 * 32 + mt * 16 + (lane >> 4) * 4 + r;
                int ui = (rowi * 8 + ((js >> 3) ^ (rowi & 7))) * 8 + (js & 7);
                hA[ui] = (unsigned short)bf16r(qq[r]);
            }
        }
    }
    __syncthreads();
    if (tid < 512) {
        int dl = tid >> 3, q = tid & 7;
        int d = e0 + dl;
        if (d < E) ps[(size_t)d * 8 + q] = sAhi[slotIdx(dl, q)];
    }
}

// proj (x from global) — fallback path only (used if ws too small for pd2/ps2)
__global__ void __launch_bounds__(256) proj_k(const float* __restrict__ x,
                                              const float* __restrict__ w1 /*[192][64]*/,
                                              float* __restrict__ pd, uint4* __restrict__ ps,
                                              int E) {
    int lane = threadIdx.x & 63;
    int w = __builtin_amdgcn_readfirstlane((int)(threadIdx.x >> 6));
    int e = blockIdx.x * EPB + lane;
    bool ok = e < E;
    int eidx = ok ? e : 0;
    int j0 = w * 16;
    const float* xr = x + (size_t)eidx * DDIM;

    float apd[16], aps[16];
    #pragma unroll
    for (int jj = 0; jj < 16; ++jj) { apd[jj] = 0.f; aps[jj] = 0.f; }
    #pragma unroll 2
    for (int c = 0; c < 16; ++c) {
        float4 v = ld4(xr + c * 4);
        float xv[4] = {v.x, v.y, v.z, v.w};
        #pragma unroll
        for (int kk = 0; kk < 4; ++kk) {
            int k = c * 4 + kk;
            const float* wd = w1 + (size_t)k * DDIM + j0;
            const float* wsv = w1 + (size_t)(DDIM + k) * DDIM + j0;
            #pragma unroll
            for (int jj = 0; jj < 16; ++jj) {
                apd[jj] = fmaf(xv[kk], wd[jj], apd[jj]);
                aps[jj] = fmaf(xv[kk], wsv[jj], aps[jj]);
            }
        }
    }
    if (ok) {
        float* pr = pd + (size_t)e * DDIM + j0;
        st4(pr + 0,  make_float4(apd[0],  apd[1],  apd[2],  apd[3]));
        st4(pr + 4,  make_float4(apd[4],  apd[5],  apd[6],  apd[7]));
        st4(pr + 8,  make_float4(apd[8],  apd[9],  apd[10], apd[11]));
        st4(pr + 12, make_float4(apd[12], apd[13], apd[14], apd[15]));
        ps[(size_t)e * 8 + 2 * w + 0] = pack8(aps + 0);
        ps[(size_t)e * 8 + 2 * w + 1] = pack8(aps + 8);
    }
}

// ---------------- fused gather + update (+ optional next-layer proj), 1024-thread ----
// 1024 threads = 16 waves, block = 64 bonds.
// P1: thread (dl, q, h): h halves walk every-other neighbor; combine via shfl_xor(1).
//     h==0 stages s (inv-scaled hi/lo bf16); h==1 stages x hi/lo.
// P2: h = silu((inv*s)@W2u + x@Uw1b + ub1 + degflag*b2u)   [1 tile/wave]
// P3: xnew = x + h@Uw2 + ub2; store; stage xnew hi/lo       [1 tile/wave]
// P4 (layer0): pdn = xnew@W1d (fp32); psn = bf16(xnew@W1s)  [2 tiles/wave]
// D layout (m89-verified): col = lane&15, row = (lane>>4)*4 + reg.
__global__ void __launch_bounds__(1024, 8) layer_k(
    float* __restrict__ x, const float* __restrict__ pd, const uint4* __restrict__ ps,
    const float* __restrict__ tt_l, const int* __restrict__ bt,
    const int* __restrict__ offs, const int* __restrict__ srclist,
    const int* __restrict__ cnt,
    const uint4* __restrict__ fW2u, const float* __restrict__ b2u,
    const uint4* __restrict__ fU1b, const float* __restrict__ ub1,
    const uint4* __restrict__ fU2, const float* __restrict__ ub2,
    const uint4* __restrict__ fP /* next-layer proj frags or nullptr */,
    float* __restrict__ pdn, uint4* __restrict__ psn, int E) {
    __shared__ uint4 sAhi[512];   // s / h / psn-staging  (hi)
    __shared__ uint4 sAlo[512];   //                      (lo)
    __shared__ uint4 sXhi[512];   // x / xnew             (hi)
    __shared__ uint4 sXlo[512];   //                      (lo)
    __shared__ float degLDS[64];  // 1.0 if deg>0 else 0.0
    int nEB = (E + EPB - 1) / EPB;
    int lb = xcd_logical_block();
    if (lb >= nEB) return;
    int tid = threadIdx.x;
    int lane = tid & 63;
    int w = __builtin_amdgcn_readfirstlane((int)(tid >> 6));   // 0..15
    int e0 = lb * EPB;

    // ---- P1: gather (16 threads per bond: 8 octets x 2 neighbor-halves) ----
    {
        int dl = tid >> 4, q = (tid >> 1) & 7, h = tid & 1;
        int d = e0 + dl;
        bool ok = d < E;
        int dd = ok ? d : 0;
        int jq = q * 8;
        float4 xv0 = {0.f, 0.f, 0.f, 0.f}, xv1 = xv0;
        if (h) {                               // issued early, used late
            const float* xr = x + (size_t)dd * DDIM + jq;
            xv0 = ld4(xr + 0); xv1 = ld4(xr + 4);
        }
        int dc = cnt[dd];
        const float* pr = pd + (size_t)dd * DDIM + jq;
        const float* tp = tt_l + (size_t)bt[dd] * DDIM + jq;
        float4 b0 = add4(ld4(pr + 0), ld4(tp + 0));
        float4 bb1 = add4(ld4(pr + 4), ld4(tp + 4));
        float4 s0 = make_float4(0, 0, 0, 0), s1 = s0;
        int p0 = ok ? offs[d] : 0, p1 = ok ? offs[d + 1] : 0;
        int p = p0 + h;
        for (; p + 2 < p1; p += 4) {
            uint4 u0 = ps[(size_t)srclist[p + 0] * 8 + q];
            uint4 u1 = ps[(size_t)srclist[p + 2] * 8 + q];
            float4 a, b;
            unpack8(u0, a, b);
            silu_acc4(s0, add4(b0, a));
            silu_acc4(s1, add4(bb1, b));
            unpack8(u1, a, b);
            silu_acc4(s0, add4(b0, a));
            silu_acc4(s1, add4(bb1, b));
        }
        for (; p < p1; p += 2) {
            uint4 u0 = ps[(size_t)srclist[p] * 8 + q];
            float4 a, b;
            unpack8(u0, a, b);
            silu_acc4(s0, add4(b0, a));
            silu_acc4(s1, add4(bb1, b));
        }
        // combine neighbor-halves (lane ^ 1)
        s0.x += __shfl_xor(s0.x, 1, 64);
        s0.y += __shfl_xor(s0.y, 1, 64);
        s0.z += __shfl_xor(s0.z, 1, 64);
        s0.w += __shfl_xor(s0.w, 1, 64);
        s1.x += __shfl_xor(s1.x, 1, 64);
        s1.y += __shfl_xor(s1.y, 1, 64);
        s1.z += __shfl_xor(s1.z, 1, 64);
        s1.w += __shfl_xor(s1.w, 1, 64);
        float inv = 1.0f / fmaxf((float)dc, 1.0f);
        int si = slotIdx(dl, q);
        uint4 h4, l4;
        if (h == 0) {
            float sv[8] = {s0.x * inv, s0.y * inv, s0.z * inv, s0.w * inv,
                           s1.x * inv, s1.y * inv, s1.z * inv, s1.w * inv};
            if (!ok) {
                #pragma unroll
                for (int i = 0; i < 8; ++i) sv[i] = 0.f;
            }
            hilo8(sv, h4, l4);
            sAhi[si] = h4; sAlo[si] = l4;
            if (q == 0) degLDS[dl] = (ok && dc > 0) ? 1.0f : 0.0f;
        } else {
            float xf[8] = {xv0.x, xv0.y, xv0.z, xv0.w, xv1.x, xv1.y, xv1.z, xv1.w};
            if (!ok) {
                #pragma unroll
                for (int i = 0; i < 8; ++i) xf[i] = 0.f;
            }
            hilo8(xf, h4, l4);
            sXhi[si] = h4; sXlo[si] = l4;
        }
    }
    // preload loop-invariant B-frags (independent of LDS; overlaps barrier wait)
    int jt = w & 3, rt = (w >> 2) & 3;
    short8 A2h0, A2h1, A2l0, A2l1;   // W2u
    short8 U1h0, U1h1, U1l0, U1l1;   // Uw1b
    loadB(fW2u, jt, lane, A2h0, A2h1, A2l0, A2l1);
    loadB(fU1b, jt, lane, U1h0, U1h1, U1l0, U1l1);
    __syncthreads();

    // ---- P2: h = silu((inv*s)@W2u + x@Uw1b + bias), 1 tile/wave ----
    int rb = rt * 16;
    f32x4 z4 = {0.f, 0.f, 0.f, 0.f};
    f32x4 acc = z4;
    acc = gemm_tile(sAhi, sAlo, rb, lane, A2h0, A2h1, A2l0, A2l1, acc);
    acc = gemm_tile(sXhi, sXlo, rb, lane, U1h0, U1h1, U1l0, U1l1, acc);
    __syncthreads();                       // all s/x fragment reads done
    int j = jt * 16 + (lane & 15);
    float ub1j = ub1[j], b2uj = b2u[j];
    unsigned short* hA = (unsigned short*)sAhi;
    unsigned short* lA = (unsigned short*)sAlo;
    #pragma unroll
    for (int r = 0; r < 4; ++r) {
        int row = rb + (lane >> 4) * 4 + r;
        float hv = silu_f(acc[r] + ub1j + degLDS[row] * b2uj);
        unsigned int hb = bf16r(hv);
        float lov = hv - __uint_as_float(hb << 16);
        int ui = (row * 8 + ((j >> 3) ^ (row & 7))) * 8 + (j & 7);
        hA[ui] = (unsigned short)hb;
        lA[ui] = (unsigned short)bf16r(lov);
    }
    __syncthreads();                       // h staged

    // ---- P3: o = h@Uw2 + ub2; xnew = x + o, 1 tile/wave ----
    short8 U2h0, U2h1, U2l0, U2l1;
    loadB(fU2, jt, lane, U2h0, U2h1, U2l0, U2l1);
    f32x4 o = gemm_tile(sAhi, sAlo, rb, lane, U2h0, U2h1, U2l0, U2l1, z4);
    float ub2j = ub2[j];
    bool haveP = (fP != nullptr);
    unsigned short* hX = (unsigned short*)sXhi;
    unsigned short* lX = (unsigned short*)sXlo;
    #pragma unroll
    for (int r = 0; r < 4; ++r) {
        int row = rb + (lane >> 4) * 4 + r;
        int e = e0 + row;
        float xvv = (e < E) ? x[(size_t)e * DDIM + j] : 0.f;
        float xn = xvv + o[r] + ub2j;
        if (e < E) x[(size_t)e * DDIM + j] = xn;
        if (haveP) {
            unsigned int hb = bf16r(xn);
            float lov = xn - __uint_as_float(hb << 16);
            int ui = (row * 8 + ((j >> 3) ^ (row & 7))) * 8 + (j & 7);
            hX[ui] = (unsigned short)hb;
            lX[ui] = (unsigned short)bf16r(lov);
        }
    }
    if (!haveP) return;
    __syncthreads();    // xnew staged; orders P3 A-reads before P4 A-writes

    // ---- P4: next-layer proj, 2 tiles/wave over the 128-wide output ----
    int c8 = w & 7, rt2 = w >> 3;
    const uint4* fPw = (c8 < 4) ? fP : (fP + 1024);
    int jp = w & 3;
    short8 Ph0, Ph1, Pl0, Pl1;
    loadB(fPw, jp, lane, Ph0, Ph1, Pl0, Pl1);
    f32x4 q0 = gemm_tile(sXhi, sXlo, rt2 * 32, lane, Ph0, Ph1, Pl0, Pl1, z4);
    f32x4 q1 = gemm_tile(sXhi, sXlo, rt2 * 32 + 16, lane, Ph0, Ph1, Pl0, Pl1, z4);
    if (c8 < 4) {
        int jd = jp * 16 + (lane & 15);
        #pragma unroll
        for (int mt = 0; mt < 2; ++mt) {
            f32x4 qq = (mt == 0) ? q0 : q1;
            #pragma unroll
            for (int r = 0; r < 4; ++r) {
                int row = rt2 * 32 + mt * 16 + (lane >> 4) * 4 + r;
                int e = e0 + row;
                if (e < E) pdn[(size_t)e * DDIM + jd] = qq[r];
            }
        }
    } else {
        int js = jp * 16 + (lane & 15);
        #pragma unroll
        for (int mt = 0; mt < 2; ++mt) {
            f32x4 qq = (mt == 0) ? q0 : q1;
            #pragma unroll
            for (int r = 0; r < 4; ++r) {
                int row = rt2 * 32 + mt * 16 + (lane >> 4) * 4 + r;
                int ui = (row * 8 + ((js >> 3) ^ (row & 7))) * 8 + (js & 7);
                hA[ui] = (unsigned short)bf16r(qq[r]);
            }
        }
    }
    __syncthreads();
    if (tid < 512) {
        int dl = tid >> 3, q = tid & 7;
        int d = e0 + dl;
        if (d < E) psn[(size_t)d * 8 + q] = sAhi[slotIdx(dl, q)];
    }
}

// ---------------- pooling ----------------
__global__ void __launch_bounds__(256) pool_k(
    const float* __restrict__ x, const int* __restrict__ row,
    const int* __restrict__ batch, float* __restrict__ gfeat, int E) {
    int lane = threadIdx.x & 63;
    int esub = threadIdx.x >> 6;       // 0..3
    int e0 = blockIdx.x * PCHUNK;
    int e1 = min(e0 + PCHUNK, E);
    float sum = 0.f;
    int cur = -1;
    for (int e = e0 + esub; e < e1; e += 4) {
        int g = batch[row[e]];         // wave-uniform -> scalar load
        if (g != cur) {
            if (cur >= 0)
                __hip_atomic_fetch_add(&gfeat[cur * DDIM + lane], sum,
                                       __ATOMIC_RELAXED, __HIP_MEMORY_SCOPE_AGENT);
            cur = g;
            sum = 0.f;
        }
        sum += x[(size_t)e * DDIM + lane];
    }
    if (cur >= 0)
        __hip_atomic_fetch_add(&gfeat[cur * DDIM + lane], sum,
                               __ATOMIC_RELAXED, __HIP_MEMORY_SCOPE_AGENT);
}

static __device__ __forceinline__ int lower_bound_bb(const int* __restrict__ row,
                                                     const int* __restrict__ batch,
                                                     int E, int g) {
    int lo = 0, hi = E;
    while (lo < hi) {
        int m = (lo + hi) >> 1;
        if (batch[row[m]] < g) lo = m + 1; else hi = m;
    }
    return lo;
}

__global__ void __launch_bounds__(64) pool_final_k(
    const int* __restrict__ row, const int* __restrict__ batch,
    float* __restrict__ gfeat, int E) {
    int g = blockIdx.x, j = threadIdx.x;
    int s = lower_bound_bb(row, batch, E, g);
    int t = lower_bound_bb(row, batch, E, g + 1);
    float cnt = fmaxf((float)(t - s), 1.0f);
    gfeat[g * DDIM + j] /= cnt;
}

extern "C" void kernel_launch(void* const* d_in, const int* in_sizes, int n_in,
                              void* d_out, int out_size, void* d_ws, size_t ws_size,
                              hipStream_t stream) {
    (void)n_in; (void)out_size;
    const float* AF    = (const float*)d_in[0];
    const int*   batch = (const int*)d_in[3];
    const int*   edge_index      = (const int*)d_in[4];
    const int*   bond_edge_index = (const int*)d_in[5];
    const float* iw1 = (const float*)d_in[6];
    const float* ib1 = (const float*)d_in[7];
    const float* iw2 = (const float*)d_in[8];
    const float* ib2 = (const float*)d_in[9];
    const float* emb = (const float*)d_in[10];
    const float* mw1 = (const float*)d_in[11];
    const float* mb1 = (const float*)d_in[12];
    const float* mw2 = (const float*)d_in[13];
    const float* mb2 = (const float*)d_in[14];
    const float* uw1 = (const float*)d_in[15];
    const float* ub1 = (const float*)d_in[16];
    const float* uw2 = (const float*)d_in[17];
    const float* ub2 = (const float*)d_in[18];

    const int N  = in_sizes[0] / HDIM;
    const int E  = in_sizes[4] / 2;
    const int BE = in_sizes[5] / 2;
    const int NB = (E + 255) / 256;
    const int EB = (E + EPB - 1) / EPB;
    const int AB = (N + 4 * APW - 1) / (4 * APW);   // atom blocks (32 atoms/block)
    const int EBS = ((EB + 7) / 8) * 8;             // swizzled grid (multiple of 8)
    const int PB = (E + PCHUNK - 1) / PCHUNK;       // pooling blocks

    float* xout  = (float*)d_out;                 // [E,64]
    float* gfeat = xout + (size_t)E * DDIM;       // [16,64]

    // workspace layout
    char* w = (char*)d_ws;
    float* tt       = (float*)w;  w += sizeof(float) * 2 * NTYPES * DDIM;
    float* b2u      = (float*)w;  w += sizeof(float) * 2 * DDIM;
    w = (char*)(((uintptr_t)w + 15) & ~(uintptr_t)15);
    // MFMA weight fragments (hi/lo bf16)
    uint4* fW2u     = (uint4*)w;  w += 2048 * sizeof(uint4);
    uint4* fU1b     = (uint4*)w;  w += 2048 * sizeof(uint4);
    uint4* fU2      = (uint4*)w;  w += 2048 * sizeof(uint4);
    uint4* fP       = (uint4*)w;  w += 2048 * sizeof(uint4);
    uint4* fIw2     = (uint4*)w;  w += 1024 * sizeof(uint4);
    uint4* fP0      = (uint4*)w;  w += 2048 * sizeof(uint4);
    int*   cnt      = (int*)w;    w += sizeof(int) * E;
    int*   offs     = (int*)w;    w += sizeof(int) * (E + 1);
    int*   cursor   = (int*)w;    w += sizeof(int) * E;
    int*   bt       = (int*)w;    w += sizeof(int) * E;
    int*   bsum     = (int*)w;    w += sizeof(int) * 1024;
    int*   bpre     = (int*)w;    w += sizeof(int) * 1024;
    int*   srclist  = (int*)w;    w += sizeof(int) * BE;
    w = (char*)(((uintptr_t)w + 15) & ~(uintptr_t)15);
    float* pd       = (float*)w;  w += sizeof(float) * (size_t)E * DDIM;
    uint4* ps       = (uint4*)w;  w += sizeof(unsigned short) * (size_t)E * DDIM;
    float* pa       = (float*)w;  w += sizeof(float) * (size_t)N * DDIM;
    float* qa       = (float*)w;  w += sizeof(float) * (size_t)N * DDIM;
    float* na       = (float*)w;  w += sizeof(float) * (size_t)N;
    w = (char*)(((uintptr_t)w + 15) & ~(uintptr_t)15);
    // optional second proj buffers (fused-proj path)
    float* pd2      = (float*)w;  w += sizeof(float) * (size_t)E * DDIM;
    uint4* ps2      = (uint4*)w;  w += sizeof(unsigned short) * (size_t)E * DDIM;
    bool fuse_proj = ((size_t)(w - (char*)d_ws) <= ws_size);

    const int* row  = edge_index;
    const int* col  = edge_index + E;
    const int* bsrc = bond_edge_index;
    const int* bdst = bond_edge_index + BE;

    // CSR build
    hipMemsetAsync(cnt, 0, (size_t)E * sizeof(int), stream);
    count_k<<<(BE + 255) / 256, 256, 0, stream>>>(bdst, cnt, BE);
    bsum_k<<<NB, 256, 0, stream>>>(cnt, bsum, E);
    bscan_k<<<1, 1024, 0, stream>>>(bsum, bpre, NB);
    offs_k<<<NB, 256, 0, stream>>>(cnt, bpre, offs, cursor, E);
    scatter_k<<<(BE + 255) / 256, 256, 0, stream>>>(bsrc, bdst, cursor, srclist, BE);

    // constants: tt + b2u + all MFMA B-fragments in one launch
    prep_k<<<100, 64, 0, stream>>>(emb, mw1, mb1, mw2, mb2, uw1, uw2, iw2,
                                   tt, b2u, fW2u, fU1b, fU2, fP, fIw2, fP0);

    // atom projections, then bond init + layer-0 proj (MFMA)
    atom_proj_k<<<AB, 256, 0, stream>>>(AF, iw1, pa, qa, na, N);
    bond_init2_k<<<EBS, 1024, 0, stream>>>(AF, row, col, pa, qa, na, ib1, fIw2, ib2,
                                           fP0, xout, bt, pd, ps, E);

    if (fuse_proj) {
        // layer 0: fused next-layer proj -> pd2/ps2
        layer_k<<<EBS, 1024, 0, stream>>>(
            xout, pd, ps, tt, bt, offs, srclist, cnt,
            fW2u, b2u, fU1b, ub1, fU2, ub2,
            fP, pd2, ps2, E);
        // layer 1: no proj
        layer_k<<<EBS, 1024, 0, stream>>>(
            xout, pd2, ps2, tt + NTYPES * DDIM, bt, offs, srclist, cnt,
            fW2u + 1024, b2u + DDIM, fU1b + 1024, ub1 + DDIM,
            fU2 + 1024, ub2 + DDIM,
            nullptr, nullptr, nullptr, E);
    } else {
        for (int l = 0; l < 2; ++l) {
            if (l > 0)
                proj_k<<<EB, 256, 0, stream>>>(xout, mw1 + (size_t)l * 192 * 64, pd, ps, E);
            layer_k<<<EBS, 1024, 0, stream>>>(
                xout, pd, ps, tt + (size_t)l * NTYPES * DDIM, bt, offs, srclist, cnt,
                fW2u + (size_t)l * 1024, b2u + (size_t)l * DDIM,
                fU1b + (size_t)l * 1024, ub1 + (size_t)l * DDIM,
                fU2 + (size_t)l * 1024, ub2 + (size_t)l * DDIM,
                nullptr, nullptr, nullptr, E);
        }
    }

    hipMemsetAsync(gfeat, 0, NGRAPHS * DDIM * sizeof(float), stream);
    pool_k<<<PB, 256, 0, stream>>>(xout, row, batch, gfeat, E);
    pool_final_k<<<NGRAPHS, 64, 0, stream>>>(row, batch, gfeat, E);
}

// Round 4
// 315.227 us; speedup vs baseline: 1.0263x; 1.0263x over previous
//
#include <hip/hip_runtime.h>
#include <cstdint>
#include <cstddef>

#define HDIM 128
#define DDIM 64
#define NTYPES 5
#define NGRAPHS 16
#define PCHUNK 128   // edges per pooling block
#define EPB 64       // edges per block (one per lane)
#define APW 8        // atoms per wave in atom_proj

typedef __attribute__((ext_vector_type(8))) short short8;   // 8 bf16
typedef __attribute__((ext_vector_type(4))) float f32x4;

static __device__ __forceinline__ short8 as_s8(uint4 u) {
    return __builtin_bit_cast(short8, u);
}

// fast silu: v_rcp_f32 (rel err ~1e-7) instead of precise-division sequence
static __device__ __forceinline__ float silu_f(float v) {
    return v * __builtin_amdgcn_rcpf(1.0f + __expf(-v));
}

static __device__ __forceinline__ float4 ld4(const float* p) {
    return *reinterpret_cast<const float4*>(p);
}

static __device__ __forceinline__ void st4(float* p, float4 v) {
    *reinterpret_cast<float4*>(p) = v;
}

static __device__ __forceinline__ float4 add4(float4 a, float4 b) {
    return make_float4(a.x + b.x, a.y + b.y, a.z + b.z, a.w + b.w);
}

static __device__ __forceinline__ void silu_acc4(float4& s, float4 v) {
    s.x += silu_f(v.x);
    s.y += silu_f(v.y);
    s.z += silu_f(v.z);
    s.w += silu_f(v.w);
}

// ---- bf16 pack/unpack (RNE; feature j0+0 in low half) ----
static __device__ __forceinline__ unsigned int bf16r(float f) {
    unsigned int u = __float_as_uint(f);
    return (u + 0x7FFFu + ((u >> 16) & 1u)) >> 16;
}
// HW packed RNE convert: dst = bf16(a) | bf16(b)<<16  (T12 recipe; no builtin on gfx950)
static __device__ __forceinline__ unsigned int cvtpk(float a, float b) {
    unsigned int r;
    asm("v_cvt_pk_bf16_f32 %0, %1, %2" : "=v"(r) : "v"(a), "v"(b));
    return r;
}
static __device__ __forceinline__ uint4 pack8(const float* f) {
    uint4 r;
    r.x = cvtpk(f[0], f[1]);
    r.y = cvtpk(f[2], f[3]);
    r.z = cvtpk(f[4], f[5]);
    r.w = cvtpk(f[6], f[7]);
    return r;
}
static __device__ __forceinline__ void unpack8(uint4 u, float4& a, float4& b) {
    a.x = __uint_as_float(u.x << 16);
    a.y = __uint_as_float(u.x & 0xFFFF0000u);
    a.z = __uint_as_float(u.y << 16);
    a.w = __uint_as_float(u.y & 0xFFFF0000u);
    b.x = __uint_as_float(u.z << 16);
    b.y = __uint_as_float(u.z & 0xFFFF0000u);
    b.z = __uint_as_float(u.w << 16);
    b.w = __uint_as_float(u.w & 0xFFFF0000u);
}

// split fp32 -> bf16 hi + bf16 lo (lo = v - float(hi)); hi+lo ~ 16 mantissa bits
static __device__ __forceinline__ void hilo8(const float* f, uint4& h, uint4& lo) {
    h = pack8(f);
    float4 a, b;
    unpack8(h, a, b);
    lo.x = cvtpk(f[0] - a.x, f[1] - a.y);
    lo.y = cvtpk(f[2] - a.z, f[3] - a.w);
    lo.z = cvtpk(f[4] - b.x, f[5] - b.y);
    lo.w = cvtpk(f[6] - b.z, f[7] - b.w);
}

// XCD-affinity swizzle (heuristic blk%8 -> XCD round-robin; validated r7:
// layer_k FETCH 82 -> 25.7 MB).
static __device__ __forceinline__ int xcd_logical_block() {
    int chunk = (int)(gridDim.x >> 3);
    return (int)(blockIdx.x & 7) * chunk + (int)(blockIdx.x >> 3);
}

// ---------------- CSR build ----------------
__global__ void __launch_bounds__(256) count_k(const int* __restrict__ bdst,
                                               int* __restrict__ cnt, int BE) {
    int i = blockIdx.x * 256 + threadIdx.x;
    if (i < BE)
        __hip_atomic_fetch_add(&cnt[bdst[i]], 1, __ATOMIC_RELAXED, __HIP_MEMORY_SCOPE_AGENT);
}

__global__ void __launch_bounds__(256) bsum_k(const int* __restrict__ cnt,
                                              int* __restrict__ bsum, int E) {
    __shared__ int red[256];
    int t = threadIdx.x;
    int i = blockIdx.x * 256 + t;
    red[t] = (i < E) ? cnt[i] : 0;
    __syncthreads();
    #pragma unroll
    for (int off = 128; off > 0; off >>= 1) {
        if (t < off) red[t] += red[t + off];
        __syncthreads();
    }
    if (t == 0) bsum[blockIdx.x] = red[0];
}

__global__ void __launch_bounds__(1024) bscan_k(const int* __restrict__ bsum,
                                                int* __restrict__ bpre, int NB) {
    __shared__ int sh[1024];
    int t = threadIdx.x;
    int v0 = (t < NB) ? bsum[t] : 0;
    sh[t] = v0;
    __syncthreads();
    for (int off = 1; off < 1024; off <<= 1) {
        int v = (t >= off) ? sh[t - off] : 0;
        __syncthreads();
        sh[t] += v;
        __syncthreads();
    }
    if (t < NB) bpre[t] = sh[t] - v0;
}

__global__ void __launch_bounds__(256) offs_k(const int* __restrict__ cnt,
                                              const int* __restrict__ bpre,
                                              int* __restrict__ offs,
                                              int* __restrict__ cursor, int E) {
    __shared__ int sh[256];
    int t = threadIdx.x;
    int i = blockIdx.x * 256 + t;
    int v0 = (i < E) ? cnt[i] : 0;
    sh[t] = v0;
    __syncthreads();
    for (int off = 1; off < 256; off <<= 1) {
        int v = (t >= off) ? sh[t - off] : 0;
        __syncthreads();
        sh[t] += v;
        __syncthreads();
    }
    int ex = sh[t] - v0 + bpre[blockIdx.x];
    if (i < E) { offs[i] = ex; cursor[i] = ex; }
    if (i == E - 1) offs[E] = ex + v0;
}

__global__ void __launch_bounds__(256) scatter_k(const int* __restrict__ bsrc,
                                                 const int* __restrict__ bdst,
                                                 int* __restrict__ cursor,
                                                 int* __restrict__ srclist, int BE) {
    int i = blockIdx.x * 256 + threadIdx.x;
    if (i < BE) {
        int d = bdst[i];
        int p = __hip_atomic_fetch_add(&cursor[d], 1, __ATOMIC_RELAXED,
                                       __HIP_MEMORY_SCOPE_AGENT);
        srclist[p] = bsrc[i];
    }
}

// ---------------- merged prep: tt + b2u + all MFMA B-fragment packs ----------------
// B-frag pack layout for mfma_f32_16x16x32_bf16 (B is K32 x N16):
//   lane l holds B[ks*32 + (l>>4)*8 + i][jt*16 + (l&15)], i=0..7, as 8 bf16.
// Buffer index: ((jt*2+ks)*64 + lane)*2 + {0=hi,1=lo}.  One 64x64 matrix = 1024 uint4.
// Blocks 0..9: tt; 10..11: b2u; 12..99: fragment packs (fW2u computed on the fly).
__global__ void __launch_bounds__(64) prep_k(const float* __restrict__ emb,
                                             const float* __restrict__ mw1,
                                             const float* __restrict__ mb1,
                                             const float* __restrict__ mw2,
                                             const float* __restrict__ mb2,
                                             const float* __restrict__ uw1,
                                             const float* __restrict__ uw2,
                                             const float* __restrict__ iw2,
                                             float* __restrict__ tt,
                                             float* __restrict__ b2u,
                                             uint4* __restrict__ fw2u,
                                             uint4* __restrict__ fu1b,
                                             uint4* __restrict__ fu2,
                                             uint4* __restrict__ fp,
                                             uint4* __restrict__ fiw2,
                                             uint4* __restrict__ fp0) {
    int b = blockIdx.x;
    int l = threadIdx.x;
    if (b < 10) {            // tt[l][t] = emb[l][t] @ mw1[l][128:192] + mb1[l]
        int ll = b / NTYPES, t = b % NTYPES;
        const float* embl = emb + (size_t)ll * NTYPES * DDIM + (size_t)t * DDIM;
        const float* w1 = mw1 + (size_t)ll * 192 * DDIM;
        float s = mb1[ll * DDIM + l];
        #pragma unroll 8
        for (int k = 0; k < DDIM; ++k)
            s = fmaf(embl[k], w1[(HDIM + k) * DDIM + l], s);
        tt[(size_t)b * DDIM + l] = s;
        return;
    }
    if (b < 12) {            // b2u[l] = mb2[l] @ uw1[l][0:64]
        int ll = b - 10;
        const float* u1 = uw1 + (size_t)ll * 128 * DDIM;
        float s = 0.f;
        #pragma unroll 8
        for (int t = 0; t < DDIM; ++t)
            s = fmaf(mb2[ll * DDIM + t], u1[(size_t)t * DDIM + l], s);
        b2u[ll * DDIM + l] = s;
        return;
    }
    int pb = b - 12;
    int mat = pb >> 3, jt = (pb >> 1) & 3, ks = pb & 1;
    int k0 = ks * 32 + (l >> 4) * 8;
    int j = jt * 16 + (l & 15);
    float f[8];
    uint4* dst;
    if (mat <= 1) {          // fW2u: w2u[k][j] = mw2[l] @ uw1[l][0:64] on the fly
        const float* w2 = mw2 + (size_t)mat * DDIM * DDIM;
        const float* u1 = uw1 + (size_t)mat * 128 * DDIM;
        #pragma unroll
        for (int i = 0; i < 8; ++i) {
            float s = 0.f;
            #pragma unroll 8
            for (int t = 0; t < DDIM; ++t)
                s = fmaf(w2[(size_t)(k0 + i) * DDIM + t], u1[(size_t)t * DDIM + j], s);
            f[i] = s;
        }
        dst = fw2u + (size_t)mat * 1024;
    } else {
        const float* src;
        switch (mat) {
            case 2:  src = uw1 + 64 * 64;                   dst = fu1b;        break;
            case 3:  src = uw1 + 128 * 64 + 64 * 64;        dst = fu1b + 1024; break;
            case 4:  src = uw2;                             dst = fu2;         break;
            case 5:  src = uw2 + 4096;                      dst = fu2 + 1024;  break;
            case 6:  src = mw1 + (size_t)192 * 64;          dst = fp;          break;
            case 7:  src = mw1 + (size_t)192 * 64 + 64 * 64; dst = fp + 1024;  break;
            case 8:  src = iw2;                             dst = fiw2;        break;
            case 9:  src = mw1;                             dst = fp0;         break;
            default: src = mw1 + (size_t)64 * 64;           dst = fp0 + 1024;  break;
        }
        #pragma unroll
        for (int i = 0; i < 8; ++i) f[i] = src[(size_t)(k0 + i) * DDIM + j];
    }
    uint4 h, lo;
    hilo8(f, h, lo);
    size_t di = ((size_t)(jt * 2 + ks) * 64 + l) * 2;
    dst[di] = h;
    dst[di + 1] = lo;
}

// LDS A-tile: [64 rows][8 slots of 16B] bf16, XOR-swizzled within the row so the
// 128B-stride fragment reads don't 16-way bank-conflict (G4).
static __device__ __forceinline__ int slotIdx(int row, int slot) {
    return row * 8 + (slot ^ (row & 7));
}

// A-frag (M16 x K32): lane l holds A[rowBase + (l&15)][ks*32 + (l>>4)*8 + i], i=0..7.
static __device__ __forceinline__ short8 ldFragA(const uint4* buf, int rowBase, int lane, int ks) {
    int row = rowBase + (lane & 15);
    int slot = ks * 4 + (lane >> 4);
    return as_s8(buf[slotIdx(row, slot)]);
}

static __device__ __forceinline__ void loadB(const uint4* __restrict__ frag, int jt, int lane,
                                             short8& h0, short8& h1, short8& l0, short8& l1) {
    const uint4* p0 = frag + ((size_t)(jt * 2 + 0) * 64 + lane) * 2;
    const uint4* p1 = frag + ((size_t)(jt * 2 + 1) * 64 + lane) * 2;
    h0 = as_s8(p0[0]); l0 = as_s8(p0[1]);
    h1 = as_s8(p1[0]); l1 = as_s8(p1[1]);
}

// one 16x16 output tile, K=64, split-precision: Ahi*Bhi + Alo*Bhi + Ahi*Blo
static __device__ __forceinline__ f32x4 gemm_tile(const uint4* Ahi, const uint4* Alo,
        int rowBase, int lane,
        short8 bh0, short8 bh1, short8 bl0, short8 bl1, f32x4 acc) {
    short8 ah0 = ldFragA(Ahi, rowBase, lane, 0);
    short8 ah1 = ldFragA(Ahi, rowBase, lane, 1);
    short8 al0 = ldFragA(Alo, rowBase, lane, 0);
    short8 al1 = ldFragA(Alo, rowBase, lane, 1);
    acc = __builtin_amdgcn_mfma_f32_16x16x32_bf16(ah0, bh0, acc, 0, 0, 0);
    acc = __builtin_amdgcn_mfma_f32_16x16x32_bf16(ah1, bh1, acc, 0, 0, 0);
    acc = __builtin_amdgcn_mfma_f32_16x16x32_bf16(al0, bh0, acc, 0, 0, 0);
    acc = __builtin_amdgcn_mfma_f32_16x16x32_bf16(al1, bh1, acc, 0, 0, 0);
    acc = __builtin_amdgcn_mfma_f32_16x16x32_bf16(ah0, bl0, acc, 0, 0, 0);
    acc = __builtin_amdgcn_mfma_f32_16x16x32_bf16(ah1, bl1, acc, 0, 0, 0);
    return acc;
}

// ---------------- atom-side projection: wave-per-8-atoms, lane = feature ----------------
__global__ void __launch_bounds__(256) atom_proj_k(
    const float* __restrict__ AF, const float* __restrict__ iw1,
    float* __restrict__ pa, float* __restrict__ qa, float* __restrict__ na, int N) {
    int lane = threadIdx.x & 63;
    int w = __builtin_amdgcn_readfirstlane((int)(threadIdx.x >> 6));
    int abase = blockIdx.x * (4 * APW) + w * APW;
    if (abase >= N) return;

    float accp[APW], accq[APW], nrm[APW];
    #pragma unroll
    for (int a = 0; a < APW; ++a) { accp[a] = 0.f; accq[a] = 0.f; nrm[a] = 0.f; }

    #pragma unroll 4
    for (int k = 0; k < HDIM; k += 4) {
        float wt[4], wb[4];
        #pragma unroll
        for (int kk = 0; kk < 4; ++kk) {
            wt[kk] = iw1[(size_t)(k + kk) * DDIM + lane];
            wb[kk] = iw1[(size_t)(HDIM + k + kk) * DDIM + lane];
        }
        #pragma unroll
        for (int a = 0; a < APW; ++a) {
            int aa = min(abase + a, N - 1);           // wave-uniform
            float4 hv = ld4(AF + (size_t)aa * HDIM + k);
            accp[a] = fmaf(hv.x, wt[0], accp[a]);
            accp[a] = fmaf(hv.y, wt[1], accp[a]);
            accp[a] = fmaf(hv.z, wt[2], accp[a]);
            accp[a] = fmaf(hv.w, wt[3], accp[a]);
            accq[a] = fmaf(hv.x, wb[0], accq[a]);
            accq[a] = fmaf(hv.y, wb[1], accq[a]);
            accq[a] = fmaf(hv.z, wb[2], accq[a]);
            accq[a] = fmaf(hv.w, wb[3], accq[a]);
            nrm[a] = fmaf(hv.x, hv.x, nrm[a]);
            nrm[a] = fmaf(hv.y, hv.y, nrm[a]);
            nrm[a] = fmaf(hv.z, hv.z, nrm[a]);
            nrm[a] = fmaf(hv.w, hv.w, nrm[a]);
        }
    }
    #pragma unroll
    for (int a = 0; a < APW; ++a) {
        int atom = abase + a;
        if (atom < N) {
            pa[(size_t)atom * DDIM + lane] = accp[a];
            qa[(size_t)atom * DDIM + lane] = accq[a];
            if (lane == 0) na[atom] = sqrtf(nrm[a]);
        }
    }
}

// ---------------- bond init (MFMA version, 512 threads) ----------------
// 512 threads = 8 waves, block = 64 bonds.
// P0: (dl=tid>>3, q=tid&7): h = silu(pa[r]+qa[c]+b1) -> hi/lo LDS; dot via shfl.
// P1: x = h@iw2 + b2 (MFMA); store fp32 x; stage x hi/lo.
// P2: pd = x@mw1_l0[0:64] (fp32), ps = bf16(x@mw1_l0[64:128]).
__global__ void __launch_bounds__(512, 4) bond_init2_k(
    const float* __restrict__ AF, const int* __restrict__ row, const int* __restrict__ col,
    const float* __restrict__ pa, const float* __restrict__ qa, const float* __restrict__ na,
    const float* __restrict__ b1, const uint4* __restrict__ fW2, const float* __restrict__ b2,
    const uint4* __restrict__ fP0,
    float* __restrict__ x, int* __restrict__ bt,
    float* __restrict__ pd, uint4* __restrict__ ps, int E) {
    __shared__ uint4 sAhi[512];   // h, then ps staging (hi)
    __shared__ uint4 sAlo[512];   //                    (lo)
    __shared__ uint4 sXhi[512];   // x                  (hi)
    __shared__ uint4 sXlo[512];   //                    (lo)
    int nEB = (E + EPB - 1) / EPB;
    int lb = xcd_logical_block();
    if (lb >= nEB) return;
    int tid = threadIdx.x;
    int lane = tid & 63;
    int w = __builtin_amdgcn_readfirstlane((int)(tid >> 6));   // 0..7
    int e0 = lb * EPB;

    // ---- P0: gather atoms, silu, classify ----
    {
        int dl = tid >> 3, q = tid & 7;
        int d = e0 + dl;
        bool ok = d < E;
        int dd = ok ? d : 0;
        int r = row[dd], c = col[dd];
        int jq = q * 8;

        // dot partial over AF[.][16q .. 16q+16)
        const float* hi = AF + (size_t)r * HDIM + q * 16;
        const float* hj = AF + (size_t)c * HDIM + q * 16;
        float dt = 0.f;
        #pragma unroll
        for (int k = 0; k < 16; k += 4) {
            float4 a4 = ld4(hi + k), b4 = ld4(hj + k);
            dt += a4.x * b4.x + a4.y * b4.y + a4.z * b4.z + a4.w * b4.w;
        }
        // reduce across the 8 lanes of this bond
        dt += __shfl_xor(dt, 1, 64);
        dt += __shfl_xor(dt, 2, 64);
        dt += __shfl_xor(dt, 4, 64);
        if (q == 0 && ok) {
            float nr = fmaxf(na[r], 1e-8f), nc = fmaxf(na[c], 1e-8f);
            float sim = dt / (nr * nc);
            int t = 0;
            if (sim > 0.8f) t = 1;
            if (sim > 0.9f) t = 2;
            if (sim < 0.3f) t = 3;
            bt[d] = t;
        }

        // h slice = silu(pa[r] + qa[c] + b1)
        const float* pr = pa + (size_t)r * DDIM + jq;
        const float* qc = qa + (size_t)c * DDIM + jq;
        float4 p0 = ld4(pr + 0), p1 = ld4(pr + 4);
        float4 q0 = ld4(qc + 0), q1 = ld4(qc + 4);
        float hv[8];
        hv[0] = silu_f(p0.x + q0.x + b1[jq + 0]);
        hv[1] = silu_f(p0.y + q0.y + b1[jq + 1]);
        hv[2] = silu_f(p0.z + q0.z + b1[jq + 2]);
        hv[3] = silu_f(p0.w + q0.w + b1[jq + 3]);
        hv[4] = silu_f(p1.x + q1.x + b1[jq + 4]);
        hv[5] = silu_f(p1.y + q1.y + b1[jq + 5]);
        hv[6] = silu_f(p1.z + q1.z + b1[jq + 6]);
        hv[7] = silu_f(p1.w + q1.w + b1[jq + 7]);
        if (!ok) {
            #pragma unroll
            for (int i = 0; i < 8; ++i) hv[i] = 0.f;
        }
        uint4 h4, l4;
        hilo8(hv, h4, l4);
        int si = slotIdx(dl, q);
        sAhi[si] = h4; sAlo[si] = l4;
    }
    // preload W2 frags (independent of LDS; overlaps barrier wait)
    int jt = w & 3, mh = w >> 2;
    short8 W2h0, W2h1, W2l0, W2l1;
    loadB(fW2, jt, lane, W2h0, W2h1, W2l0, W2l1);
    __syncthreads();

    // ---- P1: x = h@iw2 + b2 ----
    int rb0 = mh * 32, rb1 = mh * 32 + 16;
    f32x4 z4 = {0.f, 0.f, 0.f, 0.f};
    f32x4 acc0 = gemm_tile(sAhi, sAlo, rb0, lane, W2h0, W2h1, W2l0, W2l1, z4);
    f32x4 acc1 = gemm_tile(sAhi, sAlo, rb1, lane, W2h0, W2h1, W2l0, W2l1, z4);
    int j = jt * 16 + (lane & 15);
    float b2j = b2[j];
    unsigned short* hX = (unsigned short*)sXhi;
    unsigned short* lX = (unsigned short*)sXlo;
    #pragma unroll
    for (int r = 0; r < 4; ++r) {
        int rowi = rb0 + (lane >> 4) * 4 + r;
        int e = e0 + rowi;
        float xn = acc0[r] + b2j;
        if (e < E) x[(size_t)e * DDIM + j] = xn;
        unsigned int hb = bf16r(xn);
        float lov = xn - __uint_as_float(hb << 16);
        int ui = (rowi * 8 + ((j >> 3) ^ (rowi & 7))) * 8 + (j & 7);
        hX[ui] = (unsigned short)hb;
        lX[ui] = (unsigned short)bf16r(lov);
    }
    #pragma unroll
    for (int r = 0; r < 4; ++r) {
        int rowi = rb1 + (lane >> 4) * 4 + r;
        int e = e0 + rowi;
        float xn = acc1[r] + b2j;
        if (e < E) x[(size_t)e * DDIM + j] = xn;
        unsigned int hb = bf16r(xn);
        float lov = xn - __uint_as_float(hb << 16);
        int ui = (rowi * 8 + ((j >> 3) ^ (rowi & 7))) * 8 + (j & 7);
        hX[ui] = (unsigned short)hb;
        lX[ui] = (unsigned short)bf16r(lov);
    }
    __syncthreads();    // x staged; P1 h-reads done before P2 sA-writes

    // ---- P2: layer-0 proj. wave w -> 16-col strip of 128-wide output.
    const uint4* fPw = (w < 4) ? fP0 : (fP0 + 1024);
    int jp = w & 3;
    short8 Ph0, Ph1, Pl0, Pl1;
    loadB(fPw, jp, lane, Ph0, Ph1, Pl0, Pl1);
    f32x4 q0 = gemm_tile(sXhi, sXlo, 0,  lane, Ph0, Ph1, Pl0, Pl1, z4);
    f32x4 q1 = gemm_tile(sXhi, sXlo, 16, lane, Ph0, Ph1, Pl0, Pl1, z4);
    f32x4 q2 = gemm_tile(sXhi, sXlo, 32, lane, Ph0, Ph1, Pl0, Pl1, z4);
    f32x4 q3 = gemm_tile(sXhi, sXlo, 48, lane, Ph0, Ph1, Pl0, Pl1, z4);
    unsigned short* hA = (unsigned short*)sAhi;
    if (w < 4) {
        int jd = jp * 16 + (lane & 15);
        #pragma unroll
        for (int mt = 0; mt < 4; ++mt) {
            f32x4 qq = (mt == 0) ? q0 : (mt == 1) ? q1 : (mt == 2) ? q2 : q3;
            #pragma unroll
            for (int r = 0; r < 4; ++r) {
                int rowi = mt * 16 + (lane >> 4) * 4 + r;
                int e = e0 + rowi;
                if (e < E) pd[(size_t)e * DDIM + jd] = qq[r];
            }
        }
    } else {
        int js = jp * 16 + (lane & 15);
        #pragma unroll
        for (int mt = 0; mt < 4; ++mt) {
            f32x4 qq = (mt == 0) ? q0 : (mt == 1) ? q1 : (mt == 2) ? q2 : q3;
            #pragma unroll
            for (int r = 0; r < 4; ++r) {
                int rowi = mt * 16 + (lane >> 4) * 4 + r;
                int ui = (rowi * 8 + ((js >> 3) ^ (rowi & 7))) * 8 + (js & 7);
                hA[ui] = (unsigned short)bf16r(qq[r]);
            }
        }
    }
    __syncthreads();
    {
        int dl = tid >> 3, q = tid & 7;
        int d = e0 + dl;
        if (d < E) ps[(size_t)d * 8 + q] = sAhi[slotIdx(dl, q)];
    }
}

// proj (x from global) — fallback path only (used if ws too small for pd2/ps2)
__global__ void __launch_bounds__(256) proj_k(const float* __restrict__ x,
                                              const float* __restrict__ w1 /*[192][64]*/,
                                              float* __restrict__ pd, uint4* __restrict__ ps,
                                              int E) {
    int lane = threadIdx.x & 63;
    int w = __builtin_amdgcn_readfirstlane((int)(threadIdx.x >> 6));
    int e = blockIdx.x * EPB + lane;
    bool ok = e < E;
    int eidx = ok ? e : 0;
    int j0 = w * 16;
    const float* xr = x + (size_t)eidx * DDIM;

    float apd[16], aps[16];
    #pragma unroll
    for (int jj = 0; jj < 16; ++jj) { apd[jj] = 0.f; aps[jj] = 0.f; }
    #pragma unroll 2
    for (int c = 0; c < 16; ++c) {
        float4 v = ld4(xr + c * 4);
        float xv[4] = {v.x, v.y, v.z, v.w};
        #pragma unroll
        for (int kk = 0; kk < 4; ++kk) {
            int k = c * 4 + kk;
            const float* wd = w1 + (size_t)k * DDIM + j0;
            const float* wsv = w1 + (size_t)(DDIM + k) * DDIM + j0;
            #pragma unroll
            for (int jj = 0; jj < 16; ++jj) {
                apd[jj] = fmaf(xv[kk], wd[jj], apd[jj]);
                aps[jj] = fmaf(xv[kk], wsv[jj], aps[jj]);
            }
        }
    }
    if (ok) {
        float* pr = pd + (size_t)e * DDIM + j0;
        st4(pr + 0,  make_float4(apd[0],  apd[1],  apd[2],  apd[3]));
        st4(pr + 4,  make_float4(apd[4],  apd[5],  apd[6],  apd[7]));
        st4(pr + 8,  make_float4(apd[8],  apd[9],  apd[10], apd[11]));
        st4(pr + 12, make_float4(apd[12], apd[13], apd[14], apd[15]));
        ps[(size_t)e * 8 + 2 * w + 0] = pack8(aps + 0);
        ps[(size_t)e * 8 + 2 * w + 1] = pack8(aps + 8);
    }
}

// ---------------- fused gather + update (+ optional next-layer proj), 512 threads ----
// P1: gather s (bf16 ps, fp32 acc) -> inv-scaled hi/lo bf16 in LDS; stage x hi/lo.
// P2: h = silu((inv*s)@W2u + x@Uw1b + ub1 + degflag*b2u)
// P3: xnew = x(LDS hi+lo) + h@Uw2 + ub2; store; stage xnew hi/lo
// P4 (layer0): pdn = xnew@W1d (fp32); psn = bf16(xnew@W1s)
// D layout (m89-verified): col = lane&15, row = (lane>>4)*4 + reg.
__global__ void __launch_bounds__(512, 4) layer_k(
    float* __restrict__ x, const float* __restrict__ pd, const uint4* __restrict__ ps,
    const float* __restrict__ tt_l, const int* __restrict__ bt,
    const int* __restrict__ offs, const int* __restrict__ srclist,
    const int* __restrict__ cnt,
    const uint4* __restrict__ fW2u, const float* __restrict__ b2u,
    const uint4* __restrict__ fU1b, const float* __restrict__ ub1,
    const uint4* __restrict__ fU2, const float* __restrict__ ub2,
    const uint4* __restrict__ fP /* next-layer proj frags or nullptr */,
    float* __restrict__ pdn, uint4* __restrict__ psn, int E) {
    __shared__ uint4 sAhi[512];   // s / h / psn-staging  (hi)
    __shared__ uint4 sAlo[512];   //                      (lo)
    __shared__ uint4 sXhi[512];   // x / xnew             (hi)
    __shared__ uint4 sXlo[512];   //                      (lo)
    __shared__ float degLDS[64];  // 1.0 if deg>0 else 0.0
    int nEB = (E + EPB - 1) / EPB;
    int lb = xcd_logical_block();
    if (lb >= nEB) return;
    int tid = threadIdx.x;
    int lane = tid & 63;
    int w = __builtin_amdgcn_readfirstlane((int)(tid >> 6));   // 0..7
    int e0 = lb * EPB;

    // ---- P1: stage x + gather (8 threads per bond, 8 features each) ----
    {
        int dl = tid >> 3, q = tid & 7;
        int d = e0 + dl;
        bool ok = d < E;
        int dd = ok ? d : 0;
        int jq = q * 8;
        const float* xr = x + (size_t)dd * DDIM + jq;
        float4 xv0 = ld4(xr + 0), xv1 = ld4(xr + 4);   // issued early, used late
        int dc = cnt[dd];
        const float* pr = pd + (size_t)dd * DDIM + jq;
        const float* tp = tt_l + (size_t)bt[dd] * DDIM + jq;
        float4 b0 = add4(ld4(pr + 0), ld4(tp + 0));
        float4 b1 = add4(ld4(pr + 4), ld4(tp + 4));
        float4 s0 = make_float4(0, 0, 0, 0), s1 = s0;
        int p0 = ok ? offs[d] : 0, p1 = ok ? offs[d + 1] : 0;
        int p = p0;
        for (; p + 4 <= p1; p += 4) {
            uint4 u0 = ps[(size_t)srclist[p + 0] * 8 + q];
            uint4 u1 = ps[(size_t)srclist[p + 1] * 8 + q];
            uint4 u2 = ps[(size_t)srclist[p + 2] * 8 + q];
            uint4 u3 = ps[(size_t)srclist[p + 3] * 8 + q];
            float4 a, b;
            unpack8(u0, a, b);
            silu_acc4(s0, add4(b0, a));
            silu_acc4(s1, add4(b1, b));
            unpack8(u1, a, b);
            silu_acc4(s0, add4(b0, a));
            silu_acc4(s1, add4(b1, b));
            unpack8(u2, a, b);
            silu_acc4(s0, add4(b0, a));
            silu_acc4(s1, add4(b1, b));
            unpack8(u3, a, b);
            silu_acc4(s0, add4(b0, a));
            silu_acc4(s1, add4(b1, b));
        }
        for (; p < p1; ++p) {
            uint4 u0 = ps[(size_t)srclist[p] * 8 + q];
            float4 a, b;
            unpack8(u0, a, b);
            silu_acc4(s0, add4(b0, a));
            silu_acc4(s1, add4(b1, b));
        }
        float inv = 1.0f / fmaxf((float)dc, 1.0f);
        float sv[8] = {s0.x * inv, s0.y * inv, s0.z * inv, s0.w * inv,
                       s1.x * inv, s1.y * inv, s1.z * inv, s1.w * inv};
        float xf[8] = {xv0.x, xv0.y, xv0.z, xv0.w, xv1.x, xv1.y, xv1.z, xv1.w};
        if (!ok) {
            #pragma unroll
            for (int i = 0; i < 8; ++i) { sv[i] = 0.f; xf[i] = 0.f; }
        }
        uint4 h4, l4;
        int si = slotIdx(dl, q);
        hilo8(sv, h4, l4);
        sAhi[si] = h4; sAlo[si] = l4;
        hilo8(xf, h4, l4);
        sXhi[si] = h4; sXlo[si] = l4;
        if (q == 0) degLDS[dl] = (ok && dc > 0) ? 1.0f : 0.0f;
    }
    // preload loop-invariant B-frags (independent of LDS; overlaps barrier wait)
    int jt = w & 3, mh = w >> 2;
    short8 A2h0, A2h1, A2l0, A2l1;   // W2u
    short8 U1h0, U1h1, U1l0, U1l1;   // Uw1b
    loadB(fW2u, jt, lane, A2h0, A2h1, A2l0, A2l1);
    loadB(fU1b, jt, lane, U1h0, U1h1, U1l0, U1l1);
    __syncthreads();

    // ---- P2: h = silu((inv*s)@W2u + x@Uw1b + bias) ----
    int rb0 = mh * 32, rb1 = mh * 32 + 16;
    f32x4 z4 = {0.f, 0.f, 0.f, 0.f};
    f32x4 acc0 = z4, acc1 = z4;
    acc0 = gemm_tile(sAhi, sAlo, rb0, lane, A2h0, A2h1, A2l0, A2l1, acc0);
    acc0 = gemm_tile(sXhi, sXlo, rb0, lane, U1h0, U1h1, U1l0, U1l1, acc0);
    acc1 = gemm_tile(sAhi, sAlo, rb1, lane, A2h0, A2h1, A2l0, A2l1, acc1);
    acc1 = gemm_tile(sXhi, sXlo, rb1, lane, U1h0, U1h1, U1l0, U1l1, acc1);
    __syncthreads();                       // all s/x fragment reads done
    int j = jt * 16 + (lane & 15);
    float ub1j = ub1[j], b2uj = b2u[j];
    unsigned short* hA = (unsigned short*)sAhi;
    unsigned short* lA = (unsigned short*)sAlo;
    #pragma unroll
    for (int r = 0; r < 4; ++r) {
        int row = rb0 + (lane >> 4) * 4 + r;
        float hv = silu_f(acc0[r] + ub1j + degLDS[row] * b2uj);
        unsigned int hb = bf16r(hv);
        float lov = hv - __uint_as_float(hb << 16);
        int ui = (row * 8 + ((j >> 3) ^ (row & 7))) * 8 + (j & 7);
        hA[ui] = (unsigned short)hb;
        lA[ui] = (unsigned short)bf16r(lov);
    }
    #pragma unroll
    for (int r = 0; r < 4; ++r) {
        int row = rb1 + (lane >> 4) * 4 + r;
        float hv = silu_f(acc1[r] + ub1j + degLDS[row] * b2uj);
        unsigned int hb = bf16r(hv);
        float lov = hv - __uint_as_float(hb << 16);
        int ui = (row * 8 + ((j >> 3) ^ (row & 7))) * 8 + (j & 7);
        hA[ui] = (unsigned short)hb;
        lA[ui] = (unsigned short)bf16r(lov);
    }
    __syncthreads();                       // h staged

    // ---- P3: o = h@Uw2 + ub2; xnew = x(LDS) + o ----
    short8 U2h0, U2h1, U2l0, U2l1;
    loadB(fU2, jt, lane, U2h0, U2h1, U2l0, U2l1);
    f32x4 o0 = gemm_tile(sAhi, sAlo, rb0, lane, U2h0, U2h1, U2l0, U2l1, z4);
    f32x4 o1 = gemm_tile(sAhi, sAlo, rb1, lane, U2h0, U2h1, U2l0, U2l1, z4);
    float ub2j = ub2[j];
    bool haveP = (fP != nullptr);
    unsigned short* hX = (unsigned short*)sXhi;
    unsigned short* lX = (unsigned short*)sXlo;
    #pragma unroll
    for (int r = 0; r < 4; ++r) {
        int row = rb0 + (lane >> 4) * 4 + r;
        int e = e0 + row;
        int ui = (row * 8 + ((j >> 3) ^ (row & 7))) * 8 + (j & 7);
        float xvv = __uint_as_float((unsigned int)hX[ui] << 16)
                  + __uint_as_float((unsigned int)lX[ui] << 16);
        float xn = xvv + o0[r] + ub2j;
        if (e < E) x[(size_t)e * DDIM + j] = xn;
        if (haveP) {
            unsigned int hb = bf16r(xn);
            float lov = xn - __uint_as_float(hb << 16);
            hX[ui] = (unsigned short)hb;
            lX[ui] = (unsigned short)bf16r(lov);
        }
    }
    #pragma unroll
    for (int r = 0; r < 4; ++r) {
        int row = rb1 + (lane >> 4) * 4 + r;
        int e = e0 + row;
        int ui = (row * 8 + ((j >> 3) ^ (row & 7))) * 8 + (j & 7);
        float xvv = __uint_as_float((unsigned int)hX[ui] << 16)
                  + __uint_as_float((unsigned int)lX[ui] << 16);
        float xn = xvv + o1[r] + ub2j;
        if (e < E) x[(size_t)e * DDIM + j] = xn;
        if (haveP) {
            unsigned int hb = bf16r(xn);
            float lov = xn - __uint_as_float(hb << 16);
            hX[ui] = (unsigned short)hb;
            lX[ui] = (unsigned short)bf16r(lov);
        }
    }
    if (!haveP) return;
    __syncthreads();    // xnew staged; orders P3 A-reads before P4 A-writes

    // ---- P4: next-layer proj. wave w -> 16-col strip of the 128-wide output.
    const uint4* fPw = (w < 4) ? fP : (fP + 1024);
    int jp = w & 3;
    short8 Ph0, Ph1, Pl0, Pl1;
    loadB(fPw, jp, lane, Ph0, Ph1, Pl0, Pl1);
    f32x4 q0 = gemm_tile(sXhi, sXlo, 0,  lane, Ph0, Ph1, Pl0, Pl1, z4);
    f32x4 q1 = gemm_tile(sXhi, sXlo, 16, lane, Ph0, Ph1, Pl0, Pl1, z4);
    f32x4 q2 = gemm_tile(sXhi, sXlo, 32, lane, Ph0, Ph1, Pl0, Pl1, z4);
    f32x4 q3 = gemm_tile(sXhi, sXlo, 48, lane, Ph0, Ph1, Pl0, Pl1, z4);
    if (w < 4) {
        // pdn (fp32), cols jp*16 + (lane&15)
        int jd = jp * 16 + (lane & 15);
        #pragma unroll
        for (int mt = 0; mt < 4; ++mt) {
            f32x4 qq = (mt == 0) ? q0 : (mt == 1) ? q1 : (mt == 2) ? q2 : q3;
            #pragma unroll
            for (int r = 0; r < 4; ++r) {
                int row = mt * 16 + (lane >> 4) * 4 + r;
                int e = e0 + row;
                if (e < E) pdn[(size_t)e * DDIM + jd] = qq[r];
            }
        }
    } else {
        // psn (bf16): stage into sAhi rows then repack as uint4
        int js = jp * 16 + (lane & 15);
        #pragma unroll
        for (int mt = 0; mt < 4; ++mt) {
            f32x4 qq = (mt == 0) ? q0 : (mt == 1) ? q1 : (mt == 2) ? q2 : q3;
            #pragma unroll
            for (int r = 0; r < 4; ++r) {
                int row = mt * 16 + (lane >> 4) * 4 + r;
                int ui = (row * 8 + ((js >> 3) ^ (row & 7))) * 8 + (js & 7);
                hA[ui] = (unsigned short)bf16r(qq[r]);
            }
        }
    }
    __syncthreads();
    {
        int dl = tid >> 3, q = tid & 7;
        int d = e0 + dl;
        if (d < E) psn[(size_t)d * 8 + q] = sAhi[slotIdx(dl, q)];
    }
}

// ---------------- pooling ----------------
__global__ void __launch_bounds__(256) pool_k(
    const float* __restrict__ x, const int* __restrict__ row,
    const int* __restrict__ batch, float* __restrict__ gfeat, int E) {
    int lane = threadIdx.x & 63;
    int esub = threadIdx.x >> 6;       // 0..3
    int e0 = blockIdx.x * PCHUNK;
    int e1 = min(e0 + PCHUNK, E);
    float sum = 0.f;
    int cur = -1;
    for (int e = e0 + esub; e < e1; e += 4) {
        int g = batch[row[e]];         // wave-uniform -> scalar load
        if (g != cur) {
            if (cur >= 0)
                __hip_atomic_fetch_add(&gfeat[cur * DDIM + lane], sum,
                                       __ATOMIC_RELAXED, __HIP_MEMORY_SCOPE_AGENT);
            cur = g;
            sum = 0.f;
        }
        sum += x[(size_t)e * DDIM + lane];
    }
    if (cur >= 0)
        __hip_atomic_fetch_add(&gfeat[cur * DDIM + lane], sum,
                               __ATOMIC_RELAXED, __HIP_MEMORY_SCOPE_AGENT);
}

static __device__ __forceinline__ int lower_bound_bb(const int* __restrict__ row,
                                                     const int* __restrict__ batch,
                                                     int E, int g) {
    int lo = 0, hi = E;
    while (lo < hi) {
        int m = (lo + hi) >> 1;
        if (batch[row[m]] < g) lo = m + 1; else hi = m;
    }
    return lo;
}

__global__ void __launch_bounds__(64) pool_final_k(
    const int* __restrict__ row, const int* __restrict__ batch,
    float* __restrict__ gfeat, int E) {
    int g = blockIdx.x, j = threadIdx.x;
    int s = lower_bound_bb(row, batch, E, g);
    int t = lower_bound_bb(row, batch, E, g + 1);
    float cnt = fmaxf((float)(t - s), 1.0f);
    gfeat[g * DDIM + j] /= cnt;
}

extern "C" void kernel_launch(void* const* d_in, const int* in_sizes, int n_in,
                              void* d_out, int out_size, void* d_ws, size_t ws_size,
                              hipStream_t stream) {
    (void)n_in; (void)out_size;
    const float* AF    = (const float*)d_in[0];
    const int*   batch = (const int*)d_in[3];
    const int*   edge_index      = (const int*)d_in[4];
    const int*   bond_edge_index = (const int*)d_in[5];
    const float* iw1 = (const float*)d_in[6];
    const float* ib1 = (const float*)d_in[7];
    const float* iw2 = (const float*)d_in[8];
    const float* ib2 = (const float*)d_in[9];
    const float* emb = (const float*)d_in[10];
    const float* mw1 = (const float*)d_in[11];
    const float* mb1 = (const float*)d_in[12];
    const float* mw2 = (const float*)d_in[13];
    const float* mb2 = (const float*)d_in[14];
    const float* uw1 = (const float*)d_in[15];
    const float* ub1 = (const float*)d_in[16];
    const float* uw2 = (const float*)d_in[17];
    const float* ub2 = (const float*)d_in[18];

    const int N  = in_sizes[0] / HDIM;
    const int E  = in_sizes[4] / 2;
    const int BE = in_sizes[5] / 2;
    const int NB = (E + 255) / 256;
    const int EB = (E + EPB - 1) / EPB;
    const int AB = (N + 4 * APW - 1) / (4 * APW);   // atom blocks (32 atoms/block)
    const int EBS = ((EB + 7) / 8) * 8;             // swizzled grid (multiple of 8)
    const int PB = (E + PCHUNK - 1) / PCHUNK;       // pooling blocks

    float* xout  = (float*)d_out;                 // [E,64]
    float* gfeat = xout + (size_t)E * DDIM;       // [16,64]

    // workspace layout
    char* w = (char*)d_ws;
    float* tt       = (float*)w;  w += sizeof(float) * 2 * NTYPES * DDIM;
    float* b2u      = (float*)w;  w += sizeof(float) * 2 * DDIM;
    w = (char*)(((uintptr_t)w + 15) & ~(uintptr_t)15);
    // MFMA weight fragments (hi/lo bf16)
    uint4* fW2u     = (uint4*)w;  w += 2048 * sizeof(uint4);
    uint4* fU1b     = (uint4*)w;  w += 2048 * sizeof(uint4);
    uint4* fU2      = (uint4*)w;  w += 2048 * sizeof(uint4);
    uint4* fP       = (uint4*)w;  w += 2048 * sizeof(uint4);
    uint4* fIw2     = (uint4*)w;  w += 1024 * sizeof(uint4);
    uint4* fP0      = (uint4*)w;  w += 2048 * sizeof(uint4);
    int*   cnt      = (int*)w;    w += sizeof(int) * E;
    int*   offs     = (int*)w;    w += sizeof(int) * (E + 1);
    int*   cursor   = (int*)w;    w += sizeof(int) * E;
    int*   bt       = (int*)w;    w += sizeof(int) * E;
    int*   bsum     = (int*)w;    w += sizeof(int) * 1024;
    int*   bpre     = (int*)w;    w += sizeof(int) * 1024;
    int*   srclist  = (int*)w;    w += sizeof(int) * BE;
    w = (char*)(((uintptr_t)w + 15) & ~(uintptr_t)15);
    float* pd       = (float*)w;  w += sizeof(float) * (size_t)E * DDIM;
    uint4* ps       = (uint4*)w;  w += sizeof(unsigned short) * (size_t)E * DDIM;
    float* pa       = (float*)w;  w += sizeof(float) * (size_t)N * DDIM;
    float* qa       = (float*)w;  w += sizeof(float) * (size_t)N * DDIM;
    float* na       = (float*)w;  w += sizeof(float) * (size_t)N;
    w = (char*)(((uintptr_t)w + 15) & ~(uintptr_t)15);
    // optional second proj buffers (fused-proj path)
    float* pd2      = (float*)w;  w += sizeof(float) * (size_t)E * DDIM;
    uint4* ps2      = (uint4*)w;  w += sizeof(unsigned short) * (size_t)E * DDIM;
    bool fuse_proj = ((size_t)(w - (char*)d_ws) <= ws_size);

    const int* row  = edge_index;
    const int* col  = edge_index + E;
    const int* bsrc = bond_edge_index;
    const int* bdst = bond_edge_index + BE;

    // CSR build
    hipMemsetAsync(cnt, 0, (size_t)E * sizeof(int), stream);
    count_k<<<(BE + 255) / 256, 256, 0, stream>>>(bdst, cnt, BE);
    bsum_k<<<NB, 256, 0, stream>>>(cnt, bsum, E);
    bscan_k<<<1, 1024, 0, stream>>>(bsum, bpre, NB);
    offs_k<<<NB, 256, 0, stream>>>(cnt, bpre, offs, cursor, E);
    scatter_k<<<(BE + 255) / 256, 256, 0, stream>>>(bsrc, bdst, cursor, srclist, BE);

    // constants: tt + b2u + all MFMA B-fragments in one launch
    prep_k<<<100, 64, 0, stream>>>(emb, mw1, mb1, mw2, mb2, uw1, uw2, iw2,
                                   tt, b2u, fW2u, fU1b, fU2, fP, fIw2, fP0);

    // atom projections, then bond init + layer-0 proj (MFMA)
    atom_proj_k<<<AB, 256, 0, stream>>>(AF, iw1, pa, qa, na, N);
    bond_init2_k<<<EBS, 512, 0, stream>>>(AF, row, col, pa, qa, na, ib1, fIw2, ib2,
                                          fP0, xout, bt, pd, ps, E);

    if (fuse_proj) {
        // layer 0: fused next-layer proj -> pd2/ps2
        layer_k<<<EBS, 512, 0, stream>>>(
            xout, pd, ps, tt, bt, offs, srclist, cnt,
            fW2u, b2u, fU1b, ub1, fU2, ub2,
            fP, pd2, ps2, E);
        // layer 1: no proj
        layer_k<<<EBS, 512, 0, stream>>>(
            xout, pd2, ps2, tt + NTYPES * DDIM, bt, offs, srclist, cnt,
            fW2u + 1024, b2u + DDIM, fU1b + 1024, ub1 + DDIM,
            fU2 + 1024, ub2 + DDIM,
            nullptr, nullptr, nullptr, E);
    } else {
        for (int l = 0; l < 2; ++l) {
            if (l > 0)
                proj_k<<<EB, 256, 0, stream>>>(xout, mw1 + (size_t)l * 192 * 64, pd, ps, E);
            layer_k<<<EBS, 512, 0, stream>>>(
                xout, pd, ps, tt + (size_t)l * NTYPES * DDIM, bt, offs, srclist, cnt,
                fW2u + (size_t)l * 1024, b2u + (size_t)l * DDIM,
                fU1b + (size_t)l * 1024, ub1 + (size_t)l * DDIM,
                fU2 + (size_t)l * 1024, ub2 + (size_t)l * DDIM,
                nullptr, nullptr, nullptr, E);
        }
    }

    hipMemsetAsync(gfeat, 0, NGRAPHS * DDIM * sizeof(float), stream);
    pool_k<<<PB, 256, 0, stream>>>(xout, row, batch, gfeat, E);
    pool_final_k<<<NGRAPHS, 64, 0, stream>>>(row, batch, gfeat, E);
}

// Round 5
// 285.256 us; speedup vs baseline: 1.1341x; 1.1051x over previous
//
#include <hip/hip_runtime.h>
#include <cstdint>
#include <cstddef>

#define HDIM 128
#define DDIM 64
#define NTYPES 5
#define NGRAPHS 16
#define EPB 64       // edges per block (one per lane)
#define SCAP 1024    // srclist LDS prefetch capacity (per 64-bond block)

typedef __attribute__((ext_vector_type(8))) short short8;   // 8 bf16
typedef __attribute__((ext_vector_type(4))) float f32x4;

static __device__ __forceinline__ short8 as_s8(uint4 u) {
    return __builtin_bit_cast(short8, u);
}

// fast silu: v_rcp_f32 (rel err ~1e-7) instead of precise-division sequence
static __device__ __forceinline__ float silu_f(float v) {
    return v * __builtin_amdgcn_rcpf(1.0f + __expf(-v));
}

static __device__ __forceinline__ float4 ld4(const float* p) {
    return *reinterpret_cast<const float4*>(p);
}

static __device__ __forceinline__ void st4(float* p, float4 v) {
    *reinterpret_cast<float4*>(p) = v;
}

static __device__ __forceinline__ float4 add4(float4 a, float4 b) {
    return make_float4(a.x + b.x, a.y + b.y, a.z + b.z, a.w + b.w);
}

static __device__ __forceinline__ void silu_acc4(float4& s, float4 v) {
    s.x += silu_f(v.x);
    s.y += silu_f(v.y);
    s.z += silu_f(v.z);
    s.w += silu_f(v.w);
}

// ---- bf16 pack/unpack (RNE; feature j0+0 in low half) ----
static __device__ __forceinline__ unsigned int bf16r(float f) {
    unsigned int u = __float_as_uint(f);
    return (u + 0x7FFFu + ((u >> 16) & 1u)) >> 16;
}
// HW packed RNE convert: dst = bf16(a) | bf16(b)<<16  (T12 recipe; no builtin on gfx950)
static __device__ __forceinline__ unsigned int cvtpk(float a, float b) {
    unsigned int r;
    asm("v_cvt_pk_bf16_f32 %0, %1, %2" : "=v"(r) : "v"(a), "v"(b));
    return r;
}
static __device__ __forceinline__ uint4 pack8(const float* f) {
    uint4 r;
    r.x = cvtpk(f[0], f[1]);
    r.y = cvtpk(f[2], f[3]);
    r.z = cvtpk(f[4], f[5]);
    r.w = cvtpk(f[6], f[7]);
    return r;
}
static __device__ __forceinline__ void unpack8(uint4 u, float4& a, float4& b) {
    a.x = __uint_as_float(u.x << 16);
    a.y = __uint_as_float(u.x & 0xFFFF0000u);
    a.z = __uint_as_float(u.y << 16);
    a.w = __uint_as_float(u.y & 0xFFFF0000u);
    b.x = __uint_as_float(u.z << 16);
    b.y = __uint_as_float(u.z & 0xFFFF0000u);
    b.z = __uint_as_float(u.w << 16);
    b.w = __uint_as_float(u.w & 0xFFFF0000u);
}

// split fp32 -> bf16 hi + bf16 lo (lo = v - float(hi)); hi+lo ~ 16 mantissa bits
static __device__ __forceinline__ void hilo8(const float* f, uint4& h, uint4& lo) {
    h = pack8(f);
    float4 a, b;
    unpack8(h, a, b);
    lo.x = cvtpk(f[0] - a.x, f[1] - a.y);
    lo.y = cvtpk(f[2] - a.z, f[3] - a.w);
    lo.z = cvtpk(f[4] - b.x, f[5] - b.y);
    lo.w = cvtpk(f[6] - b.z, f[7] - b.w);
}

// XCD-affinity swizzle (heuristic blk%8 -> XCD round-robin)
static __device__ __forceinline__ int xcd_logical_block() {
    int chunk = (int)(gridDim.x >> 3);
    return (int)(blockIdx.x & 7) * chunk + (int)(blockIdx.x >> 3);
}

// ---------------- CSR build ----------------
__global__ void __launch_bounds__(256) count_k(const int* __restrict__ bdst,
                                               int* __restrict__ cnt, int BE) {
    int i = blockIdx.x * 256 + threadIdx.x;
    if (i < BE)
        __hip_atomic_fetch_add(&cnt[bdst[i]], 1, __ATOMIC_RELAXED, __HIP_MEMORY_SCOPE_AGENT);
}

__global__ void __launch_bounds__(256) bsum_k(const int* __restrict__ cnt,
                                              int* __restrict__ bsum, int E) {
    __shared__ int red[256];
    int t = threadIdx.x;
    int i = blockIdx.x * 256 + t;
    red[t] = (i < E) ? cnt[i] : 0;
    __syncthreads();
    #pragma unroll
    for (int off = 128; off > 0; off >>= 1) {
        if (t < off) red[t] += red[t + off];
        __syncthreads();
    }
    if (t == 0) bsum[blockIdx.x] = red[0];
}

__global__ void __launch_bounds__(1024) bscan_k(const int* __restrict__ bsum,
                                                int* __restrict__ bpre, int NB) {
    __shared__ int sh[1024];
    int t = threadIdx.x;
    int v0 = (t < NB) ? bsum[t] : 0;
    sh[t] = v0;
    __syncthreads();
    for (int off = 1; off < 1024; off <<= 1) {
        int v = (t >= off) ? sh[t - off] : 0;
        __syncthreads();
        sh[t] += v;
        __syncthreads();
    }
    if (t < NB) bpre[t] = sh[t] - v0;
}

__global__ void __launch_bounds__(256) offs_k(const int* __restrict__ cnt,
                                              const int* __restrict__ bpre,
                                              int* __restrict__ offs,
                                              int* __restrict__ cursor, int E) {
    __shared__ int sh[256];
    int t = threadIdx.x;
    int i = blockIdx.x * 256 + t;
    int v0 = (i < E) ? cnt[i] : 0;
    sh[t] = v0;
    __syncthreads();
    for (int off = 1; off < 256; off <<= 1) {
        int v = (t >= off) ? sh[t - off] : 0;
        __syncthreads();
        sh[t] += v;
        __syncthreads();
    }
    int ex = sh[t] - v0 + bpre[blockIdx.x];
    if (i < E) { offs[i] = ex; cursor[i] = ex; }
    if (i == E - 1) offs[E] = ex + v0;
}

__global__ void __launch_bounds__(256) scatter_k(const int* __restrict__ bsrc,
                                                 const int* __restrict__ bdst,
                                                 int* __restrict__ cursor,
                                                 int* __restrict__ srclist, int BE) {
    int i = blockIdx.x * 256 + threadIdx.x;
    if (i < BE) {
        int d = bdst[i];
        int p = __hip_atomic_fetch_add(&cursor[d], 1, __ATOMIC_RELAXED,
                                       __HIP_MEMORY_SCOPE_AGENT);
        srclist[p] = bsrc[i];
    }
}

// ---------------- merged prep: tt + b2u + all MFMA B-fragment packs ----------------
// B-frag pack layout for mfma_f32_16x16x32_bf16 (B is K32 x N16):
//   lane l holds B[ks*32 + (l>>4)*8 + i][jt*16 + (l&15)], i=0..7, as 8 bf16.
// Buffer index: ((jt*2+ks)*64 + lane)*2 + {0=hi,1=lo}.  One 64x64 matrix = 1024 uint4.
// Blocks 0..9: tt; 10..11: b2u; 12..131: fragment packs (fW2u computed on the fly).
__global__ void __launch_bounds__(64) prep_k(const float* __restrict__ emb,
                                             const float* __restrict__ mw1,
                                             const float* __restrict__ mb1,
                                             const float* __restrict__ mw2,
                                             const float* __restrict__ mb2,
                                             const float* __restrict__ uw1,
                                             const float* __restrict__ uw2,
                                             const float* __restrict__ iw2,
                                             const float* __restrict__ iw1,
                                             float* __restrict__ tt,
                                             float* __restrict__ b2u,
                                             uint4* __restrict__ fw2u,
                                             uint4* __restrict__ fu1b,
                                             uint4* __restrict__ fu2,
                                             uint4* __restrict__ fp,
                                             uint4* __restrict__ fiw2,
                                             uint4* __restrict__ fp0,
                                             uint4* __restrict__ fiw1) {
    int b = blockIdx.x;
    int l = threadIdx.x;
    if (b < 10) {            // tt[l][t] = emb[l][t] @ mw1[l][128:192] + mb1[l]
        int ll = b / NTYPES, t = b % NTYPES;
        const float* embl = emb + (size_t)ll * NTYPES * DDIM + (size_t)t * DDIM;
        const float* w1 = mw1 + (size_t)ll * 192 * DDIM;
        float s = mb1[ll * DDIM + l];
        #pragma unroll 8
        for (int k = 0; k < DDIM; ++k)
            s = fmaf(embl[k], w1[(HDIM + k) * DDIM + l], s);
        tt[(size_t)b * DDIM + l] = s;
        return;
    }
    if (b < 12) {            // b2u[l] = mb2[l] @ uw1[l][0:64]
        int ll = b - 10;
        const float* u1 = uw1 + (size_t)ll * 128 * DDIM;
        float s = 0.f;
        #pragma unroll 8
        for (int t = 0; t < DDIM; ++t)
            s = fmaf(mb2[ll * DDIM + t], u1[(size_t)t * DDIM + l], s);
        b2u[ll * DDIM + l] = s;
        return;
    }
    int pb = b - 12;
    int mat = pb >> 3, jt = (pb >> 1) & 3, ks = pb & 1;
    int k0 = ks * 32 + (l >> 4) * 8;
    int j = jt * 16 + (l & 15);
    float f[8];
    uint4* dst;
    if (mat <= 1) {          // fW2u: w2u[k][j] = mw2[l] @ uw1[l][0:64] on the fly
        const float* w2 = mw2 + (size_t)mat * DDIM * DDIM;
        const float* u1 = uw1 + (size_t)mat * 128 * DDIM;
        #pragma unroll
        for (int i = 0; i < 8; ++i) {
            float s = 0.f;
            #pragma unroll 8
            for (int t = 0; t < DDIM; ++t)
                s = fmaf(w2[(size_t)(k0 + i) * DDIM + t], u1[(size_t)t * DDIM + j], s);
            f[i] = s;
        }
        dst = fw2u + (size_t)mat * 1024;
    } else {
        const float* src;
        switch (mat) {
            case 2:  src = uw1 + 64 * 64;                    dst = fu1b;        break;
            case 3:  src = uw1 + 128 * 64 + 64 * 64;         dst = fu1b + 1024; break;
            case 4:  src = uw2;                              dst = fu2;         break;
            case 5:  src = uw2 + 4096;                       dst = fu2 + 1024;  break;
            case 6:  src = mw1 + (size_t)192 * 64;           dst = fp;          break;
            case 7:  src = mw1 + (size_t)192 * 64 + 64 * 64; dst = fp + 1024;   break;
            case 8:  src = iw2;                              dst = fiw2;        break;
            case 9:  src = mw1;                              dst = fp0;         break;
            case 10: src = mw1 + (size_t)64 * 64;            dst = fp0 + 1024;  break;
            case 11: src = iw1;                              dst = fiw1;        break;  // pa, K 0..63
            case 12: src = iw1 + (size_t)64 * 64;            dst = fiw1 + 1024; break;  // pa, K 64..127
            case 13: src = iw1 + (size_t)128 * 64;           dst = fiw1 + 2048; break;  // qa, K 0..63
            default: src = iw1 + (size_t)192 * 64;           dst = fiw1 + 3072; break;  // qa, K 64..127
        }
        #pragma unroll
        for (int i = 0; i < 8; ++i) f[i] = src[(size_t)(k0 + i) * DDIM + j];
    }
    uint4 h, lo;
    hilo8(f, h, lo);
    size_t di = ((size_t)(jt * 2 + ks) * 64 + l) * 2;
    dst[di] = h;
    dst[di + 1] = lo;
}

// LDS A-tile: [64 rows][8 slots of 16B] bf16, XOR-swizzled within the row so the
// 128B-stride fragment reads don't 16-way bank-conflict (G4).
static __device__ __forceinline__ int slotIdx(int row, int slot) {
    return row * 8 + (slot ^ (row & 7));
}
// K=128 variant: 16 slots/row (XOR flips low 3 bits -> bijective within 16)
static __device__ __forceinline__ int slotIdx16(int row, int slot) {
    return row * 16 + (slot ^ (row & 7));
}

// A-frag (M16 x K32): lane l holds A[rowBase + (l&15)][ks*32 + (l>>4)*8 + i], i=0..7.
static __device__ __forceinline__ short8 ldFragA(const uint4* buf, int rowBase, int lane, int ks) {
    int row = rowBase + (lane & 15);
    int slot = ks * 4 + (lane >> 4);
    return as_s8(buf[slotIdx(row, slot)]);
}
static __device__ __forceinline__ short8 ldFragA16(const uint4* buf, int rowBase, int lane, int slot0) {
    int row = rowBase + (lane & 15);
    int slot = slot0 + (lane >> 4);
    return as_s8(buf[slotIdx16(row, slot)]);
}

static __device__ __forceinline__ void loadB(const uint4* __restrict__ frag, int jt, int lane,
                                             short8& h0, short8& h1, short8& l0, short8& l1) {
    const uint4* p0 = frag + ((size_t)(jt * 2 + 0) * 64 + lane) * 2;
    const uint4* p1 = frag + ((size_t)(jt * 2 + 1) * 64 + lane) * 2;
    h0 = as_s8(p0[0]); l0 = as_s8(p0[1]);
    h1 = as_s8(p1[0]); l1 = as_s8(p1[1]);
}

// one 16x16 output tile, K=64, split-precision: Ahi*Bhi + Alo*Bhi + Ahi*Blo
static __device__ __forceinline__ f32x4 gemm_tile(const uint4* Ahi, const uint4* Alo,
        int rowBase, int lane,
        short8 bh0, short8 bh1, short8 bl0, short8 bl1, f32x4 acc) {
    short8 ah0 = ldFragA(Ahi, rowBase, lane, 0);
    short8 ah1 = ldFragA(Ahi, rowBase, lane, 1);
    short8 al0 = ldFragA(Alo, rowBase, lane, 0);
    short8 al1 = ldFragA(Alo, rowBase, lane, 1);
    acc = __builtin_amdgcn_mfma_f32_16x16x32_bf16(ah0, bh0, acc, 0, 0, 0);
    acc = __builtin_amdgcn_mfma_f32_16x16x32_bf16(ah1, bh1, acc, 0, 0, 0);
    acc = __builtin_amdgcn_mfma_f32_16x16x32_bf16(al0, bh0, acc, 0, 0, 0);
    acc = __builtin_amdgcn_mfma_f32_16x16x32_bf16(al1, bh1, acc, 0, 0, 0);
    acc = __builtin_amdgcn_mfma_f32_16x16x32_bf16(ah0, bl0, acc, 0, 0, 0);
    acc = __builtin_amdgcn_mfma_f32_16x16x32_bf16(ah1, bl1, acc, 0, 0, 0);
    return acc;
}

// same, but over a K=64 half of a K=128-tiled LDS buffer (slot base sb = 0 or 8)
static __device__ __forceinline__ f32x4 gemm_tile16(const uint4* Ahi, const uint4* Alo,
        int rowBase, int lane, int sb,
        short8 bh0, short8 bh1, short8 bl0, short8 bl1, f32x4 acc) {
    short8 ah0 = ldFragA16(Ahi, rowBase, lane, sb + 0);
    short8 ah1 = ldFragA16(Ahi, rowBase, lane, sb + 4);
    short8 al0 = ldFragA16(Alo, rowBase, lane, sb + 0);
    short8 al1 = ldFragA16(Alo, rowBase, lane, sb + 4);
    acc = __builtin_amdgcn_mfma_f32_16x16x32_bf16(ah0, bh0, acc, 0, 0, 0);
    acc = __builtin_amdgcn_mfma_f32_16x16x32_bf16(ah1, bh1, acc, 0, 0, 0);
    acc = __builtin_amdgcn_mfma_f32_16x16x32_bf16(al0, bh0, acc, 0, 0, 0);
    acc = __builtin_amdgcn_mfma_f32_16x16x32_bf16(al1, bh1, acc, 0, 0, 0);
    acc = __builtin_amdgcn_mfma_f32_16x16x32_bf16(ah0, bl0, acc, 0, 0, 0);
    acc = __builtin_amdgcn_mfma_f32_16x16x32_bf16(ah1, bl1, acc, 0, 0, 0);
    return acc;
}

// ---------------- atom-side projection (MFMA): [N,128] @ [128,128] ----------------
// 512 threads = 8 waves, 64 atoms/block. pa|qa = AF @ [iw1_top | iw1_bot].
// Wave w: col-tile ct=w (ct<4 -> pa cols, else qa), all 4 row-tiles, K=128 via 2 halves.
__global__ void __launch_bounds__(512) atom_proj_k(
    const float* __restrict__ AF, const uint4* __restrict__ fIw1,
    float* __restrict__ pa, float* __restrict__ qa, float* __restrict__ na, int N) {
    __shared__ uint4 sHi[1024];
    __shared__ uint4 sLo[1024];
    int tid = threadIdx.x;
    int lane = tid & 63;
    int w = __builtin_amdgcn_readfirstlane((int)(tid >> 6));   // 0..7
    int a0 = blockIdx.x * 64;

    // ---- stage AF rows (hi/lo) + norm ----
    {
        int dl = tid >> 3, q = tid & 7;
        int a = a0 + dl;
        bool ok = a < N;
        const float* ar = AF + (size_t)(ok ? a : 0) * HDIM + q * 16;
        float4 v0 = ld4(ar + 0), v1 = ld4(ar + 4), v2 = ld4(ar + 8), v3 = ld4(ar + 12);
        float nrm = v0.x*v0.x + v0.y*v0.y + v0.z*v0.z + v0.w*v0.w
                  + v1.x*v1.x + v1.y*v1.y + v1.z*v1.z + v1.w*v1.w
                  + v2.x*v2.x + v2.y*v2.y + v2.z*v2.z + v2.w*v2.w
                  + v3.x*v3.x + v3.y*v3.y + v3.z*v3.z + v3.w*v3.w;
        nrm += __shfl_xor(nrm, 1, 64);
        nrm += __shfl_xor(nrm, 2, 64);
        nrm += __shfl_xor(nrm, 4, 64);
        if (q == 0 && ok) na[a] = sqrtf(nrm);
        float f0[8] = {v0.x, v0.y, v0.z, v0.w, v1.x, v1.y, v1.z, v1.w};
        float f1[8] = {v2.x, v2.y, v2.z, v2.w, v3.x, v3.y, v3.z, v3.w};
        if (!ok) {
            #pragma unroll
            for (int i = 0; i < 8; ++i) { f0[i] = 0.f; f1[i] = 0.f; }
        }
        uint4 h, l;
        hilo8(f0, h, l);
        int s0 = slotIdx16(dl, q * 2);
        sHi[s0] = h; sLo[s0] = l;
        hilo8(f1, h, l);
        int s1 = slotIdx16(dl, q * 2 + 1);
        sHi[s1] = h; sLo[s1] = l;
    }
    // B frags (independent of LDS)
    int jt = w & 3;
    const uint4* m0 = fIw1 + ((w < 4) ? 0 : 2048);
    short8 B0h0, B0h1, B0l0, B0l1, B1h0, B1h1, B1l0, B1l1;
    loadB(m0, jt, lane, B0h0, B0h1, B0l0, B0l1);            // K 0..63
    loadB(m0 + 1024, jt, lane, B1h0, B1h1, B1l0, B1l1);     // K 64..127
    __syncthreads();

    float* dst = (w < 4) ? pa : qa;
    int j = jt * 16 + (lane & 15);
    f32x4 z4 = {0.f, 0.f, 0.f, 0.f};
    #pragma unroll
    for (int rt = 0; rt < 4; ++rt) {
        f32x4 acc = gemm_tile16(sHi, sLo, rt * 16, lane, 0, B0h0, B0h1, B0l0, B0l1, z4);
        acc = gemm_tile16(sHi, sLo, rt * 16, lane, 8, B1h0, B1h1, B1l0, B1l1, acc);
        #pragma unroll
        for (int r = 0; r < 4; ++r) {
            int rowi = rt * 16 + (lane >> 4) * 4 + r;
            int a = a0 + rowi;
            if (a < N) dst[(size_t)a * DDIM + j] = acc[r];
        }
    }
}

// ---------------- bond init (MFMA version, 512 threads) ----------------
__global__ void __launch_bounds__(512, 4) bond_init2_k(
    const float* __restrict__ AF, const int* __restrict__ row, const int* __restrict__ col,
    const float* __restrict__ pa, const float* __restrict__ qa, const float* __restrict__ na,
    const float* __restrict__ b1, const uint4* __restrict__ fW2, const float* __restrict__ b2,
    const uint4* __restrict__ fP0,
    float* __restrict__ x, int* __restrict__ bt,
    float* __restrict__ pd, uint4* __restrict__ ps, int E) {
    __shared__ uint4 sAhi[512];   // h, then ps staging (hi)
    __shared__ uint4 sAlo[512];   //                    (lo)
    __shared__ uint4 sXhi[512];   // x                  (hi)
    __shared__ uint4 sXlo[512];   //                    (lo)
    int nEB = (E + EPB - 1) / EPB;
    int lb = xcd_logical_block();
    if (lb >= nEB) return;
    int tid = threadIdx.x;
    int lane = tid & 63;
    int w = __builtin_amdgcn_readfirstlane((int)(tid >> 6));   // 0..7
    int e0 = lb * EPB;

    // ---- P0: gather atoms, silu, classify ----
    {
        int dl = tid >> 3, q = tid & 7;
        int d = e0 + dl;
        bool ok = d < E;
        int dd = ok ? d : 0;
        int r = row[dd], c = col[dd];
        int jq = q * 8;

        const float* hi = AF + (size_t)r * HDIM + q * 16;
        const float* hj = AF + (size_t)c * HDIM + q * 16;
        float dt = 0.f;
        #pragma unroll
        for (int k = 0; k < 16; k += 4) {
            float4 a4 = ld4(hi + k), b4 = ld4(hj + k);
            dt += a4.x * b4.x + a4.y * b4.y + a4.z * b4.z + a4.w * b4.w;
        }
        dt += __shfl_xor(dt, 1, 64);
        dt += __shfl_xor(dt, 2, 64);
        dt += __shfl_xor(dt, 4, 64);
        if (q == 0 && ok) {
            float nr = fmaxf(na[r], 1e-8f), nc = fmaxf(na[c], 1e-8f);
            float sim = dt / (nr * nc);
            int t = 0;
            if (sim > 0.8f) t = 1;
            if (sim > 0.9f) t = 2;
            if (sim < 0.3f) t = 3;
            bt[d] = t;
        }

        const float* pr = pa + (size_t)r * DDIM + jq;
        const float* qc = qa + (size_t)c * DDIM + jq;
        float4 p0 = ld4(pr + 0), p1 = ld4(pr + 4);
        float4 q0 = ld4(qc + 0), q1 = ld4(qc + 4);
        float hv[8];
        hv[0] = silu_f(p0.x + q0.x + b1[jq + 0]);
        hv[1] = silu_f(p0.y + q0.y + b1[jq + 1]);
        hv[2] = silu_f(p0.z + q0.z + b1[jq + 2]);
        hv[3] = silu_f(p0.w + q0.w + b1[jq + 3]);
        hv[4] = silu_f(p1.x + q1.x + b1[jq + 4]);
        hv[5] = silu_f(p1.y + q1.y + b1[jq + 5]);
        hv[6] = silu_f(p1.z + q1.z + b1[jq + 6]);
        hv[7] = silu_f(p1.w + q1.w + b1[jq + 7]);
        if (!ok) {
            #pragma unroll
            for (int i = 0; i < 8; ++i) hv[i] = 0.f;
        }
        uint4 h4, l4;
        hilo8(hv, h4, l4);
        int si = slotIdx(dl, q);
        sAhi[si] = h4; sAlo[si] = l4;
    }
    int jt = w & 3, mh = w >> 2;
    short8 W2h0, W2h1, W2l0, W2l1;
    loadB(fW2, jt, lane, W2h0, W2h1, W2l0, W2l1);
    __syncthreads();

    // ---- P1: x = h@iw2 + b2 ----
    int rb0 = mh * 32, rb1 = mh * 32 + 16;
    f32x4 z4 = {0.f, 0.f, 0.f, 0.f};
    f32x4 acc0 = gemm_tile(sAhi, sAlo, rb0, lane, W2h0, W2h1, W2l0, W2l1, z4);
    f32x4 acc1 = gemm_tile(sAhi, sAlo, rb1, lane, W2h0, W2h1, W2l0, W2l1, z4);
    int j = jt * 16 + (lane & 15);
    float b2j = b2[j];
    unsigned short* hX = (unsigned short*)sXhi;
    unsigned short* lX = (unsigned short*)sXlo;
    #pragma unroll
    for (int r = 0; r < 4; ++r) {
        int rowi = rb0 + (lane >> 4) * 4 + r;
        int e = e0 + rowi;
        float xn = acc0[r] + b2j;
        if (e < E) x[(size_t)e * DDIM + j] = xn;
        unsigned int hb = bf16r(xn);
        float lov = xn - __uint_as_float(hb << 16);
        int ui = (rowi * 8 + ((j >> 3) ^ (rowi & 7))) * 8 + (j & 7);
        hX[ui] = (unsigned short)hb;
        lX[ui] = (unsigned short)bf16r(lov);
    }
    #pragma unroll
    for (int r = 0; r < 4; ++r) {
        int rowi = rb1 + (lane >> 4) * 4 + r;
        int e = e0 + rowi;
        float xn = acc1[r] + b2j;
        if (e < E) x[(size_t)e * DDIM + j] = xn;
        unsigned int hb = bf16r(xn);
        float lov = xn - __uint_as_float(hb << 16);
        int ui = (rowi * 8 + ((j >> 3) ^ (rowi & 7))) * 8 + (j & 7);
        hX[ui] = (unsigned short)hb;
        lX[ui] = (unsigned short)bf16r(lov);
    }
    __syncthreads();    // x staged; P1 h-reads done before P2 sA-writes

    // ---- P2: layer-0 proj. wave w -> 16-col strip of 128-wide output.
    const uint4* fPw = (w < 4) ? fP0 : (fP0 + 1024);
    int jp = w & 3;
    short8 Ph0, Ph1, Pl0, Pl1;
    loadB(fPw, jp, lane, Ph0, Ph1, Pl0, Pl1);
    f32x4 q0 = gemm_tile(sXhi, sXlo, 0,  lane, Ph0, Ph1, Pl0, Pl1, z4);
    f32x4 q1 = gemm_tile(sXhi, sXlo, 16, lane, Ph0, Ph1, Pl0, Pl1, z4);
    f32x4 q2 = gemm_tile(sXhi, sXlo, 32, lane, Ph0, Ph1, Pl0, Pl1, z4);
    f32x4 q3 = gemm_tile(sXhi, sXlo, 48, lane, Ph0, Ph1, Pl0, Pl1, z4);
    unsigned short* hA = (unsigned short*)sAhi;
    if (w < 4) {
        int jd = jp * 16 + (lane & 15);
        #pragma unroll
        for (int mt = 0; mt < 4; ++mt) {
            f32x4 qq = (mt == 0) ? q0 : (mt == 1) ? q1 : (mt == 2) ? q2 : q3;
            #pragma unroll
            for (int r = 0; r < 4; ++r) {
                int rowi = mt * 16 + (lane >> 4) * 4 + r;
                int e = e0 + rowi;
                if (e < E) pd[(size_t)e * DDIM + jd] = qq[r];
            }
        }
    } else {
        int js = jp * 16 + (lane & 15);
        #pragma unroll
        for (int mt = 0; mt < 4; ++mt) {
            f32x4 qq = (mt == 0) ? q0 : (mt == 1) ? q1 : (mt == 2) ? q2 : q3;
            #pragma unroll
            for (int r = 0; r < 4; ++r) {
                int rowi = mt * 16 + (lane >> 4) * 4 + r;
                int ui = (rowi * 8 + ((js >> 3) ^ (rowi & 7))) * 8 + (js & 7);
                hA[ui] = (unsigned short)bf16r(qq[r]);
            }
        }
    }
    __syncthreads();
    {
        int dl = tid >> 3, q = tid & 7;
        int d = e0 + dl;
        if (d < E) ps[(size_t)d * 8 + q] = sAhi[slotIdx(dl, q)];
    }
}

// proj (x from global) — fallback path only (used if ws too small for pd2/ps2)
__global__ void __launch_bounds__(256) proj_k(const float* __restrict__ x,
                                              const float* __restrict__ w1 /*[192][64]*/,
                                              float* __restrict__ pd, uint4* __restrict__ ps,
                                              int E) {
    int lane = threadIdx.x & 63;
    int w = __builtin_amdgcn_readfirstlane((int)(threadIdx.x >> 6));
    int e = blockIdx.x * EPB + lane;
    bool ok = e < E;
    int eidx = ok ? e : 0;
    int j0 = w * 16;
    const float* xr = x + (size_t)eidx * DDIM;

    float apd[16], aps[16];
    #pragma unroll
    for (int jj = 0; jj < 16; ++jj) { apd[jj] = 0.f; aps[jj] = 0.f; }
    #pragma unroll 2
    for (int c = 0; c < 16; ++c) {
        float4 v = ld4(xr + c * 4);
        float xv[4] = {v.x, v.y, v.z, v.w};
        #pragma unroll
        for (int kk = 0; kk < 4; ++kk) {
            int k = c * 4 + kk;
            const float* wd = w1 + (size_t)k * DDIM + j0;
            const float* wsv = w1 + (size_t)(DDIM + k) * DDIM + j0;
            #pragma unroll
            for (int jj = 0; jj < 16; ++jj) {
                apd[jj] = fmaf(xv[kk], wd[jj], apd[jj]);
                aps[jj] = fmaf(xv[kk], wsv[jj], aps[jj]);
            }
        }
    }
    if (ok) {
        float* pr = pd + (size_t)e * DDIM + j0;
        st4(pr + 0,  make_float4(apd[0],  apd[1],  apd[2],  apd[3]));
        st4(pr + 4,  make_float4(apd[4],  apd[5],  apd[6],  apd[7]));
        st4(pr + 8,  make_float4(apd[8],  apd[9],  apd[10], apd[11]));
        st4(pr + 12, make_float4(apd[12], apd[13], apd[14], apd[15]));
        ps[(size_t)e * 8 + 2 * w + 0] = pack8(aps + 0);
        ps[(size_t)e * 8 + 2 * w + 1] = pack8(aps + 8);
    }
}

// ---------------- fused gather + update (+ next-layer proj | pooling) ----------------
// P1: prefetch block srclist -> LDS (SCAP); gather s; stage s and x hi/lo.
// P2: h = silu((inv*s)@W2u + x@Uw1b + ub1 + degflag*b2u)
// P3: xnew = x(LDS hi+lo) + h@Uw2 + ub2; store (keep xnew in regs)
// P4 (layer0): pdn/psn = xnew @ W1   |   pool (layer1): LDS partial mean -> gfeat atomics
__global__ void __launch_bounds__(512, 4) layer_k(
    float* __restrict__ x, const float* __restrict__ pd, const uint4* __restrict__ ps,
    const float* __restrict__ tt_l, const int* __restrict__ bt,
    const int* __restrict__ offs, const int* __restrict__ srclist,
    const int* __restrict__ cnt,
    const uint4* __restrict__ fW2u, const float* __restrict__ b2u,
    const uint4* __restrict__ fU1b, const float* __restrict__ ub1,
    const uint4* __restrict__ fU2, const float* __restrict__ ub2,
    const uint4* __restrict__ fP /* next-layer proj frags or nullptr */,
    float* __restrict__ pdn, uint4* __restrict__ psn, int E,
    const int* __restrict__ erow, const int* __restrict__ gbatch,
    float* __restrict__ gfeat, int doPool) {
    __shared__ uint4 sAhi[512];   // s / h / psn-staging / pool buffer (hi)
    __shared__ uint4 sAlo[512];   //                                  (lo)
    __shared__ uint4 sXhi[512];   // x / xnew             (hi)
    __shared__ uint4 sXlo[512];   //                      (lo)
    __shared__ float degLDS[64];  // 1.0 if deg>0 else 0.0
    __shared__ int   gidLDS[64];  // graph id per bond (-1 invalid)
    __shared__ int   sIdx[SCAP];  // prefetched srclist slice
    int nEB = (E + EPB - 1) / EPB;
    int lb = xcd_logical_block();
    if (lb >= nEB) return;
    int tid = threadIdx.x;
    int lane = tid & 63;
    int w = __builtin_amdgcn_readfirstlane((int)(tid >> 6));   // 0..7
    int e0 = lb * EPB;
    int pb0 = offs[e0];          // uniform

    // ---- P1 ----
    {
        int dl = tid >> 3, q = tid & 7;
        int d = e0 + dl;
        bool ok = d < E;
        int dd = ok ? d : 0;
        int jq = q * 8;
        const float* xr = x + (size_t)dd * DDIM + jq;
        float4 xv0 = ld4(xr + 0), xv1 = ld4(xr + 4);   // issued early, used late
        int dc = cnt[dd];
        int rAtom = (doPool && ok) ? erow[dd] : 0;
        const float* pr = pd + (size_t)dd * DDIM + jq;
        const float* tp = tt_l + (size_t)bt[dd] * DDIM + jq;
        float4 b0 = add4(ld4(pr + 0), ld4(tp + 0));
        float4 b1 = add4(ld4(pr + 4), ld4(tp + 4));
        int p0v = ok ? offs[d] : pb0, p1v = ok ? offs[d + 1] : pb0;

        // block srclist prefetch (coalesced, de-duplicates the 8x per-bond reads)
        int emax = min(e0 + EPB, E);
        int pT = offs[emax] - pb0;
        for (int i = tid; i < pT && i < SCAP; i += 512) sIdx[i] = srclist[pb0 + i];
        __syncthreads();

        float4 s0 = make_float4(0, 0, 0, 0), s1 = s0;
        if (p1v - pb0 <= SCAP) {
            int li = p0v - pb0, le = p1v - pb0;
            for (; li + 4 <= le; li += 4) {
                uint4 u0 = ps[(size_t)sIdx[li + 0] * 8 + q];
                uint4 u1 = ps[(size_t)sIdx[li + 1] * 8 + q];
                uint4 u2 = ps[(size_t)sIdx[li + 2] * 8 + q];
                uint4 u3 = ps[(size_t)sIdx[li + 3] * 8 + q];
                float4 a, b;
                unpack8(u0, a, b);
                silu_acc4(s0, add4(b0, a));
                silu_acc4(s1, add4(b1, b));
                unpack8(u1, a, b);
                silu_acc4(s0, add4(b0, a));
                silu_acc4(s1, add4(b1, b));
                unpack8(u2, a, b);
                silu_acc4(s0, add4(b0, a));
                silu_acc4(s1, add4(b1, b));
                unpack8(u3, a, b);
                silu_acc4(s0, add4(b0, a));
                silu_acc4(s1, add4(b1, b));
            }
            for (; li < le; ++li) {
                uint4 u0 = ps[(size_t)sIdx[li] * 8 + q];
                float4 a, b;
                unpack8(u0, a, b);
                silu_acc4(s0, add4(b0, a));
                silu_acc4(s1, add4(b1, b));
            }
        } else {
            int p = p0v;
            for (; p + 4 <= p1v; p += 4) {
                uint4 u0 = ps[(size_t)srclist[p + 0] * 8 + q];
                uint4 u1 = ps[(size_t)srclist[p + 1] * 8 + q];
                uint4 u2 = ps[(size_t)srclist[p + 2] * 8 + q];
                uint4 u3 = ps[(size_t)srclist[p + 3] * 8 + q];
                float4 a, b;
                unpack8(u0, a, b);
                silu_acc4(s0, add4(b0, a));
                silu_acc4(s1, add4(b1, b));
                unpack8(u1, a, b);
                silu_acc4(s0, add4(b0, a));
                silu_acc4(s1, add4(b1, b));
                unpack8(u2, a, b);
                silu_acc4(s0, add4(b0, a));
                silu_acc4(s1, add4(b1, b));
                unpack8(u3, a, b);
                silu_acc4(s0, add4(b0, a));
                silu_acc4(s1, add4(b1, b));
            }
            for (; p < p1v; ++p) {
                uint4 u0 = ps[(size_t)srclist[p] * 8 + q];
                float4 a, b;
                unpack8(u0, a, b);
                silu_acc4(s0, add4(b0, a));
                silu_acc4(s1, add4(b1, b));
            }
        }
        float inv = 1.0f / fmaxf((float)dc, 1.0f);
        float sv[8] = {s0.x * inv, s0.y * inv, s0.z * inv, s0.w * inv,
                       s1.x * inv, s1.y * inv, s1.z * inv, s1.w * inv};
        float xf[8] = {xv0.x, xv0.y, xv0.z, xv0.w, xv1.x, xv1.y, xv1.z, xv1.w};
        if (!ok) {
            #pragma unroll
            for (int i = 0; i < 8; ++i) { sv[i] = 0.f; xf[i] = 0.f; }
        }
        uint4 h4, l4;
        int si = slotIdx(dl, q);
        hilo8(sv, h4, l4);
        sAhi[si] = h4; sAlo[si] = l4;
        hilo8(xf, h4, l4);
        sXhi[si] = h4; sXlo[si] = l4;
        if (q == 0) {
            degLDS[dl] = (ok && dc > 0) ? 1.0f : 0.0f;
            gidLDS[dl] = (doPool && ok) ? gbatch[rAtom] : -1;
        }
    }
    // preload loop-invariant B-frags (independent of LDS; overlaps barrier wait)
    int jt = w & 3, mh = w >> 2;
    short8 A2h0, A2h1, A2l0, A2l1;   // W2u
    short8 U1h0, U1h1, U1l0, U1l1;   // Uw1b
    loadB(fW2u, jt, lane, A2h0, A2h1, A2l0, A2l1);
    loadB(fU1b, jt, lane, U1h0, U1h1, U1l0, U1l1);
    __syncthreads();

    // ---- P2: h = silu((inv*s)@W2u + x@Uw1b + bias) ----
    int rb0 = mh * 32, rb1 = mh * 32 + 16;
    f32x4 z4 = {0.f, 0.f, 0.f, 0.f};
    f32x4 acc0 = z4, acc1 = z4;
    acc0 = gemm_tile(sAhi, sAlo, rb0, lane, A2h0, A2h1, A2l0, A2l1, acc0);
    acc0 = gemm_tile(sXhi, sXlo, rb0, lane, U1h0, U1h1, U1l0, U1l1, acc0);
    acc1 = gemm_tile(sAhi, sAlo, rb1, lane, A2h0, A2h1, A2l0, A2l1, acc1);
    acc1 = gemm_tile(sXhi, sXlo, rb1, lane, U1h0, U1h1, U1l0, U1l1, acc1);
    __syncthreads();                       // all s/x fragment reads done
    int j = jt * 16 + (lane & 15);
    float ub1j = ub1[j], b2uj = b2u[j];
    unsigned short* hA = (unsigned short*)sAhi;
    unsigned short* lA = (unsigned short*)sAlo;
    #pragma unroll
    for (int r = 0; r < 4; ++r) {
        int row = rb0 + (lane >> 4) * 4 + r;
        float hv = silu_f(acc0[r] + ub1j + degLDS[row] * b2uj);
        unsigned int hb = bf16r(hv);
        float lov = hv - __uint_as_float(hb << 16);
        int ui = (row * 8 + ((j >> 3) ^ (row & 7))) * 8 + (j & 7);
        hA[ui] = (unsigned short)hb;
        lA[ui] = (unsigned short)bf16r(lov);
    }
    #pragma unroll
    for (int r = 0; r < 4; ++r) {
        int row = rb1 + (lane >> 4) * 4 + r;
        float hv = silu_f(acc1[r] + ub1j + degLDS[row] * b2uj);
        unsigned int hb = bf16r(hv);
        float lov = hv - __uint_as_float(hb << 16);
        int ui = (row * 8 + ((j >> 3) ^ (row & 7))) * 8 + (j & 7);
        hA[ui] = (unsigned short)hb;
        lA[ui] = (unsigned short)bf16r(lov);
    }
    __syncthreads();                       // h staged

    // ---- P3: o = h@Uw2 + ub2; xnew = x(LDS) + o ----
    short8 U2h0, U2h1, U2l0, U2l1;
    loadB(fU2, jt, lane, U2h0, U2h1, U2l0, U2l1);
    f32x4 o0 = gemm_tile(sAhi, sAlo, rb0, lane, U2h0, U2h1, U2l0, U2l1, z4);
    f32x4 o1 = gemm_tile(sAhi, sAlo, rb1, lane, U2h0, U2h1, U2l0, U2l1, z4);
    float ub2j = ub2[j];
    bool haveP = (fP != nullptr);
    unsigned short* hX = (unsigned short*)sXhi;
    unsigned short* lX = (unsigned short*)sXlo;
    float xnv0[4], xnv1[4];
    #pragma unroll
    for (int r = 0; r < 4; ++r) {
        int row = rb0 + (lane >> 4) * 4 + r;
        int e = e0 + row;
        int ui = (row * 8 + ((j >> 3) ^ (row & 7))) * 8 + (j & 7);
        float xvv = __uint_as_float((unsigned int)hX[ui] << 16)
                  + __uint_as_float((unsigned int)lX[ui] << 16);
        float xn = xvv + o0[r] + ub2j;
        xnv0[r] = xn;
        if (e < E) x[(size_t)e * DDIM + j] = xn;
        if (haveP) {
            unsigned int hb = bf16r(xn);
            float lov = xn - __uint_as_float(hb << 16);
            hX[ui] = (unsigned short)hb;
            lX[ui] = (unsigned short)bf16r(lov);
        }
    }
    #pragma unroll
    for (int r = 0; r < 4; ++r) {
        int row = rb1 + (lane >> 4) * 4 + r;
        int e = e0 + row;
        int ui = (row * 8 + ((j >> 3) ^ (row & 7))) * 8 + (j & 7);
        float xvv = __uint_as_float((unsigned int)hX[ui] << 16)
                  + __uint_as_float((unsigned int)lX[ui] << 16);
        float xn = xvv + o1[r] + ub2j;
        xnv1[r] = xn;
        if (e < E) x[(size_t)e * DDIM + j] = xn;
        if (haveP) {
            unsigned int hb = bf16r(xn);
            float lov = xn - __uint_as_float(hb << 16);
            hX[ui] = (unsigned short)hb;
            lX[ui] = (unsigned short)bf16r(lov);
        }
    }
    if (!haveP) {
        if (doPool) {
            // ---- fused pooling: per-block partial sums -> gfeat atomics ----
            __syncthreads();               // P3 LDS reads done; reuse sAhi
            float* poolB = (float*)sAhi;   // [4][64]
            if (tid < 256) poolB[tid] = 0.f;
            __syncthreads();
            int gid0 = gidLDS[0];          // e0 < E always -> valid
            bool uni = (gidLDS[EPB - 1] == gid0);
            if (uni) {
                float s = xnv0[0] + xnv0[1] + xnv0[2] + xnv0[3]
                        + xnv1[0] + xnv1[1] + xnv1[2] + xnv1[3];
                atomicAdd(&poolB[j], s);
            } else {
                #pragma unroll
                for (int r = 0; r < 4; ++r) {
                    int row = rb0 + (lane >> 4) * 4 + r;
                    int g = gidLDS[row];
                    if (g >= 0) {
                        int sl = g - gid0;
                        if (sl < 4) atomicAdd(&poolB[sl * DDIM + j], xnv0[r]);
                        else atomicAdd(&gfeat[(size_t)g * DDIM + j], xnv0[r]);
                    }
                }
                #pragma unroll
                for (int r = 0; r < 4; ++r) {
                    int row = rb1 + (lane >> 4) * 4 + r;
                    int g = gidLDS[row];
                    if (g >= 0) {
                        int sl = g - gid0;
                        if (sl < 4) atomicAdd(&poolB[sl * DDIM + j], xnv1[r]);
                        else atomicAdd(&gfeat[(size_t)g * DDIM + j], xnv1[r]);
                    }
                }
            }
            __syncthreads();
            if (tid < 256) {
                int sl = tid >> 6;
                int g = gid0 + sl;
                float v = poolB[tid];
                if (v != 0.f && g < NGRAPHS)
                    atomicAdd(&gfeat[(size_t)g * DDIM + (tid & 63)], v);
            }
        }
        return;
    }
    __syncthreads();    // xnew staged; orders P3 A-reads before P4 A-writes

    // ---- P4: next-layer proj. wave w -> 16-col strip of the 128-wide output.
    const uint4* fPw = (w < 4) ? fP : (fP + 1024);
    int jp = w & 3;
    short8 Ph0, Ph1, Pl0, Pl1;
    loadB(fPw, jp, lane, Ph0, Ph1, Pl0, Pl1);
    f32x4 q0 = gemm_tile(sXhi, sXlo, 0,  lane, Ph0, Ph1, Pl0, Pl1, z4);
    f32x4 q1 = gemm_tile(sXhi, sXlo, 16, lane, Ph0, Ph1, Pl0, Pl1, z4);
    f32x4 q2 = gemm_tile(sXhi, sXlo, 32, lane, Ph0, Ph1, Pl0, Pl1, z4);
    f32x4 q3 = gemm_tile(sXhi, sXlo, 48, lane, Ph0, Ph1, Pl0, Pl1, z4);
    if (w < 4) {
        int jd = jp * 16 + (lane & 15);
        #pragma unroll
        for (int mt = 0; mt < 4; ++mt) {
            f32x4 qq = (mt == 0) ? q0 : (mt == 1) ? q1 : (mt == 2) ? q2 : q3;
            #pragma unroll
            for (int r = 0; r < 4; ++r) {
                int row = mt * 16 + (lane >> 4) * 4 + r;
                int e = e0 + row;
                if (e < E) pdn[(size_t)e * DDIM + jd] = qq[r];
            }
        }
    } else {
        int js = jp * 16 + (lane & 15);
        #pragma unroll
        for (int mt = 0; mt < 4; ++mt) {
            f32x4 qq = (mt == 0) ? q0 : (mt == 1) ? q1 : (mt == 2) ? q2 : q3;
            #pragma unroll
            for (int r = 0; r < 4; ++r) {
                int row = mt * 16 + (lane >> 4) * 4 + r;
                int ui = (row * 8 + ((js >> 3) ^ (row & 7))) * 8 + (js & 7);
                hA[ui] = (unsigned short)bf16r(qq[r]);
            }
        }
    }
    __syncthreads();
    {
        int dl = tid >> 3, q = tid & 7;
        int d = e0 + dl;
        if (d < E) psn[(size_t)d * 8 + q] = sAhi[slotIdx(dl, q)];
    }
}

static __device__ __forceinline__ int lower_bound_bb(const int* __restrict__ row,
                                                     const int* __restrict__ batch,
                                                     int E, int g) {
    int lo = 0, hi = E;
    while (lo < hi) {
        int m = (lo + hi) >> 1;
        if (batch[row[m]] < g) lo = m + 1; else hi = m;
    }
    return lo;
}

__global__ void __launch_bounds__(64) pool_final_k(
    const int* __restrict__ row, const int* __restrict__ batch,
    float* __restrict__ gfeat, int E) {
    int g = blockIdx.x, j = threadIdx.x;
    int s = lower_bound_bb(row, batch, E, g);
    int t = lower_bound_bb(row, batch, E, g + 1);
    float cnt = fmaxf((float)(t - s), 1.0f);
    gfeat[g * DDIM + j] /= cnt;
}

extern "C" void kernel_launch(void* const* d_in, const int* in_sizes, int n_in,
                              void* d_out, int out_size, void* d_ws, size_t ws_size,
                              hipStream_t stream) {
    (void)n_in; (void)out_size;
    const float* AF    = (const float*)d_in[0];
    const int*   batch = (const int*)d_in[3];
    const int*   edge_index      = (const int*)d_in[4];
    const int*   bond_edge_index = (const int*)d_in[5];
    const float* iw1 = (const float*)d_in[6];
    const float* ib1 = (const float*)d_in[7];
    const float* iw2 = (const float*)d_in[8];
    const float* ib2 = (const float*)d_in[9];
    const float* emb = (const float*)d_in[10];
    const float* mw1 = (const float*)d_in[11];
    const float* mb1 = (const float*)d_in[12];
    const float* mw2 = (const float*)d_in[13];
    const float* mb2 = (const float*)d_in[14];
    const float* uw1 = (const float*)d_in[15];
    const float* ub1 = (const float*)d_in[16];
    const float* uw2 = (const float*)d_in[17];
    const float* ub2 = (const float*)d_in[18];

    const int N  = in_sizes[0] / HDIM;
    const int E  = in_sizes[4] / 2;
    const int BE = in_sizes[5] / 2;
    const int NB = (E + 255) / 256;
    const int EB = (E + EPB - 1) / EPB;
    const int APB = (N + 63) / 64;                  // atom blocks (64 atoms/block)
    const int EBS = ((EB + 7) / 8) * 8;             // swizzled grid (multiple of 8)

    float* xout  = (float*)d_out;                 // [E,64]
    float* gfeat = xout + (size_t)E * DDIM;       // [16,64]

    // workspace layout
    char* w = (char*)d_ws;
    float* tt       = (float*)w;  w += sizeof(float) * 2 * NTYPES * DDIM;
    float* b2u      = (float*)w;  w += sizeof(float) * 2 * DDIM;
    w = (char*)(((uintptr_t)w + 15) & ~(uintptr_t)15);
    // MFMA weight fragments (hi/lo bf16)
    uint4* fW2u     = (uint4*)w;  w += 2048 * sizeof(uint4);
    uint4* fU1b     = (uint4*)w;  w += 2048 * sizeof(uint4);
    uint4* fU2      = (uint4*)w;  w += 2048 * sizeof(uint4);
    uint4* fP       = (uint4*)w;  w += 2048 * sizeof(uint4);
    uint4* fIw2     = (uint4*)w;  w += 1024 * sizeof(uint4);
    uint4* fP0      = (uint4*)w;  w += 2048 * sizeof(uint4);
    uint4* fIw1     = (uint4*)w;  w += 4096 * sizeof(uint4);
    int*   cnt      = (int*)w;    w += sizeof(int) * E;
    int*   offs     = (int*)w;    w += sizeof(int) * (E + 1);
    int*   cursor   = (int*)w;    w += sizeof(int) * E;
    int*   bt       = (int*)w;    w += sizeof(int) * E;
    int*   bsum     = (int*)w;    w += sizeof(int) * 1024;
    int*   bpre     = (int*)w;    w += sizeof(int) * 1024;
    int*   srclist  = (int*)w;    w += sizeof(int) * BE;
    w = (char*)(((uintptr_t)w + 15) & ~(uintptr_t)15);
    float* pd       = (float*)w;  w += sizeof(float) * (size_t)E * DDIM;
    uint4* ps       = (uint4*)w;  w += sizeof(unsigned short) * (size_t)E * DDIM;
    float* pa       = (float*)w;  w += sizeof(float) * (size_t)N * DDIM;
    float* qa       = (float*)w;  w += sizeof(float) * (size_t)N * DDIM;
    float* na       = (float*)w;  w += sizeof(float) * (size_t)N;
    w = (char*)(((uintptr_t)w + 15) & ~(uintptr_t)15);
    // optional second proj buffers (fused-proj path)
    float* pd2      = (float*)w;  w += sizeof(float) * (size_t)E * DDIM;
    uint4* ps2      = (uint4*)w;  w += sizeof(unsigned short) * (size_t)E * DDIM;
    bool fuse_proj = ((size_t)(w - (char*)d_ws) <= ws_size);

    const int* row  = edge_index;
    const int* col  = edge_index + E;
    const int* bsrc = bond_edge_index;
    const int* bdst = bond_edge_index + BE;

    // CSR build
    hipMemsetAsync(cnt, 0, (size_t)E * sizeof(int), stream);
    count_k<<<(BE + 255) / 256, 256, 0, stream>>>(bdst, cnt, BE);
    bsum_k<<<NB, 256, 0, stream>>>(cnt, bsum, E);
    bscan_k<<<1, 1024, 0, stream>>>(bsum, bpre, NB);
    offs_k<<<NB, 256, 0, stream>>>(cnt, bpre, offs, cursor, E);
    scatter_k<<<(BE + 255) / 256, 256, 0, stream>>>(bsrc, bdst, cursor, srclist, BE);

    // constants: tt + b2u + all MFMA B-fragments in one launch
    prep_k<<<132, 64, 0, stream>>>(emb, mw1, mb1, mw2, mb2, uw1, uw2, iw2, iw1,
                                   tt, b2u, fW2u, fU1b, fU2, fP, fIw2, fP0, fIw1);

    // atom projections (MFMA), then bond init + layer-0 proj (MFMA)
    atom_proj_k<<<APB, 512, 0, stream>>>(AF, fIw1, pa, qa, na, N);
    bond_init2_k<<<EBS, 512, 0, stream>>>(AF, row, col, pa, qa, na, ib1, fIw2, ib2,
                                          fP0, xout, bt, pd, ps, E);

    hipMemsetAsync(gfeat, 0, NGRAPHS * DDIM * sizeof(float), stream);

    if (fuse_proj) {
        // layer 0: fused next-layer proj -> pd2/ps2
        layer_k<<<EBS, 512, 0, stream>>>(
            xout, pd, ps, tt, bt, offs, srclist, cnt,
            fW2u, b2u, fU1b, ub1, fU2, ub2,
            fP, pd2, ps2, E, row, batch, gfeat, 0);
        // layer 1: no proj, fused pooling
        layer_k<<<EBS, 512, 0, stream>>>(
            xout, pd2, ps2, tt + NTYPES * DDIM, bt, offs, srclist, cnt,
            fW2u + 1024, b2u + DDIM, fU1b + 1024, ub1 + DDIM,
            fU2 + 1024, ub2 + DDIM,
            nullptr, nullptr, nullptr, E, row, batch, gfeat, 1);
    } else {
        for (int l = 0; l < 2; ++l) {
            if (l > 0)
                proj_k<<<EB, 256, 0, stream>>>(xout, mw1 + (size_t)l * 192 * 64, pd, ps, E);
            layer_k<<<EBS, 512, 0, stream>>>(
                xout, pd, ps, tt + (size_t)l * NTYPES * DDIM, bt, offs, srclist, cnt,
                fW2u + (size_t)l * 1024, b2u + (size_t)l * DDIM,
                fU1b + (size_t)l * 1024, ub1 + (size_t)l * DDIM,
                fU2 + (size_t)l * 1024, ub2 + (size_t)l * DDIM,
                nullptr, nullptr, nullptr, E, row, batch, gfeat, l == 1 ? 1 : 0);
        }
    }

    pool_final_k<<<NGRAPHS, 64, 0, stream>>>(row, batch, gfeat, E);
}

// Round 6
// 279.832 us; speedup vs baseline: 1.1561x; 1.0194x over previous
//
#include <hip/hip_runtime.h>
#include <hip/hip_cooperative_groups.h>
#include <cstdint>
#include <cstddef>

namespace cg = cooperative_groups;

#define HDIM 128
#define DDIM 64
#define NTYPES 5
#define NGRAPHS 16
#define EPB 64       // edges per block (one per lane)
#define SCAP 1024    // srclist LDS prefetch capacity (per 64-bond block)
#define PREPB 132    // prep blocks inside prepcount_k

typedef __attribute__((ext_vector_type(8))) short short8;   // 8 bf16
typedef __attribute__((ext_vector_type(4))) float f32x4;

static __device__ __forceinline__ short8 as_s8(uint4 u) {
    return __builtin_bit_cast(short8, u);
}

// fast silu: v_rcp_f32 (rel err ~1e-7) instead of precise-division sequence
static __device__ __forceinline__ float silu_f(float v) {
    return v * __builtin_amdgcn_rcpf(1.0f + __expf(-v));
}

static __device__ __forceinline__ float4 ld4(const float* p) {
    return *reinterpret_cast<const float4*>(p);
}

static __device__ __forceinline__ void st4(float* p, float4 v) {
    *reinterpret_cast<float4*>(p) = v;
}

static __device__ __forceinline__ float4 add4(float4 a, float4 b) {
    return make_float4(a.x + b.x, a.y + b.y, a.z + b.z, a.w + b.w);
}

static __device__ __forceinline__ void silu_acc4(float4& s, float4 v) {
    s.x += silu_f(v.x);
    s.y += silu_f(v.y);
    s.z += silu_f(v.z);
    s.w += silu_f(v.w);
}

// ---- bf16 pack/unpack (RNE; feature j0+0 in low half) ----
static __device__ __forceinline__ unsigned int bf16r(float f) {
    unsigned int u = __float_as_uint(f);
    return (u + 0x7FFFu + ((u >> 16) & 1u)) >> 16;
}
// HW packed RNE convert: dst = bf16(a) | bf16(b)<<16  (T12 recipe; no builtin on gfx950)
static __device__ __forceinline__ unsigned int cvtpk(float a, float b) {
    unsigned int r;
    asm("v_cvt_pk_bf16_f32 %0, %1, %2" : "=v"(r) : "v"(a), "v"(b));
    return r;
}
static __device__ __forceinline__ uint4 pack8(const float* f) {
    uint4 r;
    r.x = cvtpk(f[0], f[1]);
    r.y = cvtpk(f[2], f[3]);
    r.z = cvtpk(f[4], f[5]);
    r.w = cvtpk(f[6], f[7]);
    return r;
}
static __device__ __forceinline__ void unpack8(uint4 u, float4& a, float4& b) {
    a.x = __uint_as_float(u.x << 16);
    a.y = __uint_as_float(u.x & 0xFFFF0000u);
    a.z = __uint_as_float(u.y << 16);
    a.w = __uint_as_float(u.y & 0xFFFF0000u);
    b.x = __uint_as_float(u.z << 16);
    b.y = __uint_as_float(u.z & 0xFFFF0000u);
    b.z = __uint_as_float(u.w << 16);
    b.w = __uint_as_float(u.w & 0xFFFF0000u);
}

// split fp32 -> bf16 hi + bf16 lo (lo = v - float(hi)); hi+lo ~ 16 mantissa bits
static __device__ __forceinline__ void hilo8(const float* f, uint4& h, uint4& lo) {
    h = pack8(f);
    float4 a, b;
    unpack8(h, a, b);
    lo.x = cvtpk(f[0] - a.x, f[1] - a.y);
    lo.y = cvtpk(f[2] - a.z, f[3] - a.w);
    lo.z = cvtpk(f[4] - b.x, f[5] - b.y);
    lo.w = cvtpk(f[6] - b.z, f[7] - b.w);
}

// XCD-affinity swizzle: each XCD owns a contiguous logical-tile range
static __device__ __forceinline__ int xcd_logical_block() {
    int chunk = (int)(gridDim.x >> 3);
    return (int)(blockIdx.x & 7) * chunk + (int)(blockIdx.x >> 3);
}

// ---------------- CSR build ----------------
__global__ void __launch_bounds__(256) bsum_k(const int* __restrict__ cnt,
                                              int* __restrict__ bsum, int E) {
    __shared__ int red[256];
    int t = threadIdx.x;
    int i = blockIdx.x * 256 + t;
    red[t] = (i < E) ? cnt[i] : 0;
    __syncthreads();
    #pragma unroll
    for (int off = 128; off > 0; off >>= 1) {
        if (t < off) red[t] += red[t + off];
        __syncthreads();
    }
    if (t == 0) bsum[blockIdx.x] = red[0];
}

__global__ void __launch_bounds__(1024) bscan_k(const int* __restrict__ bsum,
                                                int* __restrict__ bpre, int NB) {
    __shared__ int sh[1024];
    int t = threadIdx.x;
    int v0 = (t < NB) ? bsum[t] : 0;
    sh[t] = v0;
    __syncthreads();
    for (int off = 1; off < 1024; off <<= 1) {
        int v = (t >= off) ? sh[t - off] : 0;
        __syncthreads();
        sh[t] += v;
        __syncthreads();
    }
    if (t < NB) bpre[t] = sh[t] - v0;
}

__global__ void __launch_bounds__(256) offs_k(const int* __restrict__ cnt,
                                              const int* __restrict__ bpre,
                                              int* __restrict__ offs,
                                              int* __restrict__ cursor, int E) {
    __shared__ int sh[256];
    int t = threadIdx.x;
    int i = blockIdx.x * 256 + t;
    int v0 = (i < E) ? cnt[i] : 0;
    sh[t] = v0;
    __syncthreads();
    for (int off = 1; off < 256; off <<= 1) {
        int v = (t >= off) ? sh[t - off] : 0;
        __syncthreads();
        sh[t] += v;
        __syncthreads();
    }
    int ex = sh[t] - v0 + bpre[blockIdx.x];
    if (i < E) { offs[i] = ex; cursor[i] = ex; }
    if (i == E - 1) offs[E] = ex + v0;
}

__global__ void __launch_bounds__(256) scatter_k(const int* __restrict__ bsrc,
                                                 const int* __restrict__ bdst,
                                                 int* __restrict__ cursor,
                                                 int* __restrict__ srclist, int BE) {
    int i = blockIdx.x * 256 + threadIdx.x;
    if (i < BE) {
        int d = bdst[i];
        int p = __hip_atomic_fetch_add(&cursor[d], 1, __ATOMIC_RELAXED,
                                       __HIP_MEMORY_SCOPE_AGENT);
        srclist[p] = bsrc[i];
    }
}

// ---------------- prep (device body): tt + b2u + all MFMA B-fragment packs -------
// B-frag pack layout for mfma_f32_16x16x32_bf16 (B is K32 x N16):
//   lane l holds B[ks*32 + (l>>4)*8 + i][jt*16 + (l&15)], i=0..7, as 8 bf16.
// Buffer index: ((jt*2+ks)*64 + lane)*2 + {0=hi,1=lo}. One 64x64 matrix = 1024 uint4.
static __device__ void dev_prep(int b, int l,
                                const float* __restrict__ emb,
                                const float* __restrict__ mw1,
                                const float* __restrict__ mb1,
                                const float* __restrict__ mw2,
                                const float* __restrict__ mb2,
                                const float* __restrict__ uw1,
                                const float* __restrict__ uw2,
                                const float* __restrict__ iw2,
                                const float* __restrict__ iw1,
                                float* __restrict__ tt,
                                float* __restrict__ b2u,
                                uint4* __restrict__ fw2u,
                                uint4* __restrict__ fu1b,
                                uint4* __restrict__ fu2,
                                uint4* __restrict__ fp,
                                uint4* __restrict__ fiw2,
                                uint4* __restrict__ fp0,
                                uint4* __restrict__ fiw1) {
    if (b < 10) {            // tt[l][t] = emb[l][t] @ mw1[l][128:192] + mb1[l]
        int ll = b / NTYPES, t = b % NTYPES;
        const float* embl = emb + (size_t)ll * NTYPES * DDIM + (size_t)t * DDIM;
        const float* w1 = mw1 + (size_t)ll * 192 * DDIM;
        float s = mb1[ll * DDIM + l];
        #pragma unroll 8
        for (int k = 0; k < DDIM; ++k)
            s = fmaf(embl[k], w1[(HDIM + k) * DDIM + l], s);
        tt[(size_t)b * DDIM + l] = s;
        return;
    }
    if (b < 12) {            // b2u[l] = mb2[l] @ uw1[l][0:64]
        int ll = b - 10;
        const float* u1 = uw1 + (size_t)ll * 128 * DDIM;
        float s = 0.f;
        #pragma unroll 8
        for (int t = 0; t < DDIM; ++t)
            s = fmaf(mb2[ll * DDIM + t], u1[(size_t)t * DDIM + l], s);
        b2u[ll * DDIM + l] = s;
        return;
    }
    int pb = b - 12;
    int mat = pb >> 3, jt = (pb >> 1) & 3, ks = pb & 1;
    int k0 = ks * 32 + (l >> 4) * 8;
    int j = jt * 16 + (l & 15);
    float f[8];
    uint4* dst;
    if (mat <= 1) {          // fW2u: w2u[k][j] = mw2[l] @ uw1[l][0:64] on the fly
        const float* w2 = mw2 + (size_t)mat * DDIM * DDIM;
        const float* u1 = uw1 + (size_t)mat * 128 * DDIM;
        #pragma unroll
        for (int i = 0; i < 8; ++i) {
            float s = 0.f;
            #pragma unroll 8
            for (int t = 0; t < DDIM; ++t)
                s = fmaf(w2[(size_t)(k0 + i) * DDIM + t], u1[(size_t)t * DDIM + j], s);
            f[i] = s;
        }
        dst = fw2u + (size_t)mat * 1024;
    } else {
        const float* src;
        switch (mat) {
            case 2:  src = uw1 + 64 * 64;                    dst = fu1b;        break;
            case 3:  src = uw1 + 128 * 64 + 64 * 64;         dst = fu1b + 1024; break;
            case 4:  src = uw2;                              dst = fu2;         break;
            case 5:  src = uw2 + 4096;                       dst = fu2 + 1024;  break;
            case 6:  src = mw1 + (size_t)192 * 64;           dst = fp;          break;
            case 7:  src = mw1 + (size_t)192 * 64 + 64 * 64; dst = fp + 1024;   break;
            case 8:  src = iw2;                              dst = fiw2;        break;
            case 9:  src = mw1;                              dst = fp0;         break;
            case 10: src = mw1 + (size_t)64 * 64;            dst = fp0 + 1024;  break;
            case 11: src = iw1;                              dst = fiw1;        break;  // pa, K 0..63
            case 12: src = iw1 + (size_t)64 * 64;            dst = fiw1 + 1024; break;  // pa, K 64..127
            case 13: src = iw1 + (size_t)128 * 64;           dst = fiw1 + 2048; break;  // qa, K 0..63
            default: src = iw1 + (size_t)192 * 64;           dst = fiw1 + 3072; break;  // qa, K 64..127
        }
        #pragma unroll
        for (int i = 0; i < 8; ++i) f[i] = src[(size_t)(k0 + i) * DDIM + j];
    }
    uint4 h, lo;
    hilo8(f, h, lo);
    size_t di = ((size_t)(jt * 2 + ks) * 64 + l) * 2;
    dst[di] = h;
    dst[di + 1] = lo;
}

// merged prep + CSR count (independent work, one launch)
__global__ void __launch_bounds__(256) prepcount_k(
    const float* __restrict__ emb, const float* __restrict__ mw1,
    const float* __restrict__ mb1, const float* __restrict__ mw2,
    const float* __restrict__ mb2, const float* __restrict__ uw1,
    const float* __restrict__ uw2, const float* __restrict__ iw2,
    const float* __restrict__ iw1,
    float* __restrict__ tt, float* __restrict__ b2u,
    uint4* __restrict__ fw2u, uint4* __restrict__ fu1b, uint4* __restrict__ fu2,
    uint4* __restrict__ fp, uint4* __restrict__ fiw2, uint4* __restrict__ fp0,
    uint4* __restrict__ fiw1,
    const int* __restrict__ bdst, int* __restrict__ cnt, int BE) {
    int b = blockIdx.x;
    if (b < PREPB) {
        if (threadIdx.x < 64)
            dev_prep(b, threadIdx.x, emb, mw1, mb1, mw2, mb2, uw1, uw2, iw2, iw1,
                     tt, b2u, fw2u, fu1b, fu2, fp, fiw2, fp0, fiw1);
        return;
    }
    int i = (b - PREPB) * 256 + threadIdx.x;
    if (i < BE)
        __hip_atomic_fetch_add(&cnt[bdst[i]], 1, __ATOMIC_RELAXED, __HIP_MEMORY_SCOPE_AGENT);
}

// LDS A-tile: [64 rows][8 slots of 16B] bf16, XOR-swizzled within the row so the
// 128B-stride fragment reads don't 16-way bank-conflict (G4).
static __device__ __forceinline__ int slotIdx(int row, int slot) {
    return row * 8 + (slot ^ (row & 7));
}
// K=128 variant: 16 slots/row (XOR flips low 3 bits -> bijective within 16)
static __device__ __forceinline__ int slotIdx16(int row, int slot) {
    return row * 16 + (slot ^ (row & 7));
}

// A-frag (M16 x K32): lane l holds A[rowBase + (l&15)][ks*32 + (l>>4)*8 + i], i=0..7.
static __device__ __forceinline__ short8 ldFragA(const uint4* buf, int rowBase, int lane, int ks) {
    int row = rowBase + (lane & 15);
    int slot = ks * 4 + (lane >> 4);
    return as_s8(buf[slotIdx(row, slot)]);
}
static __device__ __forceinline__ short8 ldFragA16(const uint4* buf, int rowBase, int lane, int slot0) {
    int row = rowBase + (lane & 15);
    int slot = slot0 + (lane >> 4);
    return as_s8(buf[slotIdx16(row, slot)]);
}

static __device__ __forceinline__ void loadB(const uint4* __restrict__ frag, int jt, int lane,
                                             short8& h0, short8& h1, short8& l0, short8& l1) {
    const uint4* p0 = frag + ((size_t)(jt * 2 + 0) * 64 + lane) * 2;
    const uint4* p1 = frag + ((size_t)(jt * 2 + 1) * 64 + lane) * 2;
    h0 = as_s8(p0[0]); l0 = as_s8(p0[1]);
    h1 = as_s8(p1[0]); l1 = as_s8(p1[1]);
}

// one 16x16 output tile, K=64, split-precision: Ahi*Bhi + Alo*Bhi + Ahi*Blo
static __device__ __forceinline__ f32x4 gemm_tile(const uint4* Ahi, const uint4* Alo,
        int rowBase, int lane,
        short8 bh0, short8 bh1, short8 bl0, short8 bl1, f32x4 acc) {
    short8 ah0 = ldFragA(Ahi, rowBase, lane, 0);
    short8 ah1 = ldFragA(Ahi, rowBase, lane, 1);
    short8 al0 = ldFragA(Alo, rowBase, lane, 0);
    short8 al1 = ldFragA(Alo, rowBase, lane, 1);
    acc = __builtin_amdgcn_mfma_f32_16x16x32_bf16(ah0, bh0, acc, 0, 0, 0);
    acc = __builtin_amdgcn_mfma_f32_16x16x32_bf16(ah1, bh1, acc, 0, 0, 0);
    acc = __builtin_amdgcn_mfma_f32_16x16x32_bf16(al0, bh0, acc, 0, 0, 0);
    acc = __builtin_amdgcn_mfma_f32_16x16x32_bf16(al1, bh1, acc, 0, 0, 0);
    acc = __builtin_amdgcn_mfma_f32_16x16x32_bf16(ah0, bl0, acc, 0, 0, 0);
    acc = __builtin_amdgcn_mfma_f32_16x16x32_bf16(ah1, bl1, acc, 0, 0, 0);
    return acc;
}

// same, but over a K=64 half of a K=128-tiled LDS buffer (slot base sb = 0 or 8)
static __device__ __forceinline__ f32x4 gemm_tile16(const uint4* Ahi, const uint4* Alo,
        int rowBase, int lane, int sb,
        short8 bh0, short8 bh1, short8 bl0, short8 bl1, f32x4 acc) {
    short8 ah0 = ldFragA16(Ahi, rowBase, lane, sb + 0);
    short8 ah1 = ldFragA16(Ahi, rowBase, lane, sb + 4);
    short8 al0 = ldFragA16(Alo, rowBase, lane, sb + 0);
    short8 al1 = ldFragA16(Alo, rowBase, lane, sb + 4);
    acc = __builtin_amdgcn_mfma_f32_16x16x32_bf16(ah0, bh0, acc, 0, 0, 0);
    acc = __builtin_amdgcn_mfma_f32_16x16x32_bf16(ah1, bh1, acc, 0, 0, 0);
    acc = __builtin_amdgcn_mfma_f32_16x16x32_bf16(al0, bh0, acc, 0, 0, 0);
    acc = __builtin_amdgcn_mfma_f32_16x16x32_bf16(al1, bh1, acc, 0, 0, 0);
    acc = __builtin_amdgcn_mfma_f32_16x16x32_bf16(ah0, bl0, acc, 0, 0, 0);
    acc = __builtin_amdgcn_mfma_f32_16x16x32_bf16(ah1, bl1, acc, 0, 0, 0);
    return acc;
}

// ---------------- atom-side projection (MFMA): [N,128] @ [128,128] ----------------
static __device__ __forceinline__ void dev_atom_proj(
    int a0, int tid, int lane, int w,
    const float* __restrict__ AF, const uint4* __restrict__ fIw1,
    float* __restrict__ pa, float* __restrict__ qa, float* __restrict__ na, int N,
    uint4* sHi, uint4* sLo) {
    // ---- stage AF rows (hi/lo) + norm ----
    {
        int dl = tid >> 3, q = tid & 7;
        int a = a0 + dl;
        bool ok = a < N;
        const float* ar = AF + (size_t)(ok ? a : 0) * HDIM + q * 16;
        float4 v0 = ld4(ar + 0), v1 = ld4(ar + 4), v2 = ld4(ar + 8), v3 = ld4(ar + 12);
        float nrm = v0.x*v0.x + v0.y*v0.y + v0.z*v0.z + v0.w*v0.w
                  + v1.x*v1.x + v1.y*v1.y + v1.z*v1.z + v1.w*v1.w
                  + v2.x*v2.x + v2.y*v2.y + v2.z*v2.z + v2.w*v2.w
                  + v3.x*v3.x + v3.y*v3.y + v3.z*v3.z + v3.w*v3.w;
        nrm += __shfl_xor(nrm, 1, 64);
        nrm += __shfl_xor(nrm, 2, 64);
        nrm += __shfl_xor(nrm, 4, 64);
        if (q == 0 && ok) na[a] = sqrtf(nrm);
        float f0[8] = {v0.x, v0.y, v0.z, v0.w, v1.x, v1.y, v1.z, v1.w};
        float f1[8] = {v2.x, v2.y, v2.z, v2.w, v3.x, v3.y, v3.z, v3.w};
        if (!ok) {
            #pragma unroll
            for (int i = 0; i < 8; ++i) { f0[i] = 0.f; f1[i] = 0.f; }
        }
        uint4 h, l;
        hilo8(f0, h, l);
        int s0 = slotIdx16(dl, q * 2);
        sHi[s0] = h; sLo[s0] = l;
        hilo8(f1, h, l);
        int s1 = slotIdx16(dl, q * 2 + 1);
        sHi[s1] = h; sLo[s1] = l;
    }
    int jt = w & 3;
    const uint4* m0 = fIw1 + ((w < 4) ? 0 : 2048);
    short8 B0h0, B0h1, B0l0, B0l1, B1h0, B1h1, B1l0, B1l1;
    loadB(m0, jt, lane, B0h0, B0h1, B0l0, B0l1);            // K 0..63
    loadB(m0 + 1024, jt, lane, B1h0, B1h1, B1l0, B1l1);     // K 64..127
    __syncthreads();

    float* dst = (w < 4) ? pa : qa;
    int j = jt * 16 + (lane & 15);
    f32x4 z4 = {0.f, 0.f, 0.f, 0.f};
    #pragma unroll
    for (int rt = 0; rt < 4; ++rt) {
        f32x4 acc = gemm_tile16(sHi, sLo, rt * 16, lane, 0, B0h0, B0h1, B0l0, B0l1, z4);
        acc = gemm_tile16(sHi, sLo, rt * 16, lane, 8, B1h0, B1h1, B1l0, B1l1, acc);
        #pragma unroll
        for (int r = 0; r < 4; ++r) {
            int rowi = rt * 16 + (lane >> 4) * 4 + r;
            int a = a0 + rowi;
            if (a < N) dst[(size_t)a * DDIM + j] = acc[r];
        }
    }
}

__global__ void __launch_bounds__(512) atom_proj_k(
    const float* __restrict__ AF, const uint4* __restrict__ fIw1,
    float* __restrict__ pa, float* __restrict__ qa, float* __restrict__ na, int N) {
    __shared__ uint4 sHi[1024];
    __shared__ uint4 sLo[1024];
    int tid = threadIdx.x, lane = tid & 63;
    int w = __builtin_amdgcn_readfirstlane((int)(tid >> 6));
    int a0 = blockIdx.x * 64;
    if (a0 < N)
        dev_atom_proj(a0, tid, lane, w, AF, fIw1, pa, qa, na, N, sHi, sLo);
}

// ---------------- bond init (device body) ----------------
// storeX=false in the fused kernel: x is handed to the next phase via sXhi/sXlo.
static __device__ __forceinline__ void dev_bond_init(
    int lb, int tid, int lane, int w,
    const float* __restrict__ AF, const int* __restrict__ row, const int* __restrict__ col,
    const float* __restrict__ pa, const float* __restrict__ qa, const float* __restrict__ na,
    const float* __restrict__ b1, const uint4* __restrict__ fW2, const float* __restrict__ b2,
    const uint4* __restrict__ fP0,
    float* __restrict__ x, int* __restrict__ bt,
    float* __restrict__ pd, uint4* __restrict__ ps, int E,
    uint4* sAhi, uint4* sAlo, uint4* sXhi, uint4* sXlo, bool storeX) {
    int e0 = lb * EPB;

    // ---- P0: gather atoms, silu, classify ----
    {
        int dl = tid >> 3, q = tid & 7;
        int d = e0 + dl;
        bool ok = d < E;
        int dd = ok ? d : 0;
        int r = row[dd], c = col[dd];
        int jq = q * 8;

        const float* hi = AF + (size_t)r * HDIM + q * 16;
        const float* hj = AF + (size_t)c * HDIM + q * 16;
        float dt = 0.f;
        #pragma unroll
        for (int k = 0; k < 16; k += 4) {
            float4 a4 = ld4(hi + k), b4 = ld4(hj + k);
            dt += a4.x * b4.x + a4.y * b4.y + a4.z * b4.z + a4.w * b4.w;
        }
        dt += __shfl_xor(dt, 1, 64);
        dt += __shfl_xor(dt, 2, 64);
        dt += __shfl_xor(dt, 4, 64);
        if (q == 0 && ok) {
            float nr = fmaxf(na[r], 1e-8f), nc = fmaxf(na[c], 1e-8f);
            float sim = dt / (nr * nc);
            int t = 0;
            if (sim > 0.8f) t = 1;
            if (sim > 0.9f) t = 2;
            if (sim < 0.3f) t = 3;
            bt[d] = t;
        }

        const float* pr = pa + (size_t)r * DDIM + jq;
        const float* qc = qa + (size_t)c * DDIM + jq;
        float4 p0 = ld4(pr + 0), p1 = ld4(pr + 4);
        float4 q0 = ld4(qc + 0), q1 = ld4(qc + 4);
        float hv[8];
        hv[0] = silu_f(p0.x + q0.x + b1[jq + 0]);
        hv[1] = silu_f(p0.y + q0.y + b1[jq + 1]);
        hv[2] = silu_f(p0.z + q0.z + b1[jq + 2]);
        hv[3] = silu_f(p0.w + q0.w + b1[jq + 3]);
        hv[4] = silu_f(p1.x + q1.x + b1[jq + 4]);
        hv[5] = silu_f(p1.y + q1.y + b1[jq + 5]);
        hv[6] = silu_f(p1.z + q1.z + b1[jq + 6]);
        hv[7] = silu_f(p1.w + q1.w + b1[jq + 7]);
        if (!ok) {
            #pragma unroll
            for (int i = 0; i < 8; ++i) hv[i] = 0.f;
        }
        uint4 h4, l4;
        hilo8(hv, h4, l4);
        int si = slotIdx(dl, q);
        sAhi[si] = h4; sAlo[si] = l4;
    }
    int jt = w & 3, mh = w >> 2;
    short8 W2h0, W2h1, W2l0, W2l1;
    loadB(fW2, jt, lane, W2h0, W2h1, W2l0, W2l1);
    __syncthreads();

    // ---- P1: x = h@iw2 + b2 ----
    int rb0 = mh * 32, rb1 = mh * 32 + 16;
    f32x4 z4 = {0.f, 0.f, 0.f, 0.f};
    f32x4 acc0 = gemm_tile(sAhi, sAlo, rb0, lane, W2h0, W2h1, W2l0, W2l1, z4);
    f32x4 acc1 = gemm_tile(sAhi, sAlo, rb1, lane, W2h0, W2h1, W2l0, W2l1, z4);
    int j = jt * 16 + (lane & 15);
    float b2j = b2[j];
    unsigned short* hX = (unsigned short*)sXhi;
    unsigned short* lX = (unsigned short*)sXlo;
    #pragma unroll
    for (int r = 0; r < 4; ++r) {
        int rowi = rb0 + (lane >> 4) * 4 + r;
        int e = e0 + rowi;
        float xn = acc0[r] + b2j;
        if (storeX && e < E) x[(size_t)e * DDIM + j] = xn;
        unsigned int hb = bf16r(xn);
        float lov = xn - __uint_as_float(hb << 16);
        int ui = (rowi * 8 + ((j >> 3) ^ (rowi & 7))) * 8 + (j & 7);
        hX[ui] = (unsigned short)hb;
        lX[ui] = (unsigned short)bf16r(lov);
    }
    #pragma unroll
    for (int r = 0; r < 4; ++r) {
        int rowi = rb1 + (lane >> 4) * 4 + r;
        int e = e0 + rowi;
        float xn = acc1[r] + b2j;
        if (storeX && e < E) x[(size_t)e * DDIM + j] = xn;
        unsigned int hb = bf16r(xn);
        float lov = xn - __uint_as_float(hb << 16);
        int ui = (rowi * 8 + ((j >> 3) ^ (rowi & 7))) * 8 + (j & 7);
        hX[ui] = (unsigned short)hb;
        lX[ui] = (unsigned short)bf16r(lov);
    }
    __syncthreads();    // x staged; P1 h-reads done before P2 sA-writes

    // ---- P2: layer-0 proj. wave w -> 16-col strip of 128-wide output.
    const uint4* fPw = (w < 4) ? fP0 : (fP0 + 1024);
    int jp = w & 3;
    short8 Ph0, Ph1, Pl0, Pl1;
    loadB(fPw, jp, lane, Ph0, Ph1, Pl0, Pl1);
    f32x4 q0 = gemm_tile(sXhi, sXlo, 0,  lane, Ph0, Ph1, Pl0, Pl1, z4);
    f32x4 q1 = gemm_tile(sXhi, sXlo, 16, lane, Ph0, Ph1, Pl0, Pl1, z4);
    f32x4 q2 = gemm_tile(sXhi, sXlo, 32, lane, Ph0, Ph1, Pl0, Pl1, z4);
    f32x4 q3 = gemm_tile(sXhi, sXlo, 48, lane, Ph0, Ph1, Pl0, Pl1, z4);
    unsigned short* hA = (unsigned short*)sAhi;
    if (w < 4) {
        int jd = jp * 16 + (lane & 15);
        #pragma unroll
        for (int mt = 0; mt < 4; ++mt) {
            f32x4 qq = (mt == 0) ? q0 : (mt == 1) ? q1 : (mt == 2) ? q2 : q3;
            #pragma unroll
            for (int r = 0; r < 4; ++r) {
                int rowi = mt * 16 + (lane >> 4) * 4 + r;
                int e = e0 + rowi;
                if (e < E) pd[(size_t)e * DDIM + jd] = qq[r];
            }
        }
    } else {
        int js = jp * 16 + (lane & 15);
        #pragma unroll
        for (int mt = 0; mt < 4; ++mt) {
            f32x4 qq = (mt == 0) ? q0 : (mt == 1) ? q1 : (mt == 2) ? q2 : q3;
            #pragma unroll
            for (int r = 0; r < 4; ++r) {
                int rowi = mt * 16 + (lane >> 4) * 4 + r;
                int ui = (rowi * 8 + ((js >> 3) ^ (rowi & 7))) * 8 + (js & 7);
                hA[ui] = (unsigned short)bf16r(qq[r]);
            }
        }
    }
    __syncthreads();
    {
        int dl = tid >> 3, q = tid & 7;
        int d = e0 + dl;
        if (d < E) ps[(size_t)d * 8 + q] = sAhi[slotIdx(dl, q)];
    }
}

__global__ void __launch_bounds__(512, 4) bond_init2_k(
    const float* __restrict__ AF, const int* __restrict__ row, const int* __restrict__ col,
    const float* __restrict__ pa, const float* __restrict__ qa, const float* __restrict__ na,
    const float* __restrict__ b1, const uint4* __restrict__ fW2, const float* __restrict__ b2,
    const uint4* __restrict__ fP0,
    float* __restrict__ x, int* __restrict__ bt,
    float* __restrict__ pd, uint4* __restrict__ ps, int E) {
    __shared__ uint4 sAhi[512];
    __shared__ uint4 sAlo[512];
    __shared__ uint4 sXhi[512];
    __shared__ uint4 sXlo[512];
    int nEB = (E + EPB - 1) / EPB;
    int lb = xcd_logical_block();
    if (lb >= nEB) return;
    int tid = threadIdx.x, lane = tid & 63;
    int w = __builtin_amdgcn_readfirstlane((int)(tid >> 6));
    dev_bond_init(lb, tid, lane, w, AF, row, col, pa, qa, na, b1, fW2, b2, fP0,
                  x, bt, pd, ps, E, sAhi, sAlo, sXhi, sXlo, true);
}

// proj (x from global) — fallback path only (used if ws too small for pd2/ps2)
__global__ void __launch_bounds__(256) proj_k(const float* __restrict__ x,
                                              const float* __restrict__ w1 /*[192][64]*/,
                                              float* __restrict__ pd, uint4* __restrict__ ps,
                                              int E) {
    int lane = threadIdx.x & 63;
    int w = __builtin_amdgcn_readfirstlane((int)(threadIdx.x >> 6));
    int e = blockIdx.x * EPB + lane;
    bool ok = e < E;
    int eidx = ok ? e : 0;
    int j0 = w * 16;
    const float* xr = x + (size_t)eidx * DDIM;

    float apd[16], aps[16];
    #pragma unroll
    for (int jj = 0; jj < 16; ++jj) { apd[jj] = 0.f; aps[jj] = 0.f; }
    #pragma unroll 2
    for (int c = 0; c < 16; ++c) {
        float4 v = ld4(xr + c * 4);
        float xv[4] = {v.x, v.y, v.z, v.w};
        #pragma unroll
        for (int kk = 0; kk < 4; ++kk) {
            int k = c * 4 + kk;
            const float* wd = w1 + (size_t)k * DDIM + j0;
            const float* wsv = w1 + (size_t)(DDIM + k) * DDIM + j0;
            #pragma unroll
            for (int jj = 0; jj < 16; ++jj) {
                apd[jj] = fmaf(xv[kk], wd[jj], apd[jj]);
                aps[jj] = fmaf(xv[kk], wsv[jj], aps[jj]);
            }
        }
    }
    if (ok) {
        float* pr = pd + (size_t)e * DDIM + j0;
        st4(pr + 0,  make_float4(apd[0],  apd[1],  apd[2],  apd[3]));
        st4(pr + 4,  make_float4(apd[4],  apd[5],  apd[6],  apd[7]));
        st4(pr + 8,  make_float4(apd[8],  apd[9],  apd[10], apd[11]));
        st4(pr + 12, make_float4(apd[12], apd[13], apd[14], apd[15]));
        ps[(size_t)e * 8 + 2 * w + 0] = pack8(aps + 0);
        ps[(size_t)e * 8 + 2 * w + 1] = pack8(aps + 8);
    }
}

// ---------------- fused gather + update (device body) ----------------
// loadX=false (fused): x hi/lo already in sXhi/sXlo from the previous phase.
// storeX3: write xnew to global in P3 (final layer / fallback).
static __device__ __forceinline__ void dev_layer(
    int lb, int tid, int lane, int w,
    float* __restrict__ x, const float* __restrict__ pd, const uint4* __restrict__ ps,
    const float* __restrict__ tt_l, const int* __restrict__ bt,
    const int* __restrict__ offs, const int* __restrict__ srclist,
    const int* __restrict__ cnt,
    const uint4* __restrict__ fW2u, const float* __restrict__ b2u,
    const uint4* __restrict__ fU1b, const float* __restrict__ ub1,
    const uint4* __restrict__ fU2, const float* __restrict__ ub2,
    const uint4* __restrict__ fP, float* __restrict__ pdn, uint4* __restrict__ psn,
    int E, const int* __restrict__ erow, const int* __restrict__ gbatch,
    float* __restrict__ gfeat, int doPool,
    uint4* sAhi, uint4* sAlo, uint4* sXhi, uint4* sXlo,
    float* degLDS, int* gidLDS, int* sIdx, bool loadX, bool storeX3) {
    int e0 = lb * EPB;
    int pb0 = offs[e0];          // uniform

    // ---- P1 ----
    {
        int dl = tid >> 3, q = tid & 7;
        int d = e0 + dl;
        bool ok = d < E;
        int dd = ok ? d : 0;
        int jq = q * 8;
        float4 xv0 = make_float4(0, 0, 0, 0), xv1 = xv0;
        if (loadX) {
            const float* xr = x + (size_t)dd * DDIM + jq;
            xv0 = ld4(xr + 0); xv1 = ld4(xr + 4);   // issued early, used late
        }
        int dc = cnt[dd];
        int rAtom = (doPool && ok) ? erow[dd] : 0;
        const float* pr = pd + (size_t)dd * DDIM + jq;
        const float* tp = tt_l + (size_t)bt[dd] * DDIM + jq;
        float4 b0 = add4(ld4(pr + 0), ld4(tp + 0));
        float4 b1 = add4(ld4(pr + 4), ld4(tp + 4));
        int p0v = ok ? offs[d] : pb0, p1v = ok ? offs[d + 1] : pb0;

        // block srclist prefetch (coalesced, de-duplicates the 8x per-bond reads)
        int emax = min(e0 + EPB, E);
        int pT = offs[emax] - pb0;
        for (int i = tid; i < pT && i < SCAP; i += 512) sIdx[i] = srclist[pb0 + i];
        __syncthreads();

        float4 s0 = make_float4(0, 0, 0, 0), s1 = s0;
        if (p1v - pb0 <= SCAP) {
            int li = p0v - pb0, le = p1v - pb0;
            for (; li + 4 <= le; li += 4) {
                uint4 u0 = ps[(size_t)sIdx[li + 0] * 8 + q];
                uint4 u1 = ps[(size_t)sIdx[li + 1] * 8 + q];
                uint4 u2 = ps[(size_t)sIdx[li + 2] * 8 + q];
                uint4 u3 = ps[(size_t)sIdx[li + 3] * 8 + q];
                float4 a, b;
                unpack8(u0, a, b);
                silu_acc4(s0, add4(b0, a));
                silu_acc4(s1, add4(b1, b));
                unpack8(u1, a, b);
                silu_acc4(s0, add4(b0, a));
                silu_acc4(s1, add4(b1, b));
                unpack8(u2, a, b);
                silu_acc4(s0, add4(b0, a));
                silu_acc4(s1, add4(b1, b));
                unpack8(u3, a, b);
                silu_acc4(s0, add4(b0, a));
                silu_acc4(s1, add4(b1, b));
            }
            for (; li < le; ++li) {
                uint4 u0 = ps[(size_t)sIdx[li] * 8 + q];
                float4 a, b;
                unpack8(u0, a, b);
                silu_acc4(s0, add4(b0, a));
                silu_acc4(s1, add4(b1, b));
            }
        } else {
            int p = p0v;
            for (; p + 4 <= p1v; p += 4) {
                uint4 u0 = ps[(size_t)srclist[p + 0] * 8 + q];
                uint4 u1 = ps[(size_t)srclist[p + 1] * 8 + q];
                uint4 u2 = ps[(size_t)srclist[p + 2] * 8 + q];
                uint4 u3 = ps[(size_t)srclist[p + 3] * 8 + q];
                float4 a, b;
                unpack8(u0, a, b);
                silu_acc4(s0, add4(b0, a));
                silu_acc4(s1, add4(b1, b));
                unpack8(u1, a, b);
                silu_acc4(s0, add4(b0, a));
                silu_acc4(s1, add4(b1, b));
                unpack8(u2, a, b);
                silu_acc4(s0, add4(b0, a));
                silu_acc4(s1, add4(b1, b));
                unpack8(u3, a, b);
                silu_acc4(s0, add4(b0, a));
                silu_acc4(s1, add4(b1, b));
            }
            for (; p < p1v; ++p) {
                uint4 u0 = ps[(size_t)srclist[p] * 8 + q];
                float4 a, b;
                unpack8(u0, a, b);
                silu_acc4(s0, add4(b0, a));
                silu_acc4(s1, add4(b1, b));
            }
        }
        float inv = 1.0f / fmaxf((float)dc, 1.0f);
        float sv[8] = {s0.x * inv, s0.y * inv, s0.z * inv, s0.w * inv,
                       s1.x * inv, s1.y * inv, s1.z * inv, s1.w * inv};
        if (!ok) {
            #pragma unroll
            for (int i = 0; i < 8; ++i) sv[i] = 0.f;
        }
        uint4 h4, l4;
        int si = slotIdx(dl, q);
        hilo8(sv, h4, l4);
        sAhi[si] = h4; sAlo[si] = l4;
        if (loadX) {
            float xf[8] = {xv0.x, xv0.y, xv0.z, xv0.w, xv1.x, xv1.y, xv1.z, xv1.w};
            if (!ok) {
                #pragma unroll
                for (int i = 0; i < 8; ++i) xf[i] = 0.f;
            }
            hilo8(xf, h4, l4);
            sXhi[si] = h4; sXlo[si] = l4;
        }
        if (q == 0) {
            degLDS[dl] = (ok && dc > 0) ? 1.0f : 0.0f;
            gidLDS[dl] = (doPool && ok) ? gbatch[rAtom] : -1;
        }
    }
    // preload loop-invariant B-frags (independent of LDS; overlaps barrier wait)
    int jt = w & 3, mh = w >> 2;
    short8 A2h0, A2h1, A2l0, A2l1;   // W2u
    short8 U1h0, U1h1, U1l0, U1l1;   // Uw1b
    loadB(fW2u, jt, lane, A2h0, A2h1, A2l0, A2l1);
    loadB(fU1b, jt, lane, U1h0, U1h1, U1l0, U1l1);
    __syncthreads();

    // ---- P2: h = silu((inv*s)@W2u + x@Uw1b + bias) ----
    int rb0 = mh * 32, rb1 = mh * 32 + 16;
    f32x4 z4 = {0.f, 0.f, 0.f, 0.f};
    f32x4 acc0 = z4, acc1 = z4;
    acc0 = gemm_tile(sAhi, sAlo, rb0, lane, A2h0, A2h1, A2l0, A2l1, acc0);
    acc0 = gemm_tile(sXhi, sXlo, rb0, lane, U1h0, U1h1, U1l0, U1l1, acc0);
    acc1 = gemm_tile(sAhi, sAlo, rb1, lane, A2h0, A2h1, A2l0, A2l1, acc1);
    acc1 = gemm_tile(sXhi, sXlo, rb1, lane, U1h0, U1h1, U1l0, U1l1, acc1);
    __syncthreads();                       // all s/x fragment reads done
    int j = jt * 16 + (lane & 15);
    float ub1j = ub1[j], b2uj = b2u[j];
    unsigned short* hA = (unsigned short*)sAhi;
    unsigned short* lA = (unsigned short*)sAlo;
    #pragma unroll
    for (int r = 0; r < 4; ++r) {
        int row = rb0 + (lane >> 4) * 4 + r;
        float hv = silu_f(acc0[r] + ub1j + degLDS[row] * b2uj);
        unsigned int hb = bf16r(hv);
        float lov = hv - __uint_as_float(hb << 16);
        int ui = (row * 8 + ((j >> 3) ^ (row & 7))) * 8 + (j & 7);
        hA[ui] = (unsigned short)hb;
        lA[ui] = (unsigned short)bf16r(lov);
    }
    #pragma unroll
    for (int r = 0; r < 4; ++r) {
        int row = rb1 + (lane >> 4) * 4 + r;
        float hv = silu_f(acc1[r] + ub1j + degLDS[row] * b2uj);
        unsigned int hb = bf16r(hv);
        float lov = hv - __uint_as_float(hb << 16);
        int ui = (row * 8 + ((j >> 3) ^ (row & 7))) * 8 + (j & 7);
        hA[ui] = (unsigned short)hb;
        lA[ui] = (unsigned short)bf16r(lov);
    }
    __syncthreads();                       // h staged

    // ---- P3: o = h@Uw2 + ub2; xnew = x(LDS) + o ----
    short8 U2h0, U2h1, U2l0, U2l1;
    loadB(fU2, jt, lane, U2h0, U2h1, U2l0, U2l1);
    f32x4 o0 = gemm_tile(sAhi, sAlo, rb0, lane, U2h0, U2h1, U2l0, U2l1, z4);
    f32x4 o1 = gemm_tile(sAhi, sAlo, rb1, lane, U2h0, U2h1, U2l0, U2l1, z4);
    float ub2j = ub2[j];
    bool haveP = (fP != nullptr);
    unsigned short* hX = (unsigned short*)sXhi;
    unsigned short* lX = (unsigned short*)sXlo;
    float xnv0[4], xnv1[4];
    #pragma unroll
    for (int r = 0; r < 4; ++r) {
        int row = rb0 + (lane >> 4) * 4 + r;
        int e = e0 + row;
        int ui = (row * 8 + ((j >> 3) ^ (row & 7))) * 8 + (j & 7);
        float xvv = __uint_as_float((unsigned int)hX[ui] << 16)
                  + __uint_as_float((unsigned int)lX[ui] << 16);
        float xn = xvv + o0[r] + ub2j;
        xnv0[r] = xn;
        if (storeX3 && e < E) x[(size_t)e * DDIM + j] = xn;
        if (haveP) {
            unsigned int hb = bf16r(xn);
            float lov = xn - __uint_as_float(hb << 16);
            hX[ui] = (unsigned short)hb;
            lX[ui] = (unsigned short)bf16r(lov);
        }
    }
    #pragma unroll
    for (int r = 0; r < 4; ++r) {
        int row = rb1 + (lane >> 4) * 4 + r;
        int e = e0 + row;
        int ui = (row * 8 + ((j >> 3) ^ (row & 7))) * 8 + (j & 7);
        float xvv = __uint_as_float((unsigned int)hX[ui] << 16)
                  + __uint_as_float((unsigned int)lX[ui] << 16);
        float xn = xvv + o1[r] + ub2j;
        xnv1[r] = xn;
        if (storeX3 && e < E) x[(size_t)e * DDIM + j] = xn;
        if (haveP) {
            unsigned int hb = bf16r(xn);
            float lov = xn - __uint_as_float(hb << 16);
            hX[ui] = (unsigned short)hb;
            lX[ui] = (unsigned short)bf16r(lov);
        }
    }
    if (!haveP) {
        if (doPool) {
            // ---- fused pooling: per-block partial sums -> gfeat atomics ----
            __syncthreads();               // P3 LDS reads done; reuse sAhi
            float* poolB = (float*)sAhi;   // [4][64]
            if (tid < 256) poolB[tid] = 0.f;
            __syncthreads();
            int gid0 = gidLDS[0];          // e0 < E always -> valid
            bool uni = (gidLDS[EPB - 1] == gid0);
            if (uni) {
                float s = xnv0[0] + xnv0[1] + xnv0[2] + xnv0[3]
                        + xnv1[0] + xnv1[1] + xnv1[2] + xnv1[3];
                atomicAdd(&poolB[j], s);
            } else {
                #pragma unroll
                for (int r = 0; r < 4; ++r) {
                    int row = rb0 + (lane >> 4) * 4 + r;
                    int g = gidLDS[row];
                    if (g >= 0) {
                        int sl = g - gid0;
                        if (sl < 4) atomicAdd(&poolB[sl * DDIM + j], xnv0[r]);
                        else atomicAdd(&gfeat[(size_t)g * DDIM + j], xnv0[r]);
                    }
                }
                #pragma unroll
                for (int r = 0; r < 4; ++r) {
                    int row = rb1 + (lane >> 4) * 4 + r;
                    int g = gidLDS[row];
                    if (g >= 0) {
                        int sl = g - gid0;
                        if (sl < 4) atomicAdd(&poolB[sl * DDIM + j], xnv1[r]);
                        else atomicAdd(&gfeat[(size_t)g * DDIM + j], xnv1[r]);
                    }
                }
            }
            __syncthreads();
            if (tid < 256) {
                int sl = tid >> 6;
                int g = gid0 + sl;
                float v = poolB[tid];
                if (v != 0.f && g < NGRAPHS)
                    atomicAdd(&gfeat[(size_t)g * DDIM + (tid & 63)], v);
            }
        }
        return;
    }
    __syncthreads();    // xnew staged; orders P3 A-reads before P4 A-writes

    // ---- P4: next-layer proj. wave w -> 16-col strip of the 128-wide output.
    const uint4* fPw = (w < 4) ? fP : (fP + 1024);
    int jp = w & 3;
    short8 Ph0, Ph1, Pl0, Pl1;
    loadB(fPw, jp, lane, Ph0, Ph1, Pl0, Pl1);
    f32x4 q0 = gemm_tile(sXhi, sXlo, 0,  lane, Ph0, Ph1, Pl0, Pl1, z4);
    f32x4 q1 = gemm_tile(sXhi, sXlo, 16, lane, Ph0, Ph1, Pl0, Pl1, z4);
    f32x4 q2 = gemm_tile(sXhi, sXlo, 32, lane, Ph0, Ph1, Pl0, Pl1, z4);
    f32x4 q3 = gemm_tile(sXhi, sXlo, 48, lane, Ph0, Ph1, Pl0, Pl1, z4);
    if (w < 4) {
        int jd = jp * 16 + (lane & 15);
        #pragma unroll
        for (int mt = 0; mt < 4; ++mt) {
            f32x4 qq = (mt == 0) ? q0 : (mt == 1) ? q1 : (mt == 2) ? q2 : q3;
            #pragma unroll
            for (int r = 0; r < 4; ++r) {
                int row = mt * 16 + (lane >> 4) * 4 + r;
                int e = e0 + row;
                if (e < E) pdn[(size_t)e * DDIM + jd] = qq[r];
            }
        }
    } else {
        int js = jp * 16 + (lane & 15);
        #pragma unroll
        for (int mt = 0; mt < 4; ++mt) {
            f32x4 qq = (mt == 0) ? q0 : (mt == 1) ? q1 : (mt == 2) ? q2 : q3;
            #pragma unroll
            for (int r = 0; r < 4; ++r) {
                int row = mt * 16 + (lane >> 4) * 4 + r;
                int ui = (row * 8 + ((js >> 3) ^ (row & 7))) * 8 + (js & 7);
                hA[ui] = (unsigned short)bf16r(qq[r]);
            }
        }
    }
    __syncthreads();
    {
        int dl = tid >> 3, q = tid & 7;
        int d = e0 + dl;
        if (d < E) psn[(size_t)d * 8 + q] = sAhi[slotIdx(dl, q)];
    }
}

__global__ void __launch_bounds__(512, 4) layer_k(
    float* __restrict__ x, const float* __restrict__ pd, const uint4* __restrict__ ps,
    const float* __restrict__ tt_l, const int* __restrict__ bt,
    const int* __restrict__ offs, const int* __restrict__ srclist,
    const int* __restrict__ cnt,
    const uint4* __restrict__ fW2u, const float* __restrict__ b2u,
    const uint4* __restrict__ fU1b, const float* __restrict__ ub1,
    const uint4* __restrict__ fU2, const float* __restrict__ ub2,
    const uint4* __restrict__ fP,
    float* __restrict__ pdn, uint4* __restrict__ psn, int E,
    const int* __restrict__ erow, const int* __restrict__ gbatch,
    float* __restrict__ gfeat, int doPool) {
    __shared__ uint4 sAhi[512];
    __shared__ uint4 sAlo[512];
    __shared__ uint4 sXhi[512];
    __shared__ uint4 sXlo[512];
    __shared__ float degLDS[64];
    __shared__ int   gidLDS[64];
    __shared__ int   sIdx[SCAP];
    int nEB = (E + EPB - 1) / EPB;
    int lb = xcd_logical_block();
    if (lb >= nEB) return;
    int tid = threadIdx.x, lane = tid & 63;
    int w = __builtin_amdgcn_readfirstlane((int)(tid >> 6));
    dev_layer(lb, tid, lane, w, x, pd, ps, tt_l, bt, offs, srclist, cnt,
              fW2u, b2u, fU1b, ub1, fU2, ub2, fP, pdn, psn, E,
              erow, gbatch, gfeat, doPool,
              sAhi, sAlo, sXhi, sXlo, degLDS, gidLDS, sIdx, true, true);
}

static __device__ __forceinline__ int lower_bound_bb(const int* __restrict__ row,
                                                     const int* __restrict__ batch,
                                                     int E, int g) {
    int lo = 0, hi = E;
    while (lo < hi) {
        int m = (lo + hi) >> 1;
        if (batch[row[m]] < g) lo = m + 1; else hi = m;
    }
    return lo;
}

__global__ void __launch_bounds__(64) pool_final_k(
    const int* __restrict__ row, const int* __restrict__ batch,
    float* __restrict__ gfeat, int E) {
    int g = blockIdx.x, j = threadIdx.x;
    int s = lower_bound_bb(row, batch, E, g);
    int t = lower_bound_bb(row, batch, E, g + 1);
    float cnt = fmaxf((float)(t - s), 1.0f);
    gfeat[g * DDIM + j] /= cnt;
}

// ---------------- cooperative fused pipeline ----------------
// A0: atom_proj (+gfeat zero) | A1: bond_init | B: layer0 | C: layer1+pool | D: final.
// x is handed between phases via persistent sXhi/sXlo LDS (bit-identical to the
// separate-kernel path) and written to global exactly once (phase C).
__global__ void __launch_bounds__(512, 8) fused_k(
    float* x, const int* row, const int* col,
    const float* AF, const uint4* fIw1, float* pa, float* qa, float* na, int N,
    const float* ib1, const uint4* fIw2, const float* ib2, const uint4* fP0,
    int* bt, float* pd, uint4* ps,
    const float* tt, const int* offs, const int* srclist, const int* cnt,
    const uint4* fW2u, const float* b2u, const uint4* fU1b, const float* ub1,
    const uint4* fU2, const float* ub2, const uint4* fP,
    float* pd2, uint4* ps2,
    const int* gbatch, float* gfeat, int E) {
    __shared__ uint4 U1[1024];    // atom sHi | sAhi(0:512)+sAlo(512:1024)
    __shared__ uint4 U2[1024];    // atom sLo | sXhi(0:512)+sXlo(512:1024)
    __shared__ float degLDS[64];
    __shared__ int   gidLDS[64];
    __shared__ int   sIdx[SCAP];
    cg::grid_group grid = cg::this_grid();
    int tid = threadIdx.x, lane = tid & 63;
    int w = __builtin_amdgcn_readfirstlane((int)(tid >> 6));
    uint4* sAhi = U1;
    uint4* sAlo = U1 + 512;
    uint4* sXhi = U2;
    uint4* sXlo = U2 + 512;

    // ---- A0: atom projections; one idle block zeroes gfeat ----
    if ((int)blockIdx.x * 64 < N)
        dev_atom_proj((int)blockIdx.x * 64, tid, lane, w, AF, fIw1, pa, qa, na, N, U1, U2);
    if (blockIdx.x == gridDim.x - 1)
        for (int i = tid; i < NGRAPHS * DDIM; i += 512) gfeat[i] = 0.f;
    __threadfence();
    grid.sync();

    int nEB = (E + EPB - 1) / EPB;
    int lb = xcd_logical_block();

    // ---- A1: bond init (x stays in sX; no global x store) ----
    if (lb < nEB)
        dev_bond_init(lb, tid, lane, w, AF, row, col, pa, qa, na, ib1, fIw2, ib2, fP0,
                      x, bt, pd, ps, E, sAhi, sAlo, sXhi, sXlo, false);
    __threadfence();
    grid.sync();

    // ---- B: layer 0 (fused next-layer proj; x from/into sX only) ----
    if (lb < nEB)
        dev_layer(lb, tid, lane, w, x, pd, ps, tt, bt, offs, srclist, cnt,
                  fW2u, b2u, fU1b, ub1, fU2, ub2, fP, pd2, ps2, E,
                  row, gbatch, gfeat, 0,
                  sAhi, sAlo, sXhi, sXlo, degLDS, gidLDS, sIdx, false, false);
    __threadfence();
    grid.sync();

    // ---- C: layer 1 + pooling; final x store ----
    if (lb < nEB)
        dev_layer(lb, tid, lane, w, x, pd2, ps2, tt + NTYPES * DDIM, bt, offs, srclist, cnt,
                  fW2u + 1024, b2u + DDIM, fU1b + 1024, ub1 + DDIM,
                  fU2 + 1024, ub2 + DDIM, nullptr, nullptr, nullptr, E,
                  row, gbatch, gfeat, 1,
                  sAhi, sAlo, sXhi, sXlo, degLDS, gidLDS, sIdx, false, true);
    __threadfence();
    grid.sync();

    // ---- D: pool finalize ----
    if ((int)blockIdx.x < NGRAPHS && tid < 64) {
        int g = blockIdx.x, j = tid;
        int s = lower_bound_bb(row, gbatch, E, g);
        int t = lower_bound_bb(row, gbatch, E, g + 1);
        float c = fmaxf((float)(t - s), 1.0f);
        gfeat[g * DDIM + j] /= c;
    }
}

extern "C" void kernel_launch(void* const* d_in, const int* in_sizes, int n_in,
                              void* d_out, int out_size, void* d_ws, size_t ws_size,
                              hipStream_t stream) {
    (void)n_in; (void)out_size;
    const float* AF    = (const float*)d_in[0];
    const int*   batch = (const int*)d_in[3];
    const int*   edge_index      = (const int*)d_in[4];
    const int*   bond_edge_index = (const int*)d_in[5];
    const float* iw1 = (const float*)d_in[6];
    const float* ib1 = (const float*)d_in[7];
    const float* iw2 = (const float*)d_in[8];
    const float* ib2 = (const float*)d_in[9];
    const float* emb = (const float*)d_in[10];
    const float* mw1 = (const float*)d_in[11];
    const float* mb1 = (const float*)d_in[12];
    const float* mw2 = (const float*)d_in[13];
    const float* mb2 = (const float*)d_in[14];
    const float* uw1 = (const float*)d_in[15];
    const float* ub1 = (const float*)d_in[16];
    const float* uw2 = (const float*)d_in[17];
    const float* ub2 = (const float*)d_in[18];

    const int N  = in_sizes[0] / HDIM;
    const int E  = in_sizes[4] / 2;
    const int BE = in_sizes[5] / 2;
    const int NB = (E + 255) / 256;
    const int EB = (E + EPB - 1) / EPB;
    const int APB = (N + 63) / 64;                  // atom blocks (64 atoms/block)
    const int EBS = ((EB + 7) / 8) * 8;             // swizzled grid (multiple of 8)
    const int CNTB = (BE + 255) / 256;

    float* xout  = (float*)d_out;                 // [E,64]
    float* gfeat = xout + (size_t)E * DDIM;       // [16,64]

    // workspace layout
    char* w = (char*)d_ws;
    float* tt       = (float*)w;  w += sizeof(float) * 2 * NTYPES * DDIM;
    float* b2u      = (float*)w;  w += sizeof(float) * 2 * DDIM;
    w = (char*)(((uintptr_t)w + 15) & ~(uintptr_t)15);
    // MFMA weight fragments (hi/lo bf16)
    uint4* fW2u     = (uint4*)w;  w += 2048 * sizeof(uint4);
    uint4* fU1b     = (uint4*)w;  w += 2048 * sizeof(uint4);
    uint4* fU2      = (uint4*)w;  w += 2048 * sizeof(uint4);
    uint4* fP       = (uint4*)w;  w += 2048 * sizeof(uint4);
    uint4* fIw2     = (uint4*)w;  w += 1024 * sizeof(uint4);
    uint4* fP0      = (uint4*)w;  w += 2048 * sizeof(uint4);
    uint4* fIw1     = (uint4*)w;  w += 4096 * sizeof(uint4);
    int*   cnt      = (int*)w;    w += sizeof(int) * E;
    int*   offs     = (int*)w;    w += sizeof(int) * (E + 1);
    int*   cursor   = (int*)w;    w += sizeof(int) * E;
    int*   bt       = (int*)w;    w += sizeof(int) * E;
    int*   srclist  = (int*)w;    w += sizeof(int) * BE;
    int*   bsum     = (int*)w;    w += sizeof(int) * 1024;
    int*   bpre     = (int*)w;    w += sizeof(int) * 1024;
    w = (char*)(((uintptr_t)w + 15) & ~(uintptr_t)15);
    float* pd       = (float*)w;  w += sizeof(float) * (size_t)E * DDIM;
    uint4* ps       = (uint4*)w;  w += sizeof(unsigned short) * (size_t)E * DDIM;
    float* pa       = (float*)w;  w += sizeof(float) * (size_t)N * DDIM;
    float* qa       = (float*)w;  w += sizeof(float) * (size_t)N * DDIM;
    float* na       = (float*)w;  w += sizeof(float) * (size_t)N;
    w = (char*)(((uintptr_t)w + 15) & ~(uintptr_t)15);
    // second proj buffers (fused-proj path)
    float* pd2      = (float*)w;  w += sizeof(float) * (size_t)E * DDIM;
    uint4* ps2      = (uint4*)w;  w += sizeof(unsigned short) * (size_t)E * DDIM;
    bool fuse_proj = ((size_t)(w - (char*)d_ws) <= ws_size);

    const int* row  = edge_index;
    const int* col  = edge_index + E;
    const int* bsrc = bond_edge_index;
    const int* bdst = bond_edge_index + BE;

    // CSR build + constant prep (count merged into prep launch)
    hipMemsetAsync(cnt, 0, (size_t)E * sizeof(int), stream);
    prepcount_k<<<PREPB + CNTB, 256, 0, stream>>>(
        emb, mw1, mb1, mw2, mb2, uw1, uw2, iw2, iw1,
        tt, b2u, fW2u, fU1b, fU2, fP, fIw2, fP0, fIw1, bdst, cnt, BE);
    bsum_k<<<NB, 256, 0, stream>>>(cnt, bsum, E);
    bscan_k<<<1, 1024, 0, stream>>>(bsum, bpre, NB);
    offs_k<<<NB, 256, 0, stream>>>(cnt, bpre, offs, cursor, E);
    scatter_k<<<(BE + 255) / 256, 256, 0, stream>>>(bsrc, bdst, cursor, srclist, BE);

    // cooperative-launch capability (cached)
    static int s_coopBlocks = -1;
    if (s_coopBlocks < 0) {
        int dev = 0;
        hipGetDevice(&dev);
        int coopAttr = 0;
        hipDeviceGetAttribute(&coopAttr, hipDeviceAttributeCooperativeLaunch, dev);
        int nCU = 0;
        hipDeviceGetAttribute(&nCU, hipDeviceAttributeMultiprocessorCount, dev);
        int mb = 0;
        hipError_t oe = hipOccupancyMaxActiveBlocksPerMultiprocessor(&mb, fused_k, 512, 0);
        s_coopBlocks = (coopAttr && oe == hipSuccess && nCU > 0) ? mb * nCU : 0;
    }

    bool coopDone = false;
    if (fuse_proj && s_coopBlocks >= EBS) {
        int Nv = N, Ev = E;
        void* kargs[] = {
            (void*)&xout, (void*)&row, (void*)&col,
            (void*)&AF, (void*)&fIw1, (void*)&pa, (void*)&qa, (void*)&na, (void*)&Nv,
            (void*)&ib1, (void*)&fIw2, (void*)&ib2, (void*)&fP0,
            (void*)&bt, (void*)&pd, (void*)&ps,
            (void*)&tt, (void*)&offs, (void*)&srclist, (void*)&cnt,
            (void*)&fW2u, (void*)&b2u, (void*)&fU1b, (void*)&ub1,
            (void*)&fU2, (void*)&ub2, (void*)&fP,
            (void*)&pd2, (void*)&ps2,
            (void*)&batch, (void*)&gfeat, (void*)&Ev };
        hipError_t le = hipLaunchCooperativeKernel((const void*)fused_k, dim3(EBS),
                                                   dim3(512), kargs, 0, stream);
        coopDone = (le == hipSuccess);
    }

    if (!coopDone) {
        // fallback: separate-kernel path (round-5 behavior)
        atom_proj_k<<<APB, 512, 0, stream>>>(AF, fIw1, pa, qa, na, N);
        bond_init2_k<<<EBS, 512, 0, stream>>>(AF, row, col, pa, qa, na, ib1, fIw2, ib2,
                                              fP0, xout, bt, pd, ps, E);
        hipMemsetAsync(gfeat, 0, NGRAPHS * DDIM * sizeof(float), stream);
        if (fuse_proj) {
            layer_k<<<EBS, 512, 0, stream>>>(
                xout, pd, ps, tt, bt, offs, srclist, cnt,
                fW2u, b2u, fU1b, ub1, fU2, ub2,
                fP, pd2, ps2, E, row, batch, gfeat, 0);
            layer_k<<<EBS, 512, 0, stream>>>(
                xout, pd2, ps2, tt + NTYPES * DDIM, bt, offs, srclist, cnt,
                fW2u + 1024, b2u + DDIM, fU1b + 1024, ub1 + DDIM,
                fU2 + 1024, ub2 + DDIM,
                nullptr, nullptr, nullptr, E, row, batch, gfeat, 1);
        } else {
            for (int l = 0; l < 2; ++l) {
                if (l > 0)
                    proj_k<<<EB, 256, 0, stream>>>(xout, mw1 + (size_t)l * 192 * 64, pd, ps, E);
                layer_k<<<EBS, 512, 0, stream>>>(
                    xout, pd, ps, tt + (size_t)l * NTYPES * DDIM, bt, offs, srclist, cnt,
                    fW2u + (size_t)l * 1024, b2u + (size_t)l * DDIM,
                    fU1b + (size_t)l * 1024, ub1 + (size_t)l * DDIM,
                    fU2 + (size_t)l * 1024, ub2 + (size_t)l * DDIM,
                    nullptr, nullptr, nullptr, E, row, batch, gfeat, l == 1 ? 1 : 0);
            }
        }
        pool_final_k<<<NGRAPHS, 64, 0, stream>>>(row, batch, gfeat, E);
    }
}